// Round 3
// baseline (4412.325 us; speedup 1.0000x reference)
//
#include <hip/hip_runtime.h>
#include <math.h>

// ---------------- problem constants ----------------
#define B_   8
#define S_   1024
#define BS_  8192        // B*S
#define D_   512
#define IN_  1024        // INNER
#define FIN_ 75

// ---------------- workspace layout (floats) ----------------
// h      : BS_*D_           persistent residual stream
// up     : BS_*2048         [x_m | z]; x_m overwritten in-place by v; later reused as wx
// xc     : BS_*IN_          conv+silu output (mLSTM), later s-conv output (stride 512)
// q, k   : BS_*IN_
// ht     : BS_*IN_          htil / hs; first BS_*D_ floats double as xn (LN outputs)
// small  : ig, fg, a, pm, mld (B*4*S each), ylast (B*D)
#define OFF_H    0UL
#define OFF_UP   4194304UL
#define OFF_XC   20971520UL
#define OFF_Q    29360128UL
#define OFF_K    37748736UL
#define OFF_HT   46137344UL
#define OFF_XN   OFF_HT
#define OFF_IG   54525952UL
#define OFF_FG   54558720UL
#define OFF_A    54591488UL
#define OFF_PM   54624256UL
#define OFF_MLD  54657024UL
#define OFF_YL   54689792UL
// total 54,693,888 floats = ~209 MiB

static __device__ __forceinline__ float siluf(float x){ return x / (1.0f + expf(-x)); }
static __device__ __forceinline__ float logsigf(float x){ return fminf(x, 0.0f) - log1pf(expf(-fabsf(x))); }

// ---------------- 1. input projection: h = x @ w_in^T + b_in ----------------
__global__ __launch_bounds__(256) void k_inproj(const float* __restrict__ x,
                                                const float* __restrict__ w,
                                                const float* __restrict__ b,
                                                float* __restrict__ out){
  int row = blockIdx.x;
  int tid = threadIdx.x;
  __shared__ float xs[FIN_];
  if (tid < FIN_) xs[tid] = x[(size_t)row*FIN_ + tid];
  __syncthreads();
  #pragma unroll
  for (int rep = 0; rep < 2; ++rep){
    int n = tid + rep*256;
    const float* wr = w + (size_t)n*FIN_;
    float acc = b[n];
    #pragma unroll 5
    for (int k2 = 0; k2 < FIN_; ++k2) acc += xs[k2]*wr[k2];
    out[(size_t)row*D_ + n] = acc;
  }
}

// ---------------- 2. LayerNorm over D_=512 ----------------
__global__ __launch_bounds__(256) void k_ln(const float* __restrict__ in,
                                            const float* __restrict__ w,
                                            float* __restrict__ out){
  int row = blockIdx.x;
  int tid = threadIdx.x;
  const float* ip = in + (size_t)row*D_;
  float2 v = ((const float2*)ip)[tid];
  float s = v.x + v.y, ss = v.x*v.x + v.y*v.y;
  #pragma unroll
  for (int off = 32; off > 0; off >>= 1){ s += __shfl_down(s, off); ss += __shfl_down(ss, off); }
  __shared__ float rA[4], rB[4];
  int lane = tid & 63, wv = tid >> 6;
  if (lane == 0){ rA[wv] = s; rB[wv] = ss; }
  __syncthreads();
  float S = rA[0]+rA[1]+rA[2]+rA[3];
  float SS = rB[0]+rB[1]+rB[2]+rB[3];
  float mu = S * (1.0f/D_);
  float inv = rsqrtf(SS * (1.0f/D_) - mu*mu + 1e-5f);
  float2 o;
  o.x = (v.x - mu)*inv*w[2*tid];
  o.y = (v.y - mu)*inv*w[2*tid+1];
  ((float2*)(out + (size_t)row*D_))[tid] = o;
}

// ---------------- 3. generic GEMM: C = A[M,K] @ W[N,K]^T + bias (+C if accum) ----------------
__global__ __launch_bounds__(256) void k_gemm(const float* __restrict__ A,
                                              const float* __restrict__ W,
                                              const float* __restrict__ bias,
                                              float* __restrict__ C,
                                              int N, int K, int accum){
  __shared__ __align__(16) float sA[16][68];
  __shared__ __align__(16) float sB[16][68];
  int bm = blockIdx.y*64, bn = blockIdx.x*64;
  int tid = threadIdx.x;
  int ty = tid >> 4, tx = tid & 15;
  float acc[4][4] = {};
  for (int k0 = 0; k0 < K; k0 += 16){
    #pragma unroll
    for (int i = 0; i < 4; ++i){
      int idx = tid + i*256;
      int kk = idx & 15, m = idx >> 4;
      sA[kk][m] = A[(size_t)(bm+m)*K + k0 + kk];
      sB[kk][m] = W[(size_t)(bn+m)*K + k0 + kk];
    }
    __syncthreads();
    #pragma unroll
    for (int kk = 0; kk < 16; ++kk){
      float4 a4 = *(const float4*)&sA[kk][ty*4];
      float4 b4 = *(const float4*)&sB[kk][tx*4];
      acc[0][0] += a4.x*b4.x; acc[0][1] += a4.x*b4.y; acc[0][2] += a4.x*b4.z; acc[0][3] += a4.x*b4.w;
      acc[1][0] += a4.y*b4.x; acc[1][1] += a4.y*b4.y; acc[1][2] += a4.y*b4.z; acc[1][3] += a4.y*b4.w;
      acc[2][0] += a4.z*b4.x; acc[2][1] += a4.z*b4.y; acc[2][2] += a4.z*b4.z; acc[2][3] += a4.z*b4.w;
      acc[3][0] += a4.w*b4.x; acc[3][1] += a4.w*b4.y; acc[3][2] += a4.w*b4.z; acc[3][3] += a4.w*b4.w;
    }
    __syncthreads();
  }
  #pragma unroll
  for (int i = 0; i < 4; ++i){
    int rr = bm + ty*4 + i;
    #pragma unroll
    for (int j = 0; j < 4; ++j){
      int cc = bn + tx*4 + j;
      float vv = acc[i][j] + bias[cc];
      size_t off = (size_t)rr*N + cc;
      if (accum) vv += C[off];
      C[off] = vv;
    }
  }
}

// ---------------- 4. depthwise causal conv (K=4) + SiLU ----------------
__global__ __launch_bounds__(256) void k_conv_silu(const float* __restrict__ in,
                                                   const float* __restrict__ kern,
                                                   const float* __restrict__ bias,
                                                   float* __restrict__ out,
                                                   int C, int istride, int ostride){
  size_t idx = (size_t)blockIdx.x*256 + threadIdx.x;
  int c = (int)(idx % C);
  size_t rs = idx / C;
  int s = (int)(rs & 1023);
  int b = (int)(rs >> 10);
  const float* ip = in + ((size_t)b*S_)*istride + c;
  float acc = bias[c];
  #pragma unroll
  for (int j = 0; j < 4; ++j){
    int sp = s - 3 + j;
    if (sp >= 0) acc += ip[(size_t)sp*istride] * kern[j*C + c];
  }
  out[((size_t)b*S_ + s)*ostride + c] = siluf(acc);
}

// ---------------- 5. 4x4 block-diagonal (LinearHeadwiseExpand, qkv) ----------------
__global__ __launch_bounds__(256) void k_headwise4(const float* __restrict__ in,
                                                   const float* __restrict__ w,
                                                   const float* __restrict__ bias,
                                                   float* __restrict__ out,
                                                   int istride, int ostride){
  int row = blockIdx.x;
  int ph = threadIdx.x;            // 256 blocks of 4
  float4 iv = *(const float4*)&in[(size_t)row*istride + ph*4];
  const float* wp = w + ph*16;     // w[ph][o][d]
  float4 ov;
  ov.x = bias[ph*4+0] + wp[0] *iv.x + wp[1] *iv.y + wp[2] *iv.z + wp[3] *iv.w;
  ov.y = bias[ph*4+1] + wp[4] *iv.x + wp[5] *iv.y + wp[6] *iv.z + wp[7] *iv.w;
  ov.z = bias[ph*4+2] + wp[8] *iv.x + wp[9] *iv.y + wp[10]*iv.z + wp[11]*iv.w;
  ov.w = bias[ph*4+3] + wp[12]*iv.x + wp[13]*iv.y + wp[14]*iv.z + wp[15]*iv.w;
  *(float4*)&out[(size_t)row*ostride + ph*4] = ov;
}

// ---------------- 6. mLSTM i/f gate projections over concat(q,k,v) ----------------
__global__ __launch_bounds__(256) void k_gates(const float* __restrict__ q,
                                               const float* __restrict__ k,
                                               const float* __restrict__ v,
                                               const float* __restrict__ igw,
                                               const float* __restrict__ igb,
                                               const float* __restrict__ fgw,
                                               const float* __restrict__ fgb,
                                               float* __restrict__ ig,
                                               float* __restrict__ fg){
  int row = blockIdx.x, tid = threadIdx.x;
  float pi0=0,pi1=0,pi2=0,pi3=0, pf0=0,pf1=0,pf2=0,pf3=0;
  for (int c = tid; c < 3072; c += 256){
    float xv;
    if (c < 1024)      xv = q[(size_t)row*1024 + c];
    else if (c < 2048) xv = k[(size_t)row*1024 + c - 1024];
    else               xv = v[(size_t)row*2048 + c - 2048];
    pi0 += igw[c]*xv;        pf0 += fgw[c]*xv;
    pi1 += igw[3072+c]*xv;   pf1 += fgw[3072+c]*xv;
    pi2 += igw[6144+c]*xv;   pf2 += fgw[6144+c]*xv;
    pi3 += igw[9216+c]*xv;   pf3 += fgw[9216+c]*xv;
  }
  #pragma unroll
  for (int off = 32; off > 0; off >>= 1){
    pi0 += __shfl_down(pi0,off); pi1 += __shfl_down(pi1,off);
    pi2 += __shfl_down(pi2,off); pi3 += __shfl_down(pi3,off);
    pf0 += __shfl_down(pf0,off); pf1 += __shfl_down(pf1,off);
    pf2 += __shfl_down(pf2,off); pf3 += __shfl_down(pf3,off);
  }
  __shared__ float red[8][4];
  int lane = tid & 63, wv = tid >> 6;
  if (lane == 0){
    red[0][wv]=pi0; red[1][wv]=pi1; red[2][wv]=pi2; red[3][wv]=pi3;
    red[4][wv]=pf0; red[5][wv]=pf1; red[6][wv]=pf2; red[7][wv]=pf3;
  }
  __syncthreads();
  if (tid < 8){
    float sv = red[tid][0]+red[tid][1]+red[tid][2]+red[tid][3];
    int b2 = row >> 10, s2 = row & 1023;
    if (tid < 4) ig[((size_t)(b2*4 + tid))*S_ + s2] = sv + igb[tid];
    else         fg[((size_t)(b2*4 + (tid-4)))*S_ + s2] = sv + fgb[tid-4];
  }
}

// ---------------- 7. per-(b,h) decay scans: cum, a = ig - cum, prefix-max, mld ----------------
__global__ void k_decay(const float* __restrict__ ig, const float* __restrict__ fg,
                        float* __restrict__ a, float* __restrict__ pm, float* __restrict__ mld){
  int bh = threadIdx.x;            // 32 sequences
  if (bh >= 32) return;
  const float* igp = ig + (size_t)bh*S_;
  const float* fgp = fg + (size_t)bh*S_;
  float cum = 0.0f, pmax = -INFINITY;
  for (int t = 0; t < S_; ++t){
    cum += logsigf(fgp[t]);
    float av = igp[t] - cum;
    pmax = fmaxf(pmax, av);
    a[(size_t)bh*S_ + t]   = av;
    pm[(size_t)bh*S_ + t]  = pmax;
    mld[(size_t)bh*S_ + t] = cum + pmax;
  }
}

// ---------------- 8. mLSTM parallel cell + normalizer + per-head LN ----------------
__global__ __launch_bounds__(256) void k_mcell(const float* __restrict__ q,
                                               const float* __restrict__ k,
                                               const float* __restrict__ v,
                                               const float* __restrict__ aarr,
                                               const float* __restrict__ pmarr,
                                               const float* __restrict__ mldarr,
                                               const float* __restrict__ onw,
                                               float* __restrict__ htil){
  int sb = blockIdx.x, hh = blockIdx.y, bb = blockIdx.z;
  int tid = threadIdx.x;
  __shared__ __align__(16) float qs[32][260];
  __shared__ __align__(16) float ks[32][260];
  __shared__ __align__(16) float vs[32][260];
  __shared__ float wts[32][33];
  __shared__ float asld[32];
  __shared__ float pmld[32];
  __shared__ float red[32][8];
  int s0 = sb*32;
  int bh = bb*4 + hh;
  int lr = tid >> 3, lc4 = (tid & 7)*4;
  const float* qbase = q + ((size_t)(bb*S_ + s0 + lr))*IN_ + hh*256;
  #pragma unroll
  for (int i = 0; i < 8; ++i){
    float4 t4 = *(const float4*)&qbase[lc4 + i*32];
    t4.x *= 0.0625f; t4.y *= 0.0625f; t4.z *= 0.0625f; t4.w *= 0.0625f;
    *(float4*)&qs[lr][lc4 + i*32] = t4;
  }
  if (tid < 32) pmld[tid] = pmarr[(size_t)bh*S_ + s0 + tid];
  float num[8][4] = {};
  float den_acc = 0.0f;
  int r = tid >> 3;
  int tq4 = (tid & 7)*4;       // phase-A: 4 t-columns; phase-B: 4-float dim group
  for (int tt = 0; tt <= sb; ++tt){
    int t0 = tt*32;
    __syncthreads();           // protect ks/vs from previous phase-B readers
    const float* kbase = k + ((size_t)(bb*S_ + t0 + lr))*IN_ + hh*256;
    const float* vbase = v + ((size_t)(bb*S_ + t0 + lr))*2048 + hh*256;
    #pragma unroll
    for (int i = 0; i < 8; ++i){
      *(float4*)&ks[lr][lc4 + i*32] = *(const float4*)&kbase[lc4 + i*32];
      *(float4*)&vs[lr][lc4 + i*32] = *(const float4*)&vbase[lc4 + i*32];
    }
    if (tid < 32) asld[tid] = aarr[(size_t)bh*S_ + t0 + tid];
    __syncthreads();
    // phase A: qk^T for 4 t's of row r
    float ac0=0, ac1=0, ac2=0, ac3=0;
    #pragma unroll 8
    for (int kk = 0; kk < 64; ++kk){
      float4 q4 = *(const float4*)&qs[r][kk*4];
      float4 k0 = *(const float4*)&ks[tq4+0][kk*4];
      float4 k1 = *(const float4*)&ks[tq4+1][kk*4];
      float4 k2 = *(const float4*)&ks[tq4+2][kk*4];
      float4 k3 = *(const float4*)&ks[tq4+3][kk*4];
      ac0 += q4.x*k0.x + q4.y*k0.y + q4.z*k0.z + q4.w*k0.w;
      ac1 += q4.x*k1.x + q4.y*k1.y + q4.z*k1.z + q4.w*k1.w;
      ac2 += q4.x*k2.x + q4.y*k2.y + q4.z*k2.z + q4.w*k2.w;
      ac3 += q4.x*k3.x + q4.y*k3.y + q4.z*k3.z + q4.w*k3.w;
    }
    float pmr = pmld[r];
    int tg = t0 + tq4;
    float w0 = (tg+0 <= s0+r) ? ac0*expf(asld[tq4+0]-pmr) : 0.0f;
    float w1 = (tg+1 <= s0+r) ? ac1*expf(asld[tq4+1]-pmr) : 0.0f;
    float w2 = (tg+2 <= s0+r) ? ac2*expf(asld[tq4+2]-pmr) : 0.0f;
    float w3 = (tg+3 <= s0+r) ? ac3*expf(asld[tq4+3]-pmr) : 0.0f;
    wts[r][tq4+0]=w0; wts[r][tq4+1]=w1; wts[r][tq4+2]=w2; wts[r][tq4+3]=w3;
    den_acc += w0+w1+w2+w3;
    __syncthreads();
    // phase B: num += w * v
    for (int t2 = 0; t2 < 32; ++t2){
      float wvv = wts[r][t2];
      #pragma unroll
      for (int i = 0; i < 8; ++i){
        float4 v4 = *(const float4*)&vs[t2][i*32 + tq4];
        num[i][0] += wvv*v4.x; num[i][1] += wvv*v4.y;
        num[i][2] += wvv*v4.z; num[i][3] += wvv*v4.w;
      }
    }
  }
  // epilogue: normalizer + per-head LN
  __syncthreads();
  red[r][tid&7] = den_acc;
  __syncthreads();
  float den = 0;
  #pragma unroll
  for (int i = 0; i < 8; ++i) den += red[r][i];
  float mldr = mldarr[(size_t)bh*S_ + s0 + r];
  float inv = 1.0f / (fmaxf(fabsf(den), expf(-mldr)) + 1e-6f);
  float sm = 0, sq = 0;
  #pragma unroll
  for (int i = 0; i < 8; ++i)
    #pragma unroll
    for (int j = 0; j < 4; ++j){ float hv = num[i][j]*inv; sm += hv; sq += hv*hv; }
  __syncthreads();
  red[r][tid&7] = sm; __syncthreads();
  float Sm = 0;
  #pragma unroll
  for (int i = 0; i < 8; ++i) Sm += red[r][i];
  __syncthreads();
  red[r][tid&7] = sq; __syncthreads();
  float Sq = 0;
  #pragma unroll
  for (int i = 0; i < 8; ++i) Sq += red[r][i];
  float mu = Sm*(1.0f/256.0f);
  float lninv = rsqrtf(Sq*(1.0f/256.0f) - mu*mu + 1e-5f);
  float* obase = htil + ((size_t)(bb*S_ + s0 + r))*IN_ + hh*256;
  const float* onp = onw + hh*256;
  #pragma unroll
  for (int i = 0; i < 8; ++i){
    int d = i*32 + tq4;
    float4 o4;
    o4.x = (num[i][0]*inv - mu)*lninv*onp[d+0];
    o4.y = (num[i][1]*inv - mu)*lninv*onp[d+1];
    o4.z = (num[i][2]*inv - mu)*lninv*onp[d+2];
    o4.w = (num[i][3]*inv - mu)*lninv*onp[d+3];
    *(float4*)&obase[d] = o4;
  }
}

// ---------------- 9. hs = (htil + skip*xc) * silu(z), in place into htil ----------------
__global__ __launch_bounds__(256) void k_hs(const float* __restrict__ xc,
                                            const float* __restrict__ up,
                                            const float* __restrict__ skw,
                                            float* __restrict__ ht){
  size_t idx = (size_t)blockIdx.x*256 + threadIdx.x;
  int c = (int)(idx & 1023);
  size_t row = idx >> 10;
  float z = up[row*2048 + 1024 + c];
  ht[idx] = (ht[idx] + skw[c]*xc[idx]) * siluf(z);
}

// ---------------- 10. 128x128 block-diagonal gate projections -> wx ----------------
__global__ __launch_bounds__(256) void k_headwise128(const float* __restrict__ xc,
                                                     const float* __restrict__ xn,
                                                     const float* __restrict__ wi,
                                                     const float* __restrict__ wf,
                                                     const float* __restrict__ wz,
                                                     const float* __restrict__ wo,
                                                     float* __restrict__ wx){
  int mt = blockIdx.x, slice = blockIdx.y;   // 256 m-tiles of 32 rows, 16 slices
  int gate = slice >> 2, hh = slice & 3;
  const float* in = (gate < 2) ? xc : xn;
  const float* wmat = (gate==0 ? wi : gate==1 ? wf : gate==2 ? wz : wo) + (size_t)hh*16384;
  __shared__ __align__(16) float ins[32][132];
  __shared__ __align__(16) float wsl[128][132];
  int tid = threadIdx.x, m0 = mt*32;
  #pragma unroll
  for (int i = 0; i < 4; ++i){
    int idx = tid + i*256;
    int rr = idx >> 5, c4 = (idx & 31)*4;
    *(float4*)&ins[rr][c4] = *(const float4*)&in[(size_t)(m0+rr)*512 + hh*128 + c4];
  }
  #pragma unroll
  for (int i = 0; i < 16; ++i){
    int idx = tid + i*256;
    int o = idx >> 5, d4 = (idx & 31)*4;
    *(float4*)&wsl[o][d4] = *(const float4*)&wmat[(size_t)o*128 + d4];
  }
  __syncthreads();
  int rg = tid >> 4, cg = tid & 15;
  float acc[2][8] = {};
  for (int k4 = 0; k4 < 32; ++k4){
    float4 a0 = *(const float4*)&ins[rg*2+0][k4*4];
    float4 a1 = *(const float4*)&ins[rg*2+1][k4*4];
    #pragma unroll
    for (int j = 0; j < 8; ++j){
      float4 w4 = *(const float4*)&wsl[cg*8+j][k4*4];
      acc[0][j] += a0.x*w4.x + a0.y*w4.y + a0.z*w4.z + a0.w*w4.w;
      acc[1][j] += a1.x*w4.x + a1.y*w4.y + a1.z*w4.z + a1.w*w4.w;
    }
  }
  #pragma unroll
  for (int r2 = 0; r2 < 2; ++r2){
    float* op = wx + (size_t)(m0 + rg*2 + r2)*2048 + gate*512 + hh*128 + cg*8;
    float4 o0 = { acc[r2][0], acc[r2][1], acc[r2][2], acc[r2][3] };
    float4 o1 = { acc[r2][4], acc[r2][5], acc[r2][6], acc[r2][7] };
    *(float4*)&op[0] = o0;
    *(float4*)&op[4] = o1;
  }
}

// ---------------- 11. sequential sLSTM scan, one block per (b,head) ----------------
__global__ __launch_bounds__(512) void k_sscan(const float* __restrict__ wx,
                                               const float* __restrict__ R,
                                               const float* __restrict__ cb,
                                               float* __restrict__ ylast){
  int bb = blockIdx.x >> 2, hh = blockIdx.x & 3;
  int tid = threadIdx.x;                 // 512: one gate-row each
  int gate = tid >> 7, d = tid & 127;
  __shared__ __align__(16) float ys[128];
  __shared__ float raws[512];
  float4 Rr[32];
  const float* rrow = R + ((size_t)hh*512 + tid)*128;
  #pragma unroll
  for (int i = 0; i < 32; ++i) Rr[i] = ((const float4*)rrow)[i];
  float bias = cb[gate*512 + hh*128 + d];
  float c = 0, n = 0, m = 0;
  if (tid < 128) ys[tid] = 0.0f;
  __syncthreads();
  const float* wxb = wx + (size_t)bb*S_*2048 + gate*512 + hh*128 + d;
  for (int t = 0; t < S_; ++t){
    float ry = 0;
    #pragma unroll
    for (int i = 0; i < 32; ++i){
      float4 y4 = ((const float4*)ys)[i];
      ry += Rr[i].x*y4.x + Rr[i].y*y4.y + Rr[i].z*y4.z + Rr[i].w*y4.w;
    }
    raws[tid] = wxb[(size_t)t*2048] + ry + bias;
    __syncthreads();
    if (tid < 128){
      float ir = raws[d], fr = raws[128+d], zr = raws[256+d], og = raws[384+d];
      float lfm = m + logsigf(fr);
      float mnew = (n == 0.0f) ? ir : fmaxf(ir, lfm);
      float igate = expf(ir - mnew);
      float fgate = expf(lfm - mnew);
      c = fgate*c + igate*tanhf(zr);
      n = fgate*n + igate;
      m = mnew;
      float yv = (1.0f/(1.0f+expf(-og))) * c / n;
      ys[d] = yv;
      if (t == S_-1) ylast[(size_t)bb*512 + hh*128 + d] = yv;
    }
    __syncthreads();
  }
}

// ---------------- 12. last-token epilogue: mh-LN + residual + LN + FFN + LN + FC ----------------
__global__ __launch_bounds__(256) void k_final(const float* __restrict__ h,
                                               const float* __restrict__ ylast,
                                               const float* __restrict__ gnw,
                                               const float* __restrict__ ln2w,
                                               const float* __restrict__ upw,
                                               const float* __restrict__ upb,
                                               const float* __restrict__ dnw,
                                               const float* __restrict__ dnb,
                                               const float* __restrict__ lnfw,
                                               const float* __restrict__ fcw,
                                               const float* __restrict__ fcb,
                                               float* __restrict__ out){
  int b = blockIdx.x, tid = threadIdx.x;
  __shared__ __align__(16) float hb[512];
  __shared__ __align__(16) float xb[512];
  __shared__ __align__(16) float ff[1408];
  __shared__ __align__(16) float act[704];
  __shared__ float rA[4], rB[4], hstat[4][2];
  int lane = tid & 63, wv = tid >> 6;
  // per-head LN of sLSTM y_last (wave wv = head wv)
  float y0 = ylast[(size_t)b*512 + wv*128 + lane];
  float y1 = ylast[(size_t)b*512 + wv*128 + 64 + lane];
  {
    float s = y0 + y1, ss = y0*y0 + y1*y1;
    #pragma unroll
    for (int off = 32; off > 0; off >>= 1){ s += __shfl_down(s, off); ss += __shfl_down(ss, off); }
    if (lane == 0){ hstat[wv][0] = s*(1.0f/128.0f); hstat[wv][1] = ss*(1.0f/128.0f); }
  }
  __syncthreads();
  {
    float mu = hstat[wv][0];
    float inv = rsqrtf(hstat[wv][1] - mu*mu + 1e-5f);
    int d0 = wv*128 + lane, d1 = d0 + 64;
    const float* hrow = h + ((size_t)(b*S_ + S_-1))*512;
    hb[d0] = hrow[d0] + (y0 - mu)*inv*gnw[d0];
    hb[d1] = hrow[d1] + (y1 - mu)*inv*gnw[d1];
  }
  __syncthreads();
  // LN2
  {
    float v0 = hb[tid], v1 = hb[tid+256];
    float s = v0+v1, ss = v0*v0+v1*v1;
    #pragma unroll
    for (int off = 32; off > 0; off >>= 1){ s += __shfl_down(s, off); ss += __shfl_down(ss, off); }
    if (lane == 0){ rA[wv] = s; rB[wv] = ss; }
    __syncthreads();
    float S = rA[0]+rA[1]+rA[2]+rA[3], SS = rB[0]+rB[1]+rB[2]+rB[3];
    float mu = S*(1.0f/512.0f);
    float inv = rsqrtf(SS*(1.0f/512.0f) - mu*mu + 1e-5f);
    xb[tid]     = (v0 - mu)*inv*ln2w[tid];
    xb[tid+256] = (v1 - mu)*inv*ln2w[tid+256];
  }
  __syncthreads();
  for (int o = tid; o < 1408; o += 256){
    const float4* wr = (const float4*)(upw + (size_t)o*512);
    float acc = upb[o];
    for (int k4 = 0; k4 < 128; ++k4){
      float4 w4 = wr[k4]; float4 x4 = ((const float4*)xb)[k4];
      acc += w4.x*x4.x + w4.y*x4.y + w4.z*x4.z + w4.w*x4.w;
    }
    ff[o] = acc;
  }
  __syncthreads();
  for (int j = tid; j < 704; j += 256){
    float g = ff[j];
    act[j] = 0.5f*g*(1.0f + erff(g*0.70710678118654752f)) * ff[704+j];
  }
  __syncthreads();
  for (int d2 = tid; d2 < 512; d2 += 256){
    const float4* wr = (const float4*)(dnw + (size_t)d2*704);
    float acc = dnb[d2];
    for (int k4 = 0; k4 < 176; ++k4){
      float4 w4 = wr[k4]; float4 a4 = ((const float4*)act)[k4];
      acc += w4.x*a4.x + w4.y*a4.y + w4.z*a4.z + w4.w*a4.w;
    }
    hb[d2] += acc;
  }
  __syncthreads();
  // final LN
  {
    float v0 = hb[tid], v1 = hb[tid+256];
    float s = v0+v1, ss = v0*v0+v1*v1;
    #pragma unroll
    for (int off = 32; off > 0; off >>= 1){ s += __shfl_down(s, off); ss += __shfl_down(ss, off); }
    if (lane == 0){ rA[wv] = s; rB[wv] = ss; }
    __syncthreads();
    float S = rA[0]+rA[1]+rA[2]+rA[3], SS = rB[0]+rB[1]+rB[2]+rB[3];
    float mu = S*(1.0f/512.0f);
    float inv = rsqrtf(SS*(1.0f/512.0f) - mu*mu + 1e-5f);
    xb[tid]     = (v0 - mu)*inv*lnfw[tid];
    xb[tid+256] = (v1 - mu)*inv*lnfw[tid+256];
  }
  __syncthreads();
  {
    float val = xb[tid]*fcw[tid] + xb[tid+256]*fcw[tid+256];
    #pragma unroll
    for (int off = 32; off > 0; off >>= 1) val += __shfl_down(val, off);
    if (lane == 0) rA[wv] = val;
    __syncthreads();
    if (tid == 0) out[b] = rA[0]+rA[1]+rA[2]+rA[3] + fcb[0];
  }
}

// ---------------- launch ----------------
extern "C" void kernel_launch(void* const* d_in, const int* in_sizes, int n_in,
                              void* d_out, int out_size, void* d_ws, size_t ws_size,
                              hipStream_t stream) {
  const float* x      = (const float*)d_in[0];
  const float* w_in   = (const float*)d_in[1];
  const float* b_in   = (const float*)d_in[2];
  const float* ln0_w  = (const float*)d_in[3];
  const float* m_up_w = (const float*)d_in[4];
  const float* m_up_b = (const float*)d_in[5];
  const float* m_cv_k = (const float*)d_in[6];
  const float* m_cv_b = (const float*)d_in[7];
  const float* q_w    = (const float*)d_in[8];
  const float* q_b    = (const float*)d_in[9];
  const float* k_w    = (const float*)d_in[10];
  const float* k_b    = (const float*)d_in[11];
  const float* v_w    = (const float*)d_in[12];
  const float* v_b    = (const float*)d_in[13];
  const float* ig_w   = (const float*)d_in[14];
  const float* ig_b   = (const float*)d_in[15];
  const float* fg_w   = (const float*)d_in[16];
  const float* fg_b   = (const float*)d_in[17];
  const float* onormw = (const float*)d_in[18];
  const float* skip_w = (const float*)d_in[19];
  const float* m_dn_w = (const float*)d_in[20];
  const float* m_dn_b = (const float*)d_in[21];
  const float* ln1_w  = (const float*)d_in[22];
  const float* s_cv_k = (const float*)d_in[23];
  const float* s_cv_b = (const float*)d_in[24];
  const float* wi     = (const float*)d_in[25];
  const float* wf     = (const float*)d_in[26];
  const float* wz     = (const float*)d_in[27];
  const float* wo     = (const float*)d_in[28];
  const float* r_kern = (const float*)d_in[29];
  const float* cell_b = (const float*)d_in[30];
  const float* gn_w   = (const float*)d_in[31];
  const float* ln2_w  = (const float*)d_in[32];
  const float* ffup_w = (const float*)d_in[33];
  const float* ffup_b = (const float*)d_in[34];
  const float* ffdn_w = (const float*)d_in[35];
  const float* ffdn_b = (const float*)d_in[36];
  const float* lnf_w  = (const float*)d_in[37];
  const float* fc_w   = (const float*)d_in[38];
  const float* fc_b   = (const float*)d_in[39];

  float* ws   = (float*)d_ws;
  float* hb   = ws + OFF_H;
  float* up   = ws + OFF_UP;    // [x_m | z]; x_m -> v in-place; later wx
  float* xc   = ws + OFF_XC;
  float* qb   = ws + OFF_Q;
  float* kb   = ws + OFF_K;
  float* ht   = ws + OFF_HT;    // htil / hs
  float* xn   = ws + OFF_XN;    // aliases first half of ht region
  float* igv  = ws + OFF_IG;
  float* fgv  = ws + OFF_FG;
  float* av   = ws + OFF_A;
  float* pmv  = ws + OFF_PM;
  float* mldv = ws + OFF_MLD;
  float* ylast= ws + OFF_YL;
  float* outp = (float*)d_out;

  // ---- block 0: mLSTM ----
  k_inproj<<<BS_, 256, 0, stream>>>(x, w_in, b_in, hb);
  k_ln<<<BS_, 256, 0, stream>>>(hb, ln0_w, xn);
  k_gemm<<<dim3(2048/64, BS_/64), 256, 0, stream>>>(xn, m_up_w, m_up_b, up, 2048, 512, 0);
  k_conv_silu<<<(BS_*1024)/256, 256, 0, stream>>>(up, m_cv_k, m_cv_b, xc, 1024, 2048, 1024);
  k_headwise4<<<BS_, 256, 0, stream>>>(xc, q_w, q_b, qb, 1024, 1024);
  k_headwise4<<<BS_, 256, 0, stream>>>(xc, k_w, k_b, kb, 1024, 1024);
  k_headwise4<<<BS_, 256, 0, stream>>>(up, v_w, v_b, up, 2048, 2048);   // v in place over x_m
  k_gates<<<BS_, 256, 0, stream>>>(qb, kb, up, ig_w, ig_b, fg_w, fg_b, igv, fgv);
  k_decay<<<1, 32, 0, stream>>>(igv, fgv, av, pmv, mldv);
  k_mcell<<<dim3(S_/32, 4, 8), 256, 0, stream>>>(qb, kb, up, av, pmv, mldv, onormw, ht);
  k_hs<<<(BS_*1024)/256, 256, 0, stream>>>(xc, up, skip_w, ht);
  k_gemm<<<dim3(512/64, BS_/64), 256, 0, stream>>>(ht, m_dn_w, m_dn_b, hb, 512, 1024, 1);

  // ---- block 1: sLSTM ----
  k_ln<<<BS_, 256, 0, stream>>>(hb, ln1_w, xn);
  k_conv_silu<<<(BS_*512)/256, 256, 0, stream>>>(xn, s_cv_k, s_cv_b, xc, 512, 512, 512);
  k_headwise128<<<dim3(BS_/32, 16), 256, 0, stream>>>(xc, xn, wi, wf, wz, wo, up);
  k_sscan<<<32, 512, 0, stream>>>(up, r_kern, cell_b, ylast);

  // ---- last-token epilogue ----
  k_final<<<B_, 256, 0, stream>>>(hb, ylast, gn_w, ln2_w, ffup_w, ffup_b,
                                  ffdn_w, ffdn_b, lnf_w, fc_w, fc_b, outp);
}

// Round 4
// 4332.430 us; speedup vs baseline: 1.0184x; 1.0184x over previous
//
#include <hip/hip_runtime.h>
#include <math.h>

// ---------------- problem constants ----------------
#define B_   8
#define S_   1024
#define BS_  8192        // B*S
#define D_   512
#define IN_  1024        // INNER
#define FIN_ 75

typedef __attribute__((ext_vector_type(8))) short short8_t;   // 8 bf16 (4 VGPRs) MFMA A/B frag
typedef __attribute__((ext_vector_type(4))) float f32x4;      // MFMA C/D frag

// ---------------- workspace layout (floats) ----------------
#define OFF_H    0UL          // h residual: BS*512 f32
#define OFF_UP   4194304UL    // [x_m | z] f32 BS*2048; later reused as wx
#define OFF_XC   20971520UL   // conv outputs f32 (stride 1024 then 512)
#define OFF_Q    29360128UL   // q bf16 BS*1024 (ushort)
#define OFF_K    33554432UL   // k bf16
#define OFF_V    37748736UL   // v bf16
#define OFF_HT   41943040UL   // htil/hs f32 BS*1024; first BS*512 doubles as xn
#define OFF_XN   OFF_HT
#define OFF_IG   50331648UL
#define OFF_FG   50364416UL
#define OFF_A    50397184UL
#define OFF_PM   50429952UL
#define OFF_MLD  50462720UL
#define OFF_YL   50495488UL
// total 50,499,584 floats ~= 193 MiB

static __device__ __forceinline__ float siluf(float x){ return x / (1.0f + __expf(-x)); }
static __device__ __forceinline__ float logsigf(float x){ return fminf(x, 0.0f) - log1pf(expf(-fabsf(x))); }
static __device__ __forceinline__ float b2f(ushort h){ union { uint u; float f; } v; v.u = ((uint)h) << 16; return v.f; }
static __device__ __forceinline__ ushort f2b(float x){
  union { float f; uint u; } v; v.f = x;
  uint r = v.u + 0x7FFFu + ((v.u >> 16) & 1u);
  return (ushort)(r >> 16);
}

// ---------------- 1. input projection ----------------
__global__ __launch_bounds__(256) void k_inproj(const float* __restrict__ x,
                                                const float* __restrict__ w,
                                                const float* __restrict__ b,
                                                float* __restrict__ out){
  int row = blockIdx.x;
  int tid = threadIdx.x;
  __shared__ float xs[FIN_];
  if (tid < FIN_) xs[tid] = x[(size_t)row*FIN_ + tid];
  __syncthreads();
  #pragma unroll
  for (int rep = 0; rep < 2; ++rep){
    int n = tid + rep*256;
    const float* wr = w + (size_t)n*FIN_;
    float acc = b[n];
    #pragma unroll 5
    for (int k2 = 0; k2 < FIN_; ++k2) acc += xs[k2]*wr[k2];
    out[(size_t)row*D_ + n] = acc;
  }
}

// ---------------- 2. LayerNorm over 512 ----------------
__global__ __launch_bounds__(256) void k_ln(const float* __restrict__ in,
                                            const float* __restrict__ w,
                                            float* __restrict__ out){
  int row = blockIdx.x;
  int tid = threadIdx.x;
  const float* ip = in + (size_t)row*D_;
  float2 v = ((const float2*)ip)[tid];
  float s = v.x + v.y, ss = v.x*v.x + v.y*v.y;
  #pragma unroll
  for (int off = 32; off > 0; off >>= 1){ s += __shfl_down(s, off); ss += __shfl_down(ss, off); }
  __shared__ float rA[4], rB[4];
  int lane = tid & 63, wv = tid >> 6;
  if (lane == 0){ rA[wv] = s; rB[wv] = ss; }
  __syncthreads();
  float S = rA[0]+rA[1]+rA[2]+rA[3];
  float SS = rB[0]+rB[1]+rB[2]+rB[3];
  float mu = S * (1.0f/D_);
  float inv = rsqrtf(SS * (1.0f/D_) - mu*mu + 1e-5f);
  float2 o;
  o.x = (v.x - mu)*inv*w[2*tid];
  o.y = (v.y - mu)*inv*w[2*tid+1];
  ((float2*)(out + (size_t)row*D_))[tid] = o;
}

// ---------------- 3. generic GEMM (f32, unchanged this round) ----------------
__global__ __launch_bounds__(256) void k_gemm(const float* __restrict__ A,
                                              const float* __restrict__ W,
                                              const float* __restrict__ bias,
                                              float* __restrict__ C,
                                              int N, int K, int accum){
  __shared__ __align__(16) float sA[16][68];
  __shared__ __align__(16) float sB[16][68];
  int bm = blockIdx.y*64, bn = blockIdx.x*64;
  int tid = threadIdx.x;
  int ty = tid >> 4, tx = tid & 15;
  float acc[4][4] = {};
  for (int k0 = 0; k0 < K; k0 += 16){
    #pragma unroll
    for (int i = 0; i < 4; ++i){
      int idx = tid + i*256;
      int kk = idx & 15, m = idx >> 4;
      sA[kk][m] = A[(size_t)(bm+m)*K + k0 + kk];
      sB[kk][m] = W[(size_t)(bn+m)*K + k0 + kk];
    }
    __syncthreads();
    #pragma unroll
    for (int kk = 0; kk < 16; ++kk){
      float4 a4 = *(const float4*)&sA[kk][ty*4];
      float4 b4 = *(const float4*)&sB[kk][tx*4];
      acc[0][0] += a4.x*b4.x; acc[0][1] += a4.x*b4.y; acc[0][2] += a4.x*b4.z; acc[0][3] += a4.x*b4.w;
      acc[1][0] += a4.y*b4.x; acc[1][1] += a4.y*b4.y; acc[1][2] += a4.y*b4.z; acc[1][3] += a4.y*b4.w;
      acc[2][0] += a4.z*b4.x; acc[2][1] += a4.z*b4.y; acc[2][2] += a4.z*b4.z; acc[2][3] += a4.z*b4.w;
      acc[3][0] += a4.w*b4.x; acc[3][1] += a4.w*b4.y; acc[3][2] += a4.w*b4.z; acc[3][3] += a4.w*b4.w;
    }
    __syncthreads();
  }
  #pragma unroll
  for (int i = 0; i < 4; ++i){
    int rr = bm + ty*4 + i;
    #pragma unroll
    for (int j = 0; j < 4; ++j){
      int cc = bn + tx*4 + j;
      float vv = acc[i][j] + bias[cc];
      size_t off = (size_t)rr*N + cc;
      if (accum) vv += C[off];
      C[off] = vv;
    }
  }
}

// ---------------- 4. depthwise causal conv (K=4) + SiLU ----------------
__global__ __launch_bounds__(256) void k_conv_silu(const float* __restrict__ in,
                                                   const float* __restrict__ kern,
                                                   const float* __restrict__ bias,
                                                   float* __restrict__ out,
                                                   int C, int istride, int ostride){
  size_t idx = (size_t)blockIdx.x*256 + threadIdx.x;
  int c = (int)(idx % C);
  size_t rs = idx / C;
  int s = (int)(rs & 1023);
  int b = (int)(rs >> 10);
  const float* ip = in + ((size_t)b*S_)*istride + c;
  float acc = bias[c];
  #pragma unroll
  for (int j = 0; j < 4; ++j){
    int sp = s - 3 + j;
    if (sp >= 0) acc += ip[(size_t)sp*istride] * kern[j*C + c];
  }
  out[((size_t)b*S_ + s)*ostride + c] = siluf(acc);
}

// ---------------- 5. 4x4 block-diagonal -> bf16 output ----------------
__global__ __launch_bounds__(256) void k_headwise4b(const float* __restrict__ in,
                                                    const float* __restrict__ w,
                                                    const float* __restrict__ bias,
                                                    ushort* __restrict__ out,
                                                    int istride){
  int row = blockIdx.x;
  int ph = threadIdx.x;
  float4 iv = *(const float4*)&in[(size_t)row*istride + ph*4];
  const float* wp = w + ph*16;
  float o0 = bias[ph*4+0] + wp[0] *iv.x + wp[1] *iv.y + wp[2] *iv.z + wp[3] *iv.w;
  float o1 = bias[ph*4+1] + wp[4] *iv.x + wp[5] *iv.y + wp[6] *iv.z + wp[7] *iv.w;
  float o2 = bias[ph*4+2] + wp[8] *iv.x + wp[9] *iv.y + wp[10]*iv.z + wp[11]*iv.w;
  float o3 = bias[ph*4+3] + wp[12]*iv.x + wp[13]*iv.y + wp[14]*iv.z + wp[15]*iv.w;
  ushort4 ov = { f2b(o0), f2b(o1), f2b(o2), f2b(o3) };
  *(ushort4*)&out[(size_t)row*1024 + ph*4] = ov;
}

// ---------------- 6. mLSTM i/f gate projections (bf16 inputs) ----------------
__global__ __launch_bounds__(256) void k_gates(const ushort* __restrict__ q,
                                               const ushort* __restrict__ k,
                                               const ushort* __restrict__ v,
                                               const float* __restrict__ igw,
                                               const float* __restrict__ igb,
                                               const float* __restrict__ fgw,
                                               const float* __restrict__ fgb,
                                               float* __restrict__ ig,
                                               float* __restrict__ fg){
  int row = blockIdx.x, tid = threadIdx.x;
  float pi0=0,pi1=0,pi2=0,pi3=0, pf0=0,pf1=0,pf2=0,pf3=0;
  for (int c = tid; c < 3072; c += 256){
    float xv;
    if (c < 1024)      xv = b2f(q[(size_t)row*1024 + c]);
    else if (c < 2048) xv = b2f(k[(size_t)row*1024 + c - 1024]);
    else               xv = b2f(v[(size_t)row*1024 + c - 2048]);
    pi0 += igw[c]*xv;        pf0 += fgw[c]*xv;
    pi1 += igw[3072+c]*xv;   pf1 += fgw[3072+c]*xv;
    pi2 += igw[6144+c]*xv;   pf2 += fgw[6144+c]*xv;
    pi3 += igw[9216+c]*xv;   pf3 += fgw[9216+c]*xv;
  }
  #pragma unroll
  for (int off = 32; off > 0; off >>= 1){
    pi0 += __shfl_down(pi0,off); pi1 += __shfl_down(pi1,off);
    pi2 += __shfl_down(pi2,off); pi3 += __shfl_down(pi3,off);
    pf0 += __shfl_down(pf0,off); pf1 += __shfl_down(pf1,off);
    pf2 += __shfl_down(pf2,off); pf3 += __shfl_down(pf3,off);
  }
  __shared__ float red[8][4];
  int lane = tid & 63, wv = tid >> 6;
  if (lane == 0){
    red[0][wv]=pi0; red[1][wv]=pi1; red[2][wv]=pi2; red[3][wv]=pi3;
    red[4][wv]=pf0; red[5][wv]=pf1; red[6][wv]=pf2; red[7][wv]=pf3;
  }
  __syncthreads();
  if (tid < 8){
    float sv = red[tid][0]+red[tid][1]+red[tid][2]+red[tid][3];
    int b2 = row >> 10, s2 = row & 1023;
    if (tid < 4) ig[((size_t)(b2*4 + tid))*S_ + s2] = sv + igb[tid];
    else         fg[((size_t)(b2*4 + (tid-4)))*S_ + s2] = sv + fgb[tid-4];
  }
}

// ---------------- 7. per-(b,h) decay scans ----------------
__global__ void k_decay(const float* __restrict__ ig, const float* __restrict__ fg,
                        float* __restrict__ a, float* __restrict__ pm, float* __restrict__ mld){
  int bh = threadIdx.x;
  if (bh >= 32) return;
  const float* igp = ig + (size_t)bh*S_;
  const float* fgp = fg + (size_t)bh*S_;
  float cum = 0.0f, pmax = -INFINITY;
  for (int t = 0; t < S_; ++t){
    cum += logsigf(fgp[t]);
    float av = igp[t] - cum;
    pmax = fmaxf(pmax, av);
    a[(size_t)bh*S_ + t]   = av;
    pm[(size_t)bh*S_ + t]  = pmax;
    mld[(size_t)bh*S_ + t] = cum + pmax;
  }
}

// ---------------- 8. mLSTM cell via bf16 MFMA ----------------
// scores = Q.K^T (mfma, no transpose needed); w = score/16*exp(a[t]-pm[s]) masked;
// H = W.V via mfma with V staged transposed in LDS. Per-head LN epilogue.
// LDS ~57KB -> 2 blocks/CU. XOR swizzle (chunk ^= row&7) on qs/ks; 80B-row pad on vst/wlds.
__global__ __launch_bounds__(256, 2) void k_mcell(const ushort* __restrict__ qg,
                                                  const ushort* __restrict__ kg,
                                                  const ushort* __restrict__ vg,
                                                  const float* __restrict__ aarr,
                                                  const float* __restrict__ pmarr,
                                                  const float* __restrict__ mldarr,
                                                  const float* __restrict__ onw,
                                                  float* __restrict__ htil){
  int sb = blockIdx.x, hh = blockIdx.y, bb = blockIdx.z;
  int tid = threadIdx.x;
  __shared__ ushort qs[32*256];    // 16KB, swizzled bf16
  __shared__ ushort ks[32*256];    // 16KB, swizzled bf16
  __shared__ ushort vst[256*40];   // 20KB, V transposed [d][t], 80B rows
  __shared__ ushort wlds[32*40];   // 2.5KB, weights [qr][t], 80B rows
  __shared__ float asld[32], pmld[32], mldld[32];
  __shared__ float denred[2][32], smred[2][32], sqred[2][32];
  int s0 = sb*32, bh = bb*4 + hh;
  int lane = tid & 63, wid = tid >> 6;
  int ln15 = lane & 15, hi = lane >> 4;
  int mt = wid >> 1, nt = wid & 1;

  // stage Q once (swizzled)
  {
    int lr = tid >> 3, lc = tid & 7;
    const ushort* qrow = qg + ((size_t)(bb*S_ + s0 + lr))*IN_ + hh*256 + lc*32;
    int rbase = lr*512, xr = (lr & 7) << 4;
    #pragma unroll
    for (int i = 0; i < 4; ++i){
      short8_t v8 = *(const short8_t*)(qrow + i*8);
      *(short8_t*)((char*)qs + rbase + ((lc*64 + i*16) ^ xr)) = v8;
    }
  }
  if (tid < 32){
    pmld[tid]  = pmarr[(size_t)bh*S_ + s0 + tid];
    mldld[tid] = mldarr[(size_t)bh*S_ + s0 + tid];
  }

  f32x4 pv[8];
  #pragma unroll
  for (int q = 0; q < 8; ++q) pv[q] = (f32x4){0.f,0.f,0.f,0.f};
  float den_acc[4] = {0.f,0.f,0.f,0.f};

  for (int tt = 0; tt <= sb; ++tt){
    int t0 = tt*32;
    __syncthreads();                                // protect LDS from prev readers
    // stage K (swizzled)
    {
      int lr = tid >> 3, lc = tid & 7;
      const ushort* krow = kg + ((size_t)(bb*S_ + t0 + lr))*IN_ + hh*256 + lc*32;
      int rbase = lr*512, xr = (lr & 7) << 4;
      #pragma unroll
      for (int i = 0; i < 4; ++i){
        short8_t v8 = *(const short8_t*)(krow + i*8);
        *(short8_t*)((char*)ks + rbase + ((lc*64 + i*16) ^ xr)) = v8;
      }
    }
    // stage V transposed: thread (dd=tid>>4 -> 16 d's, tt2=tid&15 -> t pair)
    {
      int dd = tid >> 4, tt2 = tid & 15;
      const ushort* v0r = vg + ((size_t)(bb*S_ + t0 + 2*tt2))*IN_ + hh*256 + dd*16;
      const ushort* v1r = v0r + IN_;
      short8_t va0 = *(const short8_t*)(v0r);
      short8_t va1 = *(const short8_t*)(v0r + 8);
      short8_t vb0 = *(const short8_t*)(v1r);
      short8_t vb1 = *(const short8_t*)(v1r + 8);
      #pragma unroll
      for (int j = 0; j < 8; ++j){
        uint p0 = (uint)(ushort)va0[j] | ((uint)(ushort)vb0[j] << 16);
        *(uint*)((char*)vst + (dd*16 + j)*80 + tt2*4) = p0;
        uint p1 = (uint)(ushort)va1[j] | ((uint)(ushort)vb1[j] << 16);
        *(uint*)((char*)vst + (dd*16 + 8 + j)*80 + tt2*4) = p1;
      }
    }
    if (tid < 32) asld[tid] = aarr[(size_t)bh*S_ + t0 + tid];
    __syncthreads();                                // staged data ready
    // phase A: 16x16 score quadrant per wave (mt rows, nt cols), K=256
    f32x4 sc = (f32x4){0.f,0.f,0.f,0.f};
    int rA = mt*16 + ln15, rB = nt*16 + ln15;
    int xA = (rA & 7) << 4, xB = (rB & 7) << 4;
    #pragma unroll
    for (int st = 0; st < 8; ++st){
      int cb = st*64 + hi*16;
      short8_t af = *(const short8_t*)((const char*)qs + rA*512 + (cb ^ xA));
      short8_t bf = *(const short8_t*)((const char*)ks + rB*512 + (cb ^ xB));
      sc = __builtin_amdgcn_mfma_f32_16x16x32_bf16(af, bf, sc, 0, 0, 0);
    }
    float av = asld[nt*16 + ln15];
    int tg = t0 + nt*16 + ln15;
    #pragma unroll
    for (int rg = 0; rg < 4; ++rg){
      int qr = mt*16 + hi*4 + rg;
      float wv = (tg <= s0 + qr) ? sc[rg]*0.0625f*__expf(av - pmld[qr]) : 0.0f;
      den_acc[rg] += wv;
      *((ushort*)((char*)wlds + qr*80 + (nt*16 + ln15)*2)) = f2b(wv);
    }
    __syncthreads();                                // wlds ready
    // phase B: H quadrant += W.V ; wave covers rows mt*16..+15, dims nt*128..+127
    short8_t aw = *(const short8_t*)((const char*)wlds + (mt*16 + ln15)*80 + hi*16);
    #pragma unroll
    for (int q = 0; q < 8; ++q){
      int dr = (nt*8 + q)*16 + ln15;
      short8_t bv = *(const short8_t*)((const char*)vst + dr*80 + hi*16);
      pv[q] = __builtin_amdgcn_mfma_f32_16x16x32_bf16(aw, bv, pv[q], 0, 0, 0);
    }
  }
  // ---- epilogue: normalizer + per-head LN ----
  #pragma unroll
  for (int rg = 0; rg < 4; ++rg){
    float d = den_acc[rg];
    d += __shfl_xor(d, 1); d += __shfl_xor(d, 2);
    d += __shfl_xor(d, 4); d += __shfl_xor(d, 8);
    if (ln15 == 0) denred[nt][mt*16 + hi*4 + rg] = d;
  }
  __syncthreads();
  float invr[4], s1[4], s2[4];
  #pragma unroll
  for (int rg = 0; rg < 4; ++rg){
    int qr = mt*16 + hi*4 + rg;
    float den = denred[0][qr] + denred[1][qr];
    invr[rg] = 1.0f / (fmaxf(fabsf(den), __expf(-mldld[qr])) + 1e-6f);
    float a1 = 0.f, a2 = 0.f;
    #pragma unroll
    for (int q = 0; q < 8; ++q){ float hv = pv[q][rg]; a1 += hv; a2 += hv*hv; }
    a1 += __shfl_xor(a1, 1); a1 += __shfl_xor(a1, 2); a1 += __shfl_xor(a1, 4); a1 += __shfl_xor(a1, 8);
    a2 += __shfl_xor(a2, 1); a2 += __shfl_xor(a2, 2); a2 += __shfl_xor(a2, 4); a2 += __shfl_xor(a2, 8);
    if (ln15 == 0){ smred[nt][qr] = a1; sqred[nt][qr] = a2; }
  }
  __syncthreads();
  const float* onp = onw + hh*256;
  #pragma unroll
  for (int rg = 0; rg < 4; ++rg){
    int qr = mt*16 + hi*4 + rg;
    float iv = invr[rg];
    float Sm = (smred[0][qr] + smred[1][qr]) * iv * (1.0f/256.0f);
    float Sq = (sqred[0][qr] + sqred[1][qr]) * iv * iv * (1.0f/256.0f);
    float lninv = rsqrtf(Sq - Sm*Sm + 1e-5f);
    float* orow = htil + ((size_t)(bb*S_ + s0 + qr))*IN_ + hh*256;
    #pragma unroll
    for (int q = 0; q < 8; ++q){
      int d = (nt*8 + q)*16 + ln15;
      float hv = pv[q][rg]*iv;
      orow[d] = (hv - Sm)*lninv*onp[d];
    }
  }
}

// ---------------- 9. hs = (htil + skip*xc) * silu(z) ----------------
__global__ __launch_bounds__(256) void k_hs(const float* __restrict__ xc,
                                            const float* __restrict__ up,
                                            const float* __restrict__ skw,
                                            float* __restrict__ ht){
  size_t idx = (size_t)blockIdx.x*256 + threadIdx.x;
  int c = (int)(idx & 1023);
  size_t row = idx >> 10;
  float z = up[row*2048 + 1024 + c];
  ht[idx] = (ht[idx] + skw[c]*xc[idx]) * siluf(z);
}

// ---------------- 10. 128x128 block-diagonal gate projections -> wx ----------------
__global__ __launch_bounds__(256) void k_headwise128(const float* __restrict__ xc,
                                                     const float* __restrict__ xn,
                                                     const float* __restrict__ wi,
                                                     const float* __restrict__ wf,
                                                     const float* __restrict__ wz,
                                                     const float* __restrict__ wo,
                                                     float* __restrict__ wx){
  int mt = blockIdx.x, slice = blockIdx.y;
  int gate = slice >> 2, hh = slice & 3;
  const float* in = (gate < 2) ? xc : xn;
  const float* wmat = (gate==0 ? wi : gate==1 ? wf : gate==2 ? wz : wo) + (size_t)hh*16384;
  __shared__ __align__(16) float ins[32][132];
  __shared__ __align__(16) float wsl[128][132];
  int tid = threadIdx.x, m0 = mt*32;
  #pragma unroll
  for (int i = 0; i < 4; ++i){
    int idx = tid + i*256;
    int rr = idx >> 5, c4 = (idx & 31)*4;
    *(float4*)&ins[rr][c4] = *(const float4*)&in[(size_t)(m0+rr)*512 + hh*128 + c4];
  }
  #pragma unroll
  for (int i = 0; i < 16; ++i){
    int idx = tid + i*256;
    int o = idx >> 5, d4 = (idx & 31)*4;
    *(float4*)&wsl[o][d4] = *(const float4*)&wmat[(size_t)o*128 + d4];
  }
  __syncthreads();
  int rg = tid >> 4, cg = tid & 15;
  float acc[2][8] = {};
  for (int k4 = 0; k4 < 32; ++k4){
    float4 a0 = *(const float4*)&ins[rg*2+0][k4*4];
    float4 a1 = *(const float4*)&ins[rg*2+1][k4*4];
    #pragma unroll
    for (int j = 0; j < 8; ++j){
      float4 w4 = *(const float4*)&wsl[cg*8+j][k4*4];
      acc[0][j] += a0.x*w4.x + a0.y*w4.y + a0.z*w4.z + a0.w*w4.w;
      acc[1][j] += a1.x*w4.x + a1.y*w4.y + a1.z*w4.z + a1.w*w4.w;
    }
  }
  #pragma unroll
  for (int r2 = 0; r2 < 2; ++r2){
    float* op = wx + (size_t)(m0 + rg*2 + r2)*2048 + gate*512 + hh*128 + cg*8;
    float4 o0 = { acc[r2][0], acc[r2][1], acc[r2][2], acc[r2][3] };
    float4 o1 = { acc[r2][4], acc[r2][5], acc[r2][6], acc[r2][7] };
    *(float4*)&op[0] = o0;
    *(float4*)&op[4] = o1;
  }
}

// ---------------- 11. sequential sLSTM scan ----------------
#define DOT4(acc, R4, Y4) acc += (R4).x*(Y4).x + (R4).y*(Y4).y + (R4).z*(Y4).z + (R4).w*(Y4).w
__global__ __launch_bounds__(512) void k_sscan(const float* __restrict__ wx,
                                               const float* __restrict__ R,
                                               const float* __restrict__ cb,
                                               float* __restrict__ ylast){
  int bb = blockIdx.x >> 2, hh = blockIdx.x & 3;
  int tid = threadIdx.x;
  int gate = tid >> 7, d = tid & 127;
  __shared__ __align__(16) float ys[128];
  __shared__ float raws[512];
  float4 Rr[32];
  const float* rrow = R + ((size_t)hh*512 + tid)*128;
  #pragma unroll
  for (int i = 0; i < 32; ++i) Rr[i] = ((const float4*)rrow)[i];
  float bias = cb[gate*512 + hh*128 + d];
  float c = 0, n = 0, m = 0;
  if (tid < 128) ys[tid] = 0.0f;
  __syncthreads();
  const float* wxb = wx + (size_t)bb*S_*2048 + gate*512 + hh*128 + d;
  float wcur = wxb[0];
  for (int t = 0; t < S_; ++t){
    float wnext = (t+1 < S_) ? wxb[(size_t)(t+1)*2048] : 0.0f;  // prefetch (hides HBM under matvec)
    const float4* yp = (const float4*)ys;
    float a0=0,a1=0,a2=0,a3=0,a4=0,a5=0,a6=0,a7=0;              // 8 accs break the dep chain
    #pragma unroll
    for (int i = 0; i < 4; ++i){
      float4 y;
      y = yp[i];      DOT4(a0, Rr[i],      y);
      y = yp[4+i];    DOT4(a1, Rr[4+i],    y);
      y = yp[8+i];    DOT4(a2, Rr[8+i],    y);
      y = yp[12+i];   DOT4(a3, Rr[12+i],   y);
      y = yp[16+i];   DOT4(a4, Rr[16+i],   y);
      y = yp[20+i];   DOT4(a5, Rr[20+i],   y);
      y = yp[24+i];   DOT4(a6, Rr[24+i],   y);
      y = yp[28+i];   DOT4(a7, Rr[28+i],   y);
    }
    float ry = ((a0+a1)+(a2+a3)) + ((a4+a5)+(a6+a7));
    raws[tid] = wcur + ry + bias;
    __syncthreads();
    if (tid < 128){
      float ir = raws[d], fr = raws[128+d], zr = raws[256+d], og = raws[384+d];
      float lfm = m + fminf(fr, 0.0f) - log1pf(__expf(-fabsf(fr)));
      float mnew = (n == 0.0f) ? ir : fmaxf(ir, lfm);
      float igate = __expf(ir - mnew);
      float fgate = __expf(lfm - mnew);
      float zc = fminf(fmaxf(zr, -15.0f), 15.0f);
      float e2 = __expf(2.0f*zc);
      c = fgate*c + igate*((e2 - 1.0f)/(e2 + 1.0f));
      n = fgate*n + igate;
      m = mnew;
      float yv = c / (n*(1.0f + __expf(-og)));
      ys[d] = yv;
      if (t == S_-1) ylast[(size_t)bb*512 + hh*128 + d] = yv;
    }
    __syncthreads();
    wcur = wnext;
  }
}

// ---------------- 12. last-token epilogue ----------------
__global__ __launch_bounds__(256) void k_final(const float* __restrict__ h,
                                               const float* __restrict__ ylast,
                                               const float* __restrict__ gnw,
                                               const float* __restrict__ ln2w,
                                               const float* __restrict__ upw,
                                               const float* __restrict__ upb,
                                               const float* __restrict__ dnw,
                                               const float* __restrict__ dnb,
                                               const float* __restrict__ lnfw,
                                               const float* __restrict__ fcw,
                                               const float* __restrict__ fcb,
                                               float* __restrict__ out){
  int b = blockIdx.x, tid = threadIdx.x;
  __shared__ __align__(16) float hb[512];
  __shared__ __align__(16) float xb[512];
  __shared__ __align__(16) float ff[1408];
  __shared__ __align__(16) float act[704];
  __shared__ float rA[4], rB[4], hstat[4][2];
  int lane = tid & 63, wv = tid >> 6;
  float y0 = ylast[(size_t)b*512 + wv*128 + lane];
  float y1 = ylast[(size_t)b*512 + wv*128 + 64 + lane];
  {
    float s = y0 + y1, ss = y0*y0 + y1*y1;
    #pragma unroll
    for (int off = 32; off > 0; off >>= 1){ s += __shfl_down(s, off); ss += __shfl_down(ss, off); }
    if (lane == 0){ hstat[wv][0] = s*(1.0f/128.0f); hstat[wv][1] = ss*(1.0f/128.0f); }
  }
  __syncthreads();
  {
    float mu = hstat[wv][0];
    float inv = rsqrtf(hstat[wv][1] - mu*mu + 1e-5f);
    int d0 = wv*128 + lane, d1 = d0 + 64;
    const float* hrow = h + ((size_t)(b*S_ + S_-1))*512;
    hb[d0] = hrow[d0] + (y0 - mu)*inv*gnw[d0];
    hb[d1] = hrow[d1] + (y1 - mu)*inv*gnw[d1];
  }
  __syncthreads();
  {
    float v0 = hb[tid], v1 = hb[tid+256];
    float s = v0+v1, ss = v0*v0+v1*v1;
    #pragma unroll
    for (int off = 32; off > 0; off >>= 1){ s += __shfl_down(s, off); ss += __shfl_down(ss, off); }
    if (lane == 0){ rA[wv] = s; rB[wv] = ss; }
    __syncthreads();
    float S = rA[0]+rA[1]+rA[2]+rA[3], SS = rB[0]+rB[1]+rB[2]+rB[3];
    float mu = S*(1.0f/512.0f);
    float inv = rsqrtf(SS*(1.0f/512.0f) - mu*mu + 1e-5f);
    xb[tid]     = (v0 - mu)*inv*ln2w[tid];
    xb[tid+256] = (v1 - mu)*inv*ln2w[tid+256];
  }
  __syncthreads();
  for (int o = tid; o < 1408; o += 256){
    const float4* wr = (const float4*)(upw + (size_t)o*512);
    float acc = upb[o];
    for (int k4 = 0; k4 < 128; ++k4){
      float4 w4 = wr[k4]; float4 x4 = ((const float4*)xb)[k4];
      acc += w4.x*x4.x + w4.y*x4.y + w4.z*x4.z + w4.w*x4.w;
    }
    ff[o] = acc;
  }
  __syncthreads();
  for (int j = tid; j < 704; j += 256){
    float g = ff[j];
    act[j] = 0.5f*g*(1.0f + erff(g*0.70710678118654752f)) * ff[704+j];
  }
  __syncthreads();
  for (int d2 = tid; d2 < 512; d2 += 256){
    const float4* wr = (const float4*)(dnw + (size_t)d2*704);
    float acc = dnb[d2];
    for (int k4 = 0; k4 < 176; ++k4){
      float4 w4 = wr[k4]; float4 a4 = ((const float4*)act)[k4];
      acc += w4.x*a4.x + w4.y*a4.y + w4.z*a4.z + w4.w*a4.w;
    }
    hb[d2] += acc;
  }
  __syncthreads();
  {
    float v0 = hb[tid], v1 = hb[tid+256];
    float s = v0+v1, ss = v0*v0+v1*v1;
    #pragma unroll
    for (int off = 32; off > 0; off >>= 1){ s += __shfl_down(s, off); ss += __shfl_down(ss, off); }
    if (lane == 0){ rA[wv] = s; rB[wv] = ss; }
    __syncthreads();
    float S = rA[0]+rA[1]+rA[2]+rA[3], SS = rB[0]+rB[1]+rB[2]+rB[3];
    float mu = S*(1.0f/512.0f);
    float inv = rsqrtf(SS*(1.0f/512.0f) - mu*mu + 1e-5f);
    xb[tid]     = (v0 - mu)*inv*lnfw[tid];
    xb[tid+256] = (v1 - mu)*inv*lnfw[tid+256];
  }
  __syncthreads();
  {
    float val = xb[tid]*fcw[tid] + xb[tid+256]*fcw[tid+256];
    #pragma unroll
    for (int off = 32; off > 0; off >>= 1) val += __shfl_down(val, off);
    if (lane == 0) rA[wv] = val;
    __syncthreads();
    if (tid == 0) out[b] = rA[0]+rA[1]+rA[2]+rA[3] + fcb[0];
  }
}

// ---------------- launch ----------------
extern "C" void kernel_launch(void* const* d_in, const int* in_sizes, int n_in,
                              void* d_out, int out_size, void* d_ws, size_t ws_size,
                              hipStream_t stream) {
  const float* x      = (const float*)d_in[0];
  const float* w_in   = (const float*)d_in[1];
  const float* b_in   = (const float*)d_in[2];
  const float* ln0_w  = (const float*)d_in[3];
  const float* m_up_w = (const float*)d_in[4];
  const float* m_up_b = (const float*)d_in[5];
  const float* m_cv_k = (const float*)d_in[6];
  const float* m_cv_b = (const float*)d_in[7];
  const float* q_w    = (const float*)d_in[8];
  const float* q_b    = (const float*)d_in[9];
  const float* k_w    = (const float*)d_in[10];
  const float* k_b    = (const float*)d_in[11];
  const float* v_w    = (const float*)d_in[12];
  const float* v_b    = (const float*)d_in[13];
  const float* ig_w   = (const float*)d_in[14];
  const float* ig_b   = (const float*)d_in[15];
  const float* fg_w   = (const float*)d_in[16];
  const float* fg_b   = (const float*)d_in[17];
  const float* onormw = (const float*)d_in[18];
  const float* skip_w = (const float*)d_in[19];
  const float* m_dn_w = (const float*)d_in[20];
  const float* m_dn_b = (const float*)d_in[21];
  const float* ln1_w  = (const float*)d_in[22];
  const float* s_cv_k = (const float*)d_in[23];
  const float* s_cv_b = (const float*)d_in[24];
  const float* wi     = (const float*)d_in[25];
  const float* wf     = (const float*)d_in[26];
  const float* wz     = (const float*)d_in[27];
  const float* wo     = (const float*)d_in[28];
  const float* r_kern = (const float*)d_in[29];
  const float* cell_b = (const float*)d_in[30];
  const float* gn_w   = (const float*)d_in[31];
  const float* ln2_w  = (const float*)d_in[32];
  const float* ffup_w = (const float*)d_in[33];
  const float* ffup_b = (const float*)d_in[34];
  const float* ffdn_w = (const float*)d_in[35];
  const float* ffdn_b = (const float*)d_in[36];
  const float* lnf_w  = (const float*)d_in[37];
  const float* fc_w   = (const float*)d_in[38];
  const float* fc_b   = (const float*)d_in[39];

  float* ws   = (float*)d_ws;
  float* hb   = ws + OFF_H;
  float* up   = ws + OFF_UP;
  float* xc   = ws + OFF_XC;
  ushort* qbu = (ushort*)(ws + OFF_Q);
  ushort* kbu = (ushort*)(ws + OFF_K);
  ushort* vbu = (ushort*)(ws + OFF_V);
  float* ht   = ws + OFF_HT;
  float* xn   = ws + OFF_XN;
  float* igv  = ws + OFF_IG;
  float* fgv  = ws + OFF_FG;
  float* av   = ws + OFF_A;
  float* pmv  = ws + OFF_PM;
  float* mldv = ws + OFF_MLD;
  float* ylast= ws + OFF_YL;
  float* outp = (float*)d_out;

  // ---- block 0: mLSTM ----
  k_inproj<<<BS_, 256, 0, stream>>>(x, w_in, b_in, hb);
  k_ln<<<BS_, 256, 0, stream>>>(hb, ln0_w, xn);
  k_gemm<<<dim3(2048/64, BS_/64), 256, 0, stream>>>(xn, m_up_w, m_up_b, up, 2048, 512, 0);
  k_conv_silu<<<(BS_*1024)/256, 256, 0, stream>>>(up, m_cv_k, m_cv_b, xc, 1024, 2048, 1024);
  k_headwise4b<<<BS_, 256, 0, stream>>>(xc, q_w, q_b, qbu, 1024);
  k_headwise4b<<<BS_, 256, 0, stream>>>(xc, k_w, k_b, kbu, 1024);
  k_headwise4b<<<BS_, 256, 0, stream>>>(up, v_w, v_b, vbu, 2048);
  k_gates<<<BS_, 256, 0, stream>>>(qbu, kbu, vbu, ig_w, ig_b, fg_w, fg_b, igv, fgv);
  k_decay<<<1, 32, 0, stream>>>(igv, fgv, av, pmv, mldv);
  k_mcell<<<dim3(S_/32, 4, 8), 256, 0, stream>>>(qbu, kbu, vbu, av, pmv, mldv, onormw, ht);
  k_hs<<<(BS_*1024)/256, 256, 0, stream>>>(xc, up, skip_w, ht);
  k_gemm<<<dim3(512/64, BS_/64), 256, 0, stream>>>(ht, m_dn_w, m_dn_b, hb, 512, 1024, 1);

  // ---- block 1: sLSTM ----
  k_ln<<<BS_, 256, 0, stream>>>(hb, ln1_w, xn);
  k_conv_silu<<<(BS_*512)/256, 256, 0, stream>>>(xn, s_cv_k, s_cv_b, xc, 512, 512, 512);
  k_headwise128<<<dim3(BS_/32, 16), 256, 0, stream>>>(xc, xn, wi, wf, wz, wo, up);
  k_sscan<<<32, 512, 0, stream>>>(up, r_kern, cell_b, ylast);

  // ---- last-token epilogue ----
  k_final<<<B_, 256, 0, stream>>>(hb, ylast, gn_w, ln2_w, ffup_w, ffup_b,
                                  ffdn_w, ffdn_b, lnf_w, fc_w, fc_b, outp);
}

// Round 5
// 3725.119 us; speedup vs baseline: 1.1845x; 1.1630x over previous
//
#include <hip/hip_runtime.h>
#include <math.h>

// ---------------- problem constants ----------------
#define B_   8
#define S_   1024
#define BS_  8192        // B*S
#define D_   512
#define IN_  1024        // INNER
#define FIN_ 75

typedef __attribute__((ext_vector_type(8))) short short8_t;   // 8 bf16 (4 VGPRs) MFMA A/B frag
typedef __attribute__((ext_vector_type(4))) float f32x4;      // MFMA C/D frag

// ---------------- workspace layout (floats) ----------------
#define OFF_H    0UL          // h residual: BS*512 f32
#define OFF_UP   4194304UL    // [x_m | z] f32 BS*2048; later reused as wx
#define OFF_XC   20971520UL   // conv outputs f32 (stride 1024 then 512)
#define OFF_Q    29360128UL   // q bf16 BS*1024 (ushort)
#define OFF_K    33554432UL   // k bf16
#define OFF_V    37748736UL   // v bf16
#define OFF_HT   41943040UL   // htil/hs f32 BS*1024; first BS*512 doubles as xn
#define OFF_XN   OFF_HT
#define OFF_IG   50331648UL
#define OFF_FG   50364416UL
#define OFF_A    50397184UL
#define OFF_PM   50429952UL
#define OFF_MLD  50462720UL
#define OFF_YL   50495488UL
// total 50,499,584 floats ~= 193 MiB

static __device__ __forceinline__ float siluf(float x){ return x / (1.0f + __expf(-x)); }
static __device__ __forceinline__ float logsigf(float x){ return fminf(x, 0.0f) - log1pf(expf(-fabsf(x))); }
static __device__ __forceinline__ float b2f(ushort h){ union { uint u; float f; } v; v.u = ((uint)h) << 16; return v.f; }
static __device__ __forceinline__ ushort f2b(float x){
  union { float f; uint u; } v; v.f = x;
  uint r = v.u + 0x7FFFu + ((v.u >> 16) & 1u);
  return (ushort)(r >> 16);
}

// ---------------- 1. input projection ----------------
__global__ __launch_bounds__(256) void k_inproj(const float* __restrict__ x,
                                                const float* __restrict__ w,
                                                const float* __restrict__ b,
                                                float* __restrict__ out){
  int row = blockIdx.x;
  int tid = threadIdx.x;
  __shared__ float xs[FIN_];
  if (tid < FIN_) xs[tid] = x[(size_t)row*FIN_ + tid];
  __syncthreads();
  #pragma unroll
  for (int rep = 0; rep < 2; ++rep){
    int n = tid + rep*256;
    const float* wr = w + (size_t)n*FIN_;
    float acc = b[n];
    #pragma unroll 5
    for (int k2 = 0; k2 < FIN_; ++k2) acc += xs[k2]*wr[k2];
    out[(size_t)row*D_ + n] = acc;
  }
}

// ---------------- 2. LayerNorm over 512 ----------------
__global__ __launch_bounds__(256) void k_ln(const float* __restrict__ in,
                                            const float* __restrict__ w,
                                            float* __restrict__ out){
  int row = blockIdx.x;
  int tid = threadIdx.x;
  const float* ip = in + (size_t)row*D_;
  float2 v = ((const float2*)ip)[tid];
  float s = v.x + v.y, ss = v.x*v.x + v.y*v.y;
  #pragma unroll
  for (int off = 32; off > 0; off >>= 1){ s += __shfl_down(s, off); ss += __shfl_down(ss, off); }
  __shared__ float rA[4], rB[4];
  int lane = tid & 63, wv = tid >> 6;
  if (lane == 0){ rA[wv] = s; rB[wv] = ss; }
  __syncthreads();
  float S = rA[0]+rA[1]+rA[2]+rA[3];
  float SS = rB[0]+rB[1]+rB[2]+rB[3];
  float mu = S * (1.0f/D_);
  float inv = rsqrtf(SS * (1.0f/D_) - mu*mu + 1e-5f);
  float2 o;
  o.x = (v.x - mu)*inv*w[2*tid];
  o.y = (v.y - mu)*inv*w[2*tid+1];
  ((float2*)(out + (size_t)row*D_))[tid] = o;
}

// ---------------- 3. generic GEMM (f32) ----------------
__global__ __launch_bounds__(256) void k_gemm(const float* __restrict__ A,
                                              const float* __restrict__ W,
                                              const float* __restrict__ bias,
                                              float* __restrict__ C,
                                              int N, int K, int accum){
  __shared__ __align__(16) float sA[16][68];
  __shared__ __align__(16) float sB[16][68];
  int bm = blockIdx.y*64, bn = blockIdx.x*64;
  int tid = threadIdx.x;
  int ty = tid >> 4, tx = tid & 15;
  float acc[4][4] = {};
  for (int k0 = 0; k0 < K; k0 += 16){
    #pragma unroll
    for (int i = 0; i < 4; ++i){
      int idx = tid + i*256;
      int kk = idx & 15, m = idx >> 4;
      sA[kk][m] = A[(size_t)(bm+m)*K + k0 + kk];
      sB[kk][m] = W[(size_t)(bn+m)*K + k0 + kk];
    }
    __syncthreads();
    #pragma unroll
    for (int kk = 0; kk < 16; ++kk){
      float4 a4 = *(const float4*)&sA[kk][ty*4];
      float4 b4 = *(const float4*)&sB[kk][tx*4];
      acc[0][0] += a4.x*b4.x; acc[0][1] += a4.x*b4.y; acc[0][2] += a4.x*b4.z; acc[0][3] += a4.x*b4.w;
      acc[1][0] += a4.y*b4.x; acc[1][1] += a4.y*b4.y; acc[1][2] += a4.y*b4.z; acc[1][3] += a4.y*b4.w;
      acc[2][0] += a4.z*b4.x; acc[2][1] += a4.z*b4.y; acc[2][2] += a4.z*b4.z; acc[2][3] += a4.z*b4.w;
      acc[3][0] += a4.w*b4.x; acc[3][1] += a4.w*b4.y; acc[3][2] += a4.w*b4.z; acc[3][3] += a4.w*b4.w;
    }
    __syncthreads();
  }
  #pragma unroll
  for (int i = 0; i < 4; ++i){
    int rr = bm + ty*4 + i;
    #pragma unroll
    for (int j = 0; j < 4; ++j){
      int cc = bn + tx*4 + j;
      float vv = acc[i][j] + bias[cc];
      size_t off = (size_t)rr*N + cc;
      if (accum) vv += C[off];
      C[off] = vv;
    }
  }
}

// ---------------- 4. depthwise causal conv (K=4) + SiLU ----------------
__global__ __launch_bounds__(256) void k_conv_silu(const float* __restrict__ in,
                                                   const float* __restrict__ kern,
                                                   const float* __restrict__ bias,
                                                   float* __restrict__ out,
                                                   int C, int istride, int ostride){
  size_t idx = (size_t)blockIdx.x*256 + threadIdx.x;
  int c = (int)(idx % C);
  size_t rs = idx / C;
  int s = (int)(rs & 1023);
  int b = (int)(rs >> 10);
  const float* ip = in + ((size_t)b*S_)*istride + c;
  float acc = bias[c];
  #pragma unroll
  for (int j = 0; j < 4; ++j){
    int sp = s - 3 + j;
    if (sp >= 0) acc += ip[(size_t)sp*istride] * kern[j*C + c];
  }
  out[((size_t)b*S_ + s)*ostride + c] = siluf(acc);
}

// ---------------- 5. 4x4 block-diagonal -> bf16 output ----------------
__global__ __launch_bounds__(256) void k_headwise4b(const float* __restrict__ in,
                                                    const float* __restrict__ w,
                                                    const float* __restrict__ bias,
                                                    ushort* __restrict__ out,
                                                    int istride){
  int row = blockIdx.x;
  int ph = threadIdx.x;
  float4 iv = *(const float4*)&in[(size_t)row*istride + ph*4];
  const float* wp = w + ph*16;
  float o0 = bias[ph*4+0] + wp[0] *iv.x + wp[1] *iv.y + wp[2] *iv.z + wp[3] *iv.w;
  float o1 = bias[ph*4+1] + wp[4] *iv.x + wp[5] *iv.y + wp[6] *iv.z + wp[7] *iv.w;
  float o2 = bias[ph*4+2] + wp[8] *iv.x + wp[9] *iv.y + wp[10]*iv.z + wp[11]*iv.w;
  float o3 = bias[ph*4+3] + wp[12]*iv.x + wp[13]*iv.y + wp[14]*iv.z + wp[15]*iv.w;
  ushort4 ov = { f2b(o0), f2b(o1), f2b(o2), f2b(o3) };
  *(ushort4*)&out[(size_t)row*1024 + ph*4] = ov;
}

// ---------------- 6. mLSTM i/f gate projections (bf16 inputs) ----------------
__global__ __launch_bounds__(256) void k_gates(const ushort* __restrict__ q,
                                               const ushort* __restrict__ k,
                                               const ushort* __restrict__ v,
                                               const float* __restrict__ igw,
                                               const float* __restrict__ igb,
                                               const float* __restrict__ fgw,
                                               const float* __restrict__ fgb,
                                               float* __restrict__ ig,
                                               float* __restrict__ fg){
  int row = blockIdx.x, tid = threadIdx.x;
  float pi0=0,pi1=0,pi2=0,pi3=0, pf0=0,pf1=0,pf2=0,pf3=0;
  for (int c = tid; c < 3072; c += 256){
    float xv;
    if (c < 1024)      xv = b2f(q[(size_t)row*1024 + c]);
    else if (c < 2048) xv = b2f(k[(size_t)row*1024 + c - 1024]);
    else               xv = b2f(v[(size_t)row*1024 + c - 2048]);
    pi0 += igw[c]*xv;        pf0 += fgw[c]*xv;
    pi1 += igw[3072+c]*xv;   pf1 += fgw[3072+c]*xv;
    pi2 += igw[6144+c]*xv;   pf2 += fgw[6144+c]*xv;
    pi3 += igw[9216+c]*xv;   pf3 += fgw[9216+c]*xv;
  }
  #pragma unroll
  for (int off = 32; off > 0; off >>= 1){
    pi0 += __shfl_down(pi0,off); pi1 += __shfl_down(pi1,off);
    pi2 += __shfl_down(pi2,off); pi3 += __shfl_down(pi3,off);
    pf0 += __shfl_down(pf0,off); pf1 += __shfl_down(pf1,off);
    pf2 += __shfl_down(pf2,off); pf3 += __shfl_down(pf3,off);
  }
  __shared__ float red[8][4];
  int lane = tid & 63, wv = tid >> 6;
  if (lane == 0){
    red[0][wv]=pi0; red[1][wv]=pi1; red[2][wv]=pi2; red[3][wv]=pi3;
    red[4][wv]=pf0; red[5][wv]=pf1; red[6][wv]=pf2; red[7][wv]=pf3;
  }
  __syncthreads();
  if (tid < 8){
    float sv = red[tid][0]+red[tid][1]+red[tid][2]+red[tid][3];
    int b2 = row >> 10, s2 = row & 1023;
    if (tid < 4) ig[((size_t)(b2*4 + tid))*S_ + s2] = sv + igb[tid];
    else         fg[((size_t)(b2*4 + (tid-4)))*S_ + s2] = sv + fgb[tid-4];
  }
}

// ---------------- 7. per-(b,h) decay scans ----------------
__global__ void k_decay(const float* __restrict__ ig, const float* __restrict__ fg,
                        float* __restrict__ a, float* __restrict__ pm, float* __restrict__ mld){
  int bh = threadIdx.x;
  if (bh >= 32) return;
  const float* igp = ig + (size_t)bh*S_;
  const float* fgp = fg + (size_t)bh*S_;
  float cum = 0.0f, pmax = -INFINITY;
  for (int t = 0; t < S_; ++t){
    cum += logsigf(fgp[t]);
    float av = igp[t] - cum;
    pmax = fmaxf(pmax, av);
    a[(size_t)bh*S_ + t]   = av;
    pm[(size_t)bh*S_ + t]  = pmax;
    mld[(size_t)bh*S_ + t] = cum + pmax;
  }
}

// ---------------- 8. mLSTM cell via bf16 MFMA (unchanged, passing) ----------------
__global__ __launch_bounds__(256, 2) void k_mcell(const ushort* __restrict__ qg,
                                                  const ushort* __restrict__ kg,
                                                  const ushort* __restrict__ vg,
                                                  const float* __restrict__ aarr,
                                                  const float* __restrict__ pmarr,
                                                  const float* __restrict__ mldarr,
                                                  const float* __restrict__ onw,
                                                  float* __restrict__ htil){
  int sb = blockIdx.x, hh = blockIdx.y, bb = blockIdx.z;
  int tid = threadIdx.x;
  __shared__ ushort qs[32*256];    // 16KB, swizzled bf16
  __shared__ ushort ks[32*256];    // 16KB, swizzled bf16
  __shared__ ushort vst[256*40];   // 20KB, V transposed [d][t], 80B rows
  __shared__ ushort wlds[32*40];   // 2.5KB, weights [qr][t], 80B rows
  __shared__ float asld[32], pmld[32], mldld[32];
  __shared__ float denred[2][32], smred[2][32], sqred[2][32];
  int s0 = sb*32, bh = bb*4 + hh;
  int lane = tid & 63, wid = tid >> 6;
  int ln15 = lane & 15, hi = lane >> 4;
  int mt = wid >> 1, nt = wid & 1;

  {
    int lr = tid >> 3, lc = tid & 7;
    const ushort* qrow = qg + ((size_t)(bb*S_ + s0 + lr))*IN_ + hh*256 + lc*32;
    int rbase = lr*512, xr = (lr & 7) << 4;
    #pragma unroll
    for (int i = 0; i < 4; ++i){
      short8_t v8 = *(const short8_t*)(qrow + i*8);
      *(short8_t*)((char*)qs + rbase + ((lc*64 + i*16) ^ xr)) = v8;
    }
  }
  if (tid < 32){
    pmld[tid]  = pmarr[(size_t)bh*S_ + s0 + tid];
    mldld[tid] = mldarr[(size_t)bh*S_ + s0 + tid];
  }

  f32x4 pv[8];
  #pragma unroll
  for (int q = 0; q < 8; ++q) pv[q] = (f32x4){0.f,0.f,0.f,0.f};
  float den_acc[4] = {0.f,0.f,0.f,0.f};

  for (int tt = 0; tt <= sb; ++tt){
    int t0 = tt*32;
    __syncthreads();
    {
      int lr = tid >> 3, lc = tid & 7;
      const ushort* krow = kg + ((size_t)(bb*S_ + t0 + lr))*IN_ + hh*256 + lc*32;
      int rbase = lr*512, xr = (lr & 7) << 4;
      #pragma unroll
      for (int i = 0; i < 4; ++i){
        short8_t v8 = *(const short8_t*)(krow + i*8);
        *(short8_t*)((char*)ks + rbase + ((lc*64 + i*16) ^ xr)) = v8;
      }
    }
    {
      int dd = tid >> 4, tt2 = tid & 15;
      const ushort* v0r = vg + ((size_t)(bb*S_ + t0 + 2*tt2))*IN_ + hh*256 + dd*16;
      const ushort* v1r = v0r + IN_;
      short8_t va0 = *(const short8_t*)(v0r);
      short8_t va1 = *(const short8_t*)(v0r + 8);
      short8_t vb0 = *(const short8_t*)(v1r);
      short8_t vb1 = *(const short8_t*)(v1r + 8);
      #pragma unroll
      for (int j = 0; j < 8; ++j){
        uint p0 = (uint)(ushort)va0[j] | ((uint)(ushort)vb0[j] << 16);
        *(uint*)((char*)vst + (dd*16 + j)*80 + tt2*4) = p0;
        uint p1 = (uint)(ushort)va1[j] | ((uint)(ushort)vb1[j] << 16);
        *(uint*)((char*)vst + (dd*16 + 8 + j)*80 + tt2*4) = p1;
      }
    }
    if (tid < 32) asld[tid] = aarr[(size_t)bh*S_ + t0 + tid];
    __syncthreads();
    f32x4 sc = (f32x4){0.f,0.f,0.f,0.f};
    int rA = mt*16 + ln15, rB = nt*16 + ln15;
    int xA = (rA & 7) << 4, xB = (rB & 7) << 4;
    #pragma unroll
    for (int st = 0; st < 8; ++st){
      int cb = st*64 + hi*16;
      short8_t af = *(const short8_t*)((const char*)qs + rA*512 + (cb ^ xA));
      short8_t bf = *(const short8_t*)((const char*)ks + rB*512 + (cb ^ xB));
      sc = __builtin_amdgcn_mfma_f32_16x16x32_bf16(af, bf, sc, 0, 0, 0);
    }
    float av = asld[nt*16 + ln15];
    int tg = t0 + nt*16 + ln15;
    #pragma unroll
    for (int rg = 0; rg < 4; ++rg){
      int qr = mt*16 + hi*4 + rg;
      float wv = (tg <= s0 + qr) ? sc[rg]*0.0625f*__expf(av - pmld[qr]) : 0.0f;
      den_acc[rg] += wv;
      *((ushort*)((char*)wlds + qr*80 + (nt*16 + ln15)*2)) = f2b(wv);
    }
    __syncthreads();
    short8_t aw = *(const short8_t*)((const char*)wlds + (mt*16 + ln15)*80 + hi*16);
    #pragma unroll
    for (int q = 0; q < 8; ++q){
      int dr = (nt*8 + q)*16 + ln15;
      short8_t bv = *(const short8_t*)((const char*)vst + dr*80 + hi*16);
      pv[q] = __builtin_amdgcn_mfma_f32_16x16x32_bf16(aw, bv, pv[q], 0, 0, 0);
    }
  }
  #pragma unroll
  for (int rg = 0; rg < 4; ++rg){
    float d = den_acc[rg];
    d += __shfl_xor(d, 1); d += __shfl_xor(d, 2);
    d += __shfl_xor(d, 4); d += __shfl_xor(d, 8);
    if (ln15 == 0) denred[nt][mt*16 + hi*4 + rg] = d;
  }
  __syncthreads();
  float invr[4];
  #pragma unroll
  for (int rg = 0; rg < 4; ++rg){
    int qr = mt*16 + hi*4 + rg;
    float den = denred[0][qr] + denred[1][qr];
    invr[rg] = 1.0f / (fmaxf(fabsf(den), __expf(-mldld[qr])) + 1e-6f);
    float a1 = 0.f, a2 = 0.f;
    #pragma unroll
    for (int q = 0; q < 8; ++q){ float hv = pv[q][rg]; a1 += hv; a2 += hv*hv; }
    a1 += __shfl_xor(a1, 1); a1 += __shfl_xor(a1, 2); a1 += __shfl_xor(a1, 4); a1 += __shfl_xor(a1, 8);
    a2 += __shfl_xor(a2, 1); a2 += __shfl_xor(a2, 2); a2 += __shfl_xor(a2, 4); a2 += __shfl_xor(a2, 8);
    if (ln15 == 0){ smred[nt][qr] = a1; sqred[nt][qr] = a2; }
  }
  __syncthreads();
  const float* onp = onw + hh*256;
  #pragma unroll
  for (int rg = 0; rg < 4; ++rg){
    int qr = mt*16 + hi*4 + rg;
    float iv = invr[rg];
    float Sm = (smred[0][qr] + smred[1][qr]) * iv * (1.0f/256.0f);
    float Sq = (sqred[0][qr] + sqred[1][qr]) * iv * iv * (1.0f/256.0f);
    float lninv = rsqrtf(Sq - Sm*Sm + 1e-5f);
    float* orow = htil + ((size_t)(bb*S_ + s0 + qr))*IN_ + hh*256;
    #pragma unroll
    for (int q = 0; q < 8; ++q){
      int d = (nt*8 + q)*16 + ln15;
      float hv = pv[q][rg]*iv;
      orow[d] = (hv - Sm)*lninv*onp[d];
    }
  }
}

// ---------------- 9. hs = (htil + skip*xc) * silu(z) ----------------
__global__ __launch_bounds__(256) void k_hs(const float* __restrict__ xc,
                                            const float* __restrict__ up,
                                            const float* __restrict__ skw,
                                            float* __restrict__ ht){
  size_t idx = (size_t)blockIdx.x*256 + threadIdx.x;
  int c = (int)(idx & 1023);
  size_t row = idx >> 10;
  float z = up[row*2048 + 1024 + c];
  ht[idx] = (ht[idx] + skw[c]*xc[idx]) * siluf(z);
}

// ---------------- 10. 128x128 block-diagonal gate projections -> wx ----------------
__global__ __launch_bounds__(256) void k_headwise128(const float* __restrict__ xc,
                                                     const float* __restrict__ xn,
                                                     const float* __restrict__ wi,
                                                     const float* __restrict__ wf,
                                                     const float* __restrict__ wz,
                                                     const float* __restrict__ wo,
                                                     float* __restrict__ wx){
  int mt = blockIdx.x, slice = blockIdx.y;
  int gate = slice >> 2, hh = slice & 3;
  const float* in = (gate < 2) ? xc : xn;
  const float* wmat = (gate==0 ? wi : gate==1 ? wf : gate==2 ? wz : wo) + (size_t)hh*16384;
  __shared__ __align__(16) float ins[32][132];
  __shared__ __align__(16) float wsl[128][132];
  int tid = threadIdx.x, m0 = mt*32;
  #pragma unroll
  for (int i = 0; i < 4; ++i){
    int idx = tid + i*256;
    int rr = idx >> 5, c4 = (idx & 31)*4;
    *(float4*)&ins[rr][c4] = *(const float4*)&in[(size_t)(m0+rr)*512 + hh*128 + c4];
  }
  #pragma unroll
  for (int i = 0; i < 16; ++i){
    int idx = tid + i*256;
    int o = idx >> 5, d4 = (idx & 31)*4;
    *(float4*)&wsl[o][d4] = *(const float4*)&wmat[(size_t)o*128 + d4];
  }
  __syncthreads();
  int rg = tid >> 4, cg = tid & 15;
  float acc[2][8] = {};
  for (int k4 = 0; k4 < 32; ++k4){
    float4 a0 = *(const float4*)&ins[rg*2+0][k4*4];
    float4 a1 = *(const float4*)&ins[rg*2+1][k4*4];
    #pragma unroll
    for (int j = 0; j < 8; ++j){
      float4 w4 = *(const float4*)&wsl[cg*8+j][k4*4];
      acc[0][j] += a0.x*w4.x + a0.y*w4.y + a0.z*w4.z + a0.w*w4.w;
      acc[1][j] += a1.x*w4.x + a1.y*w4.y + a1.z*w4.z + a1.w*w4.w;
    }
  }
  #pragma unroll
  for (int r2 = 0; r2 < 2; ++r2){
    float* op = wx + (size_t)(m0 + rg*2 + r2)*2048 + gate*512 + hh*128 + cg*8;
    float4 o0 = { acc[r2][0], acc[r2][1], acc[r2][2], acc[r2][3] };
    float4 o1 = { acc[r2][4], acc[r2][5], acc[r2][6], acc[r2][7] };
    *(float4*)&op[0] = o0;
    *(float4*)&op[4] = o1;
  }
}

// ---------------- 11. sLSTM scan: 1 block/head, R held as MFMA B-frags in registers ----------------
// raw[b][n] = sum_k y[b][k]*R[n][k] via mfma_f32_16x16x32_bf16 (M=16 rows, b<8 valid).
// Wave wid owns n in [wid*64,(wid+1)*64): 4 tiles x 4 ksteps = 16 B-frags = 64 VGPR (no spill).
// y kept bf16 in 4KB swizzled LDS; wx prefetched 1 step ahead into regs (hidden under MFMA).
__global__ __launch_bounds__(512) void k_sscan(const float* __restrict__ wx,
                                               const float* __restrict__ R,
                                               const float* __restrict__ cb,
                                               float* __restrict__ ylast){
  int hh = blockIdx.x;
  int tid = threadIdx.x;
  int lane = tid & 63, wid = tid >> 6;
  int ln15 = lane & 15, hi = lane >> 4;
  __shared__ __align__(16) ushort y_lds[16*128];   // [b][d] bf16, XOR-swizzled, rows 8..15 zero pad
  __shared__ float raws[8][512];

  // prologue: R slice -> B-frags (once)
  short8_t Rf[4][4];
  #pragma unroll
  for (int tile = 0; tile < 4; ++tile){
    int n = wid*64 + tile*16 + ln15;
    #pragma unroll
    for (int ks = 0; ks < 4; ++ks){
      const float* rr = R + ((size_t)hh*512 + n)*128 + ks*32 + hi*8;
      short8_t f;
      #pragma unroll
      for (int j = 0; j < 8; ++j) f[j] = (short)f2b(rr[j]);
      Rf[tile][ks] = f;
    }
  }
  for (int i = tid; i < 2048; i += 512) ((uint*)y_lds)[i] = 0u;

  // gate-thread mapping: pairs (b0,d0)=(tid>>7, tid&127), (b1,d1)=(b0+4, d0)
  int b0 = tid >> 7, d0 = tid & 127;
  int b1 = b0 + 4;
  size_t wbase0 = ((size_t)(b0*1024))*2048 + hh*128 + d0;
  size_t wbase1 = ((size_t)(b1*1024))*2048 + hh*128 + d0;
  float bias0[4], bias1[4];
  #pragma unroll
  for (int g = 0; g < 4; ++g){
    bias0[g] = cb[g*512 + hh*128 + d0];
    bias1[g] = cb[g*512 + hh*128 + d0];
  }
  float c0=0,nn0=0,m0=0, c1=0,nn1=0,m1=0;
  float wcur[8], wnext[8];
  #pragma unroll
  for (int g = 0; g < 4; ++g){
    wcur[g]   = wx[wbase0 + (size_t)g*512];
    wcur[4+g] = wx[wbase1 + (size_t)g*512];
  }
  int swz0 = (b0 & 7) << 4, swz1 = (b1 & 7) << 4;
  __syncthreads();

  for (int t = 0; t < S_; ++t){
    int tp = (t+1 < S_) ? t+1 : t;
    #pragma unroll
    for (int g = 0; g < 4; ++g){
      wnext[g]   = wx[wbase0 + (size_t)tp*2048 + (size_t)g*512];
      wnext[4+g] = wx[wbase1 + (size_t)tp*2048 + (size_t)g*512];
    }
    // MFMA phase: A-frags from y_lds (swizzled, conflict-free)
    short8_t a[4];
    #pragma unroll
    for (int ks = 0; ks < 4; ++ks){
      int byt = (ks*64 + hi*16) ^ ((ln15 & 7) << 4);
      a[ks] = *(const short8_t*)((const char*)y_lds + ln15*256 + byt);
    }
    #pragma unroll
    for (int tile = 0; tile < 4; ++tile){
      f32x4 acc = (f32x4){0.f,0.f,0.f,0.f};
      #pragma unroll
      for (int ks = 0; ks < 4; ++ks)
        acc = __builtin_amdgcn_mfma_f32_16x16x32_bf16(a[ks], Rf[tile][ks], acc, 0, 0, 0);
      if (hi < 2){
        int nn = wid*64 + tile*16 + ln15;
        #pragma unroll
        for (int r = 0; r < 4; ++r) raws[hi*4 + r][nn] = acc[r];
      }
    }
    __syncthreads();
    // gate phase (pair 0)
    {
      float ir = raws[b0][d0]     + wcur[0] + bias0[0];
      float fr = raws[b0][128+d0] + wcur[1] + bias0[1];
      float zr = raws[b0][256+d0] + wcur[2] + bias0[2];
      float og = raws[b0][384+d0] + wcur[3] + bias0[3];
      float lfm = m0 + fminf(fr, 0.0f) - log1pf(__expf(-fabsf(fr)));
      float mnew = (nn0 == 0.0f) ? ir : fmaxf(ir, lfm);
      float igt = __expf(ir - mnew), fgt = __expf(lfm - mnew);
      float zc = fminf(fmaxf(zr, -15.0f), 15.0f);
      float e2 = __expf(2.0f*zc);
      c0 = fgt*c0 + igt*((e2-1.0f)/(e2+1.0f));
      nn0 = fgt*nn0 + igt; m0 = mnew;
      float yv = c0 / (nn0*(1.0f + __expf(-og)));
      *(ushort*)((char*)y_lds + b0*256 + ((d0*2) ^ swz0)) = f2b(yv);
      if (t == S_-1) ylast[(size_t)b0*512 + hh*128 + d0] = yv;
    }
    // gate phase (pair 1)
    {
      float ir = raws[b1][d0]     + wcur[4] + bias1[0];
      float fr = raws[b1][128+d0] + wcur[5] + bias1[1];
      float zr = raws[b1][256+d0] + wcur[6] + bias1[2];
      float og = raws[b1][384+d0] + wcur[7] + bias1[3];
      float lfm = m1 + fminf(fr, 0.0f) - log1pf(__expf(-fabsf(fr)));
      float mnew = (nn1 == 0.0f) ? ir : fmaxf(ir, lfm);
      float igt = __expf(ir - mnew), fgt = __expf(lfm - mnew);
      float zc = fminf(fmaxf(zr, -15.0f), 15.0f);
      float e2 = __expf(2.0f*zc);
      c1 = fgt*c1 + igt*((e2-1.0f)/(e2+1.0f));
      nn1 = fgt*nn1 + igt; m1 = mnew;
      float yv = c1 / (nn1*(1.0f + __expf(-og)));
      *(ushort*)((char*)y_lds + b1*256 + ((d0*2) ^ swz1)) = f2b(yv);
      if (t == S_-1) ylast[(size_t)b1*512 + hh*128 + d0] = yv;
    }
    __syncthreads();
    #pragma unroll
    for (int g = 0; g < 8; ++g) wcur[g] = wnext[g];
  }
}

// ---------------- 12. last-token epilogue ----------------
__global__ __launch_bounds__(256) void k_final(const float* __restrict__ h,
                                               const float* __restrict__ ylast,
                                               const float* __restrict__ gnw,
                                               const float* __restrict__ ln2w,
                                               const float* __restrict__ upw,
                                               const float* __restrict__ upb,
                                               const float* __restrict__ dnw,
                                               const float* __restrict__ dnb,
                                               const float* __restrict__ lnfw,
                                               const float* __restrict__ fcw,
                                               const float* __restrict__ fcb,
                                               float* __restrict__ out){
  int b = blockIdx.x, tid = threadIdx.x;
  __shared__ __align__(16) float hb[512];
  __shared__ __align__(16) float xb[512];
  __shared__ __align__(16) float ff[1408];
  __shared__ __align__(16) float act[704];
  __shared__ float rA[4], rB[4], hstat[4][2];
  int lane = tid & 63, wv = tid >> 6;
  float y0 = ylast[(size_t)b*512 + wv*128 + lane];
  float y1 = ylast[(size_t)b*512 + wv*128 + 64 + lane];
  {
    float s = y0 + y1, ss = y0*y0 + y1*y1;
    #pragma unroll
    for (int off = 32; off > 0; off >>= 1){ s += __shfl_down(s, off); ss += __shfl_down(ss, off); }
    if (lane == 0){ hstat[wv][0] = s*(1.0f/128.0f); hstat[wv][1] = ss*(1.0f/128.0f); }
  }
  __syncthreads();
  {
    float mu = hstat[wv][0];
    float inv = rsqrtf(hstat[wv][1] - mu*mu + 1e-5f);
    int d0 = wv*128 + lane, d1 = d0 + 64;
    const float* hrow = h + ((size_t)(b*S_ + S_-1))*512;
    hb[d0] = hrow[d0] + (y0 - mu)*inv*gnw[d0];
    hb[d1] = hrow[d1] + (y1 - mu)*inv*gnw[d1];
  }
  __syncthreads();
  {
    float v0 = hb[tid], v1 = hb[tid+256];
    float s = v0+v1, ss = v0*v0+v1*v1;
    #pragma unroll
    for (int off = 32; off > 0; off >>= 1){ s += __shfl_down(s, off); ss += __shfl_down(ss, off); }
    if (lane == 0){ rA[wv] = s; rB[wv] = ss; }
    __syncthreads();
    float S = rA[0]+rA[1]+rA[2]+rA[3], SS = rB[0]+rB[1]+rB[2]+rB[3];
    float mu = S*(1.0f/512.0f);
    float inv = rsqrtf(SS*(1.0f/512.0f) - mu*mu + 1e-5f);
    xb[tid]     = (v0 - mu)*inv*ln2w[tid];
    xb[tid+256] = (v1 - mu)*inv*ln2w[tid+256];
  }
  __syncthreads();
  for (int o = tid; o < 1408; o += 256){
    const float4* wr = (const float4*)(upw + (size_t)o*512);
    float acc = upb[o];
    for (int k4 = 0; k4 < 128; ++k4){
      float4 w4 = wr[k4]; float4 x4 = ((const float4*)xb)[k4];
      acc += w4.x*x4.x + w4.y*x4.y + w4.z*x4.z + w4.w*x4.w;
    }
    ff[o] = acc;
  }
  __syncthreads();
  for (int j = tid; j < 704; j += 256){
    float g = ff[j];
    act[j] = 0.5f*g*(1.0f + erff(g*0.70710678118654752f)) * ff[704+j];
  }
  __syncthreads();
  for (int d2 = tid; d2 < 512; d2 += 256){
    const float4* wr = (const float4*)(dnw + (size_t)d2*704);
    float acc = dnb[d2];
    for (int k4 = 0; k4 < 176; ++k4){
      float4 w4 = wr[k4]; float4 a4 = ((const float4*)act)[k4];
      acc += w4.x*a4.x + w4.y*a4.y + w4.z*a4.z + w4.w*a4.w;
    }
    hb[d2] += acc;
  }
  __syncthreads();
  {
    float v0 = hb[tid], v1 = hb[tid+256];
    float s = v0+v1, ss = v0*v0+v1*v1;
    #pragma unroll
    for (int off = 32; off > 0; off >>= 1){ s += __shfl_down(s, off); ss += __shfl_down(ss, off); }
    if (lane == 0){ rA[wv] = s; rB[wv] = ss; }
    __syncthreads();
    float S = rA[0]+rA[1]+rA[2]+rA[3], SS = rB[0]+rB[1]+rB[2]+rB[3];
    float mu = S*(1.0f/512.0f);
    float inv = rsqrtf(SS*(1.0f/512.0f) - mu*mu + 1e-5f);
    xb[tid]     = (v0 - mu)*inv*lnfw[tid];
    xb[tid+256] = (v1 - mu)*inv*lnfw[tid+256];
  }
  __syncthreads();
  {
    float val = xb[tid]*fcw[tid] + xb[tid+256]*fcw[tid+256];
    #pragma unroll
    for (int off = 32; off > 0; off >>= 1) val += __shfl_down(val, off);
    if (lane == 0) rA[wv] = val;
    __syncthreads();
    if (tid == 0) out[b] = rA[0]+rA[1]+rA[2]+rA[3] + fcb[0];
  }
}

// ---------------- launch ----------------
extern "C" void kernel_launch(void* const* d_in, const int* in_sizes, int n_in,
                              void* d_out, int out_size, void* d_ws, size_t ws_size,
                              hipStream_t stream) {
  const float* x      = (const float*)d_in[0];
  const float* w_in   = (const float*)d_in[1];
  const float* b_in   = (const float*)d_in[2];
  const float* ln0_w  = (const float*)d_in[3];
  const float* m_up_w = (const float*)d_in[4];
  const float* m_up_b = (const float*)d_in[5];
  const float* m_cv_k = (const float*)d_in[6];
  const float* m_cv_b = (const float*)d_in[7];
  const float* q_w    = (const float*)d_in[8];
  const float* q_b    = (const float*)d_in[9];
  const float* k_w    = (const float*)d_in[10];
  const float* k_b    = (const float*)d_in[11];
  const float* v_w    = (const float*)d_in[12];
  const float* v_b    = (const float*)d_in[13];
  const float* ig_w   = (const float*)d_in[14];
  const float* ig_b   = (const float*)d_in[15];
  const float* fg_w   = (const float*)d_in[16];
  const float* fg_b   = (const float*)d_in[17];
  const float* onormw = (const float*)d_in[18];
  const float* skip_w = (const float*)d_in[19];
  const float* m_dn_w = (const float*)d_in[20];
  const float* m_dn_b = (const float*)d_in[21];
  const float* ln1_w  = (const float*)d_in[22];
  const float* s_cv_k = (const float*)d_in[23];
  const float* s_cv_b = (const float*)d_in[24];
  const float* wi     = (const float*)d_in[25];
  const float* wf     = (const float*)d_in[26];
  const float* wz     = (const float*)d_in[27];
  const float* wo     = (const float*)d_in[28];
  const float* r_kern = (const float*)d_in[29];
  const float* cell_b = (const float*)d_in[30];
  const float* gn_w   = (const float*)d_in[31];
  const float* ln2_w  = (const float*)d_in[32];
  const float* ffup_w = (const float*)d_in[33];
  const float* ffup_b = (const float*)d_in[34];
  const float* ffdn_w = (const float*)d_in[35];
  const float* ffdn_b = (const float*)d_in[36];
  const float* lnf_w  = (const float*)d_in[37];
  const float* fc_w   = (const float*)d_in[38];
  const float* fc_b   = (const float*)d_in[39];

  float* ws   = (float*)d_ws;
  float* hb   = ws + OFF_H;
  float* up   = ws + OFF_UP;
  float* xc   = ws + OFF_XC;
  ushort* qbu = (ushort*)(ws + OFF_Q);
  ushort* kbu = (ushort*)(ws + OFF_K);
  ushort* vbu = (ushort*)(ws + OFF_V);
  float* ht   = ws + OFF_HT;
  float* xn   = ws + OFF_XN;
  float* igv  = ws + OFF_IG;
  float* fgv  = ws + OFF_FG;
  float* av   = ws + OFF_A;
  float* pmv  = ws + OFF_PM;
  float* mldv = ws + OFF_MLD;
  float* ylast= ws + OFF_YL;
  float* outp = (float*)d_out;

  // ---- block 0: mLSTM ----
  k_inproj<<<BS_, 256, 0, stream>>>(x, w_in, b_in, hb);
  k_ln<<<BS_, 256, 0, stream>>>(hb, ln0_w, xn);
  k_gemm<<<dim3(2048/64, BS_/64), 256, 0, stream>>>(xn, m_up_w, m_up_b, up, 2048, 512, 0);
  k_conv_silu<<<(BS_*1024)/256, 256, 0, stream>>>(up, m_cv_k, m_cv_b, xc, 1024, 2048, 1024);
  k_headwise4b<<<BS_, 256, 0, stream>>>(xc, q_w, q_b, qbu, 1024);
  k_headwise4b<<<BS_, 256, 0, stream>>>(xc, k_w, k_b, kbu, 1024);
  k_headwise4b<<<BS_, 256, 0, stream>>>(up, v_w, v_b, vbu, 2048);
  k_gates<<<BS_, 256, 0, stream>>>(qbu, kbu, vbu, ig_w, ig_b, fg_w, fg_b, igv, fgv);
  k_decay<<<1, 32, 0, stream>>>(igv, fgv, av, pmv, mldv);
  k_mcell<<<dim3(S_/32, 4, 8), 256, 0, stream>>>(qbu, kbu, vbu, av, pmv, mldv, onormw, ht);
  k_hs<<<(BS_*1024)/256, 256, 0, stream>>>(xc, up, skip_w, ht);
  k_gemm<<<dim3(512/64, BS_/64), 256, 0, stream>>>(ht, m_dn_w, m_dn_b, hb, 512, 1024, 1);

  // ---- block 1: sLSTM ----
  k_ln<<<BS_, 256, 0, stream>>>(hb, ln1_w, xn);
  k_conv_silu<<<(BS_*512)/256, 256, 0, stream>>>(xn, s_cv_k, s_cv_b, xc, 512, 512, 512);
  k_headwise128<<<dim3(BS_/32, 16), 256, 0, stream>>>(xc, xn, wi, wf, wz, wo, up);
  k_sscan<<<4, 512, 0, stream>>>(up, r_kern, cell_b, ylast);

  // ---- last-token epilogue ----
  k_final<<<B_, 256, 0, stream>>>(hb, ylast, gn_w, ln2_w, ffup_w, ffup_b,
                                  ffdn_w, ffdn_b, lnf_w, fc_w, fc_b, outp);
}

// Round 8
// 2748.018 us; speedup vs baseline: 1.6056x; 1.3556x over previous
//
#include <hip/hip_runtime.h>
#include <math.h>

// ---------------- problem constants ----------------
#define B_   8
#define S_   1024
#define BS_  8192        // B*S
#define D_   512
#define IN_  1024        // INNER
#define FIN_ 75

typedef __attribute__((ext_vector_type(8))) short short8_t;   // 8 bf16 (4 VGPRs) MFMA A/B frag
typedef __attribute__((ext_vector_type(4))) float f32x4;      // MFMA C/D frag

// ---------------- workspace layout (floats) ----------------
#define OFF_H    0UL          // h residual: BS*512 f32
#define OFF_UP   4194304UL    // [x_m | z] f32 BS*2048; later reused as wx
#define OFF_XC   20971520UL   // conv outputs f32 (stride 1024 then 512)
#define OFF_Q    29360128UL   // q bf16 BS*1024 (ushort)
#define OFF_K    33554432UL   // k bf16
#define OFF_V    37748736UL   // v bf16
#define OFF_HT   41943040UL   // htil/hs f32 BS*1024; first BS*512 doubles as xn
#define OFF_XN   OFF_HT
#define OFF_IG   50331648UL
#define OFF_FG   50364416UL
#define OFF_A    50397184UL
#define OFF_PM   50429952UL
#define OFF_MLD  50462720UL
#define OFF_YL   50495488UL
// total 50,499,584 floats ~= 193 MiB

static __device__ __forceinline__ float siluf(float x){ return x / (1.0f + __expf(-x)); }
static __device__ __forceinline__ float logsigf(float x){ return fminf(x, 0.0f) - log1pf(expf(-fabsf(x))); }
static __device__ __forceinline__ float b2f(ushort h){ union { uint u; float f; } v; v.u = ((uint)h) << 16; return v.f; }
static __device__ __forceinline__ ushort f2b(float x){
  union { float f; uint u; } v; v.f = x;
  uint r = v.u + 0x7FFFu + ((v.u >> 16) & 1u);
  return (ushort)(r >> 16);
}

// ---------------- 1. input projection ----------------
__global__ __launch_bounds__(256) void k_inproj(const float* __restrict__ x,
                                                const float* __restrict__ w,
                                                const float* __restrict__ b,
                                                float* __restrict__ out){
  int row = blockIdx.x;
  int tid = threadIdx.x;
  __shared__ float xs[FIN_];
  if (tid < FIN_) xs[tid] = x[(size_t)row*FIN_ + tid];
  __syncthreads();
  #pragma unroll
  for (int rep = 0; rep < 2; ++rep){
    int n = tid + rep*256;
    const float* wr = w + (size_t)n*FIN_;
    float acc = b[n];
    #pragma unroll 5
    for (int k2 = 0; k2 < FIN_; ++k2) acc += xs[k2]*wr[k2];
    out[(size_t)row*D_ + n] = acc;
  }
}

// ---------------- 2. LayerNorm over 512 ----------------
__global__ __launch_bounds__(256) void k_ln(const float* __restrict__ in,
                                            const float* __restrict__ w,
                                            float* __restrict__ out){
  int row = blockIdx.x;
  int tid = threadIdx.x;
  const float* ip = in + (size_t)row*D_;
  float2 v = ((const float2*)ip)[tid];
  float s = v.x + v.y, ss = v.x*v.x + v.y*v.y;
  #pragma unroll
  for (int off = 32; off > 0; off >>= 1){ s += __shfl_down(s, off); ss += __shfl_down(ss, off); }
  __shared__ float rA[4], rB[4];
  int lane = tid & 63, wv = tid >> 6;
  if (lane == 0){ rA[wv] = s; rB[wv] = ss; }
  __syncthreads();
  float S = rA[0]+rA[1]+rA[2]+rA[3];
  float SS = rB[0]+rB[1]+rB[2]+rB[3];
  float mu = S * (1.0f/D_);
  float inv = rsqrtf(SS * (1.0f/D_) - mu*mu + 1e-5f);
  float2 o;
  o.x = (v.x - mu)*inv*w[2*tid];
  o.y = (v.y - mu)*inv*w[2*tid+1];
  ((float2*)(out + (size_t)row*D_))[tid] = o;
}

// ---------------- 3. generic GEMM (f32) ----------------
__global__ __launch_bounds__(256) void k_gemm(const float* __restrict__ A,
                                              const float* __restrict__ W,
                                              const float* __restrict__ bias,
                                              float* __restrict__ C,
                                              int N, int K, int accum){
  __shared__ __align__(16) float sA[16][68];
  __shared__ __align__(16) float sB[16][68];
  int bm = blockIdx.y*64, bn = blockIdx.x*64;
  int tid = threadIdx.x;
  int ty = tid >> 4, tx = tid & 15;
  float acc[4][4] = {};
  for (int k0 = 0; k0 < K; k0 += 16){
    #pragma unroll
    for (int i = 0; i < 4; ++i){
      int idx = tid + i*256;
      int kk = idx & 15, m = idx >> 4;
      sA[kk][m] = A[(size_t)(bm+m)*K + k0 + kk];
      sB[kk][m] = W[(size_t)(bn+m)*K + k0 + kk];
    }
    __syncthreads();
    #pragma unroll
    for (int kk = 0; kk < 16; ++kk){
      float4 a4 = *(const float4*)&sA[kk][ty*4];
      float4 b4 = *(const float4*)&sB[kk][tx*4];
      acc[0][0] += a4.x*b4.x; acc[0][1] += a4.x*b4.y; acc[0][2] += a4.x*b4.z; acc[0][3] += a4.x*b4.w;
      acc[1][0] += a4.y*b4.x; acc[1][1] += a4.y*b4.y; acc[1][2] += a4.y*b4.z; acc[1][3] += a4.y*b4.w;
      acc[2][0] += a4.z*b4.x; acc[2][1] += a4.z*b4.y; acc[2][2] += a4.z*b4.z; acc[2][3] += a4.z*b4.w;
      acc[3][0] += a4.w*b4.x; acc[3][1] += a4.w*b4.y; acc[3][2] += a4.w*b4.z; acc[3][3] += a4.w*b4.w;
    }
    __syncthreads();
  }
  #pragma unroll
  for (int i = 0; i < 4; ++i){
    int rr = bm + ty*4 + i;
    #pragma unroll
    for (int j = 0; j < 4; ++j){
      int cc = bn + tx*4 + j;
      float vv = acc[i][j] + bias[cc];
      size_t off = (size_t)rr*N + cc;
      if (accum) vv += C[off];
      C[off] = vv;
    }
  }
}

// ---------------- 4. depthwise causal conv (K=4) + SiLU ----------------
__global__ __launch_bounds__(256) void k_conv_silu(const float* __restrict__ in,
                                                   const float* __restrict__ kern,
                                                   const float* __restrict__ bias,
                                                   float* __restrict__ out,
                                                   int C, int istride, int ostride){
  size_t idx = (size_t)blockIdx.x*256 + threadIdx.x;
  int c = (int)(idx % C);
  size_t rs = idx / C;
  int s = (int)(rs & 1023);
  int b = (int)(rs >> 10);
  const float* ip = in + ((size_t)b*S_)*istride + c;
  float acc = bias[c];
  #pragma unroll
  for (int j = 0; j < 4; ++j){
    int sp = s - 3 + j;
    if (sp >= 0) acc += ip[(size_t)sp*istride] * kern[j*C + c];
  }
  out[((size_t)b*S_ + s)*ostride + c] = siluf(acc);
}

// ---------------- 5. 4x4 block-diagonal -> bf16 output ----------------
__global__ __launch_bounds__(256) void k_headwise4b(const float* __restrict__ in,
                                                    const float* __restrict__ w,
                                                    const float* __restrict__ bias,
                                                    ushort* __restrict__ out,
                                                    int istride){
  int row = blockIdx.x;
  int ph = threadIdx.x;
  float4 iv = *(const float4*)&in[(size_t)row*istride + ph*4];
  const float* wp = w + ph*16;
  float o0 = bias[ph*4+0] + wp[0] *iv.x + wp[1] *iv.y + wp[2] *iv.z + wp[3] *iv.w;
  float o1 = bias[ph*4+1] + wp[4] *iv.x + wp[5] *iv.y + wp[6] *iv.z + wp[7] *iv.w;
  float o2 = bias[ph*4+2] + wp[8] *iv.x + wp[9] *iv.y + wp[10]*iv.z + wp[11]*iv.w;
  float o3 = bias[ph*4+3] + wp[12]*iv.x + wp[13]*iv.y + wp[14]*iv.z + wp[15]*iv.w;
  ushort4 ov = { f2b(o0), f2b(o1), f2b(o2), f2b(o3) };
  *(ushort4*)&out[(size_t)row*1024 + ph*4] = ov;
}

// ---------------- 6. mLSTM i/f gate projections (bf16 inputs) ----------------
__global__ __launch_bounds__(256) void k_gates(const ushort* __restrict__ q,
                                               const ushort* __restrict__ k,
                                               const ushort* __restrict__ v,
                                               const float* __restrict__ igw,
                                               const float* __restrict__ igb,
                                               const float* __restrict__ fgw,
                                               const float* __restrict__ fgb,
                                               float* __restrict__ ig,
                                               float* __restrict__ fg){
  int row = blockIdx.x, tid = threadIdx.x;
  float pi0=0,pi1=0,pi2=0,pi3=0, pf0=0,pf1=0,pf2=0,pf3=0;
  for (int c = tid; c < 3072; c += 256){
    float xv;
    if (c < 1024)      xv = b2f(q[(size_t)row*1024 + c]);
    else if (c < 2048) xv = b2f(k[(size_t)row*1024 + c - 1024]);
    else               xv = b2f(v[(size_t)row*1024 + c - 2048]);
    pi0 += igw[c]*xv;        pf0 += fgw[c]*xv;
    pi1 += igw[3072+c]*xv;   pf1 += fgw[3072+c]*xv;
    pi2 += igw[6144+c]*xv;   pf2 += fgw[6144+c]*xv;
    pi3 += igw[9216+c]*xv;   pf3 += fgw[9216+c]*xv;
  }
  #pragma unroll
  for (int off = 32; off > 0; off >>= 1){
    pi0 += __shfl_down(pi0,off); pi1 += __shfl_down(pi1,off);
    pi2 += __shfl_down(pi2,off); pi3 += __shfl_down(pi3,off);
    pf0 += __shfl_down(pf0,off); pf1 += __shfl_down(pf1,off);
    pf2 += __shfl_down(pf2,off); pf3 += __shfl_down(pf3,off);
  }
  __shared__ float red[8][4];
  int lane = tid & 63, wv = tid >> 6;
  if (lane == 0){
    red[0][wv]=pi0; red[1][wv]=pi1; red[2][wv]=pi2; red[3][wv]=pi3;
    red[4][wv]=pf0; red[5][wv]=pf1; red[6][wv]=pf2; red[7][wv]=pf3;
  }
  __syncthreads();
  if (tid < 8){
    float sv = red[tid][0]+red[tid][1]+red[tid][2]+red[tid][3];
    int b2 = row >> 10, s2 = row & 1023;
    if (tid < 4) ig[((size_t)(b2*4 + tid))*S_ + s2] = sv + igb[tid];
    else         fg[((size_t)(b2*4 + (tid-4)))*S_ + s2] = sv + fgb[tid-4];
  }
}

// ---------------- 7. per-(b,h) decay scans ----------------
__global__ void k_decay(const float* __restrict__ ig, const float* __restrict__ fg,
                        float* __restrict__ a, float* __restrict__ pm, float* __restrict__ mld){
  int bh = threadIdx.x;
  if (bh >= 32) return;
  const float* igp = ig + (size_t)bh*S_;
  const float* fgp = fg + (size_t)bh*S_;
  float cum = 0.0f, pmax = -INFINITY;
  for (int t = 0; t < S_; ++t){
    cum += logsigf(fgp[t]);
    float av = igp[t] - cum;
    pmax = fmaxf(pmax, av);
    a[(size_t)bh*S_ + t]   = av;
    pm[(size_t)bh*S_ + t]  = pmax;
    mld[(size_t)bh*S_ + t] = cum + pmax;
  }
}

// ---------------- 8. mLSTM cell via bf16 MFMA (unchanged, passing) ----------------
__global__ __launch_bounds__(256, 2) void k_mcell(const ushort* __restrict__ qg,
                                                  const ushort* __restrict__ kg,
                                                  const ushort* __restrict__ vg,
                                                  const float* __restrict__ aarr,
                                                  const float* __restrict__ pmarr,
                                                  const float* __restrict__ mldarr,
                                                  const float* __restrict__ onw,
                                                  float* __restrict__ htil){
  int sb = blockIdx.x, hh = blockIdx.y, bb = blockIdx.z;
  int tid = threadIdx.x;
  __shared__ ushort qs[32*256];    // 16KB, swizzled bf16
  __shared__ ushort ks[32*256];    // 16KB, swizzled bf16
  __shared__ ushort vst[256*40];   // 20KB, V transposed [d][t], 80B rows
  __shared__ ushort wlds[32*40];   // 2.5KB, weights [qr][t], 80B rows
  __shared__ float asld[32], pmld[32], mldld[32];
  __shared__ float denred[2][32], smred[2][32], sqred[2][32];
  int s0 = sb*32, bh = bb*4 + hh;
  int lane = tid & 63, wid = tid >> 6;
  int ln15 = lane & 15, hi = lane >> 4;
  int mt = wid >> 1, nt = wid & 1;

  {
    int lr = tid >> 3, lc = tid & 7;
    const ushort* qrow = qg + ((size_t)(bb*S_ + s0 + lr))*IN_ + hh*256 + lc*32;
    int rbase = lr*512, xr = (lr & 7) << 4;
    #pragma unroll
    for (int i = 0; i < 4; ++i){
      short8_t v8 = *(const short8_t*)(qrow + i*8);
      *(short8_t*)((char*)qs + rbase + ((lc*64 + i*16) ^ xr)) = v8;
    }
  }
  if (tid < 32){
    pmld[tid]  = pmarr[(size_t)bh*S_ + s0 + tid];
    mldld[tid] = mldarr[(size_t)bh*S_ + s0 + tid];
  }

  f32x4 pv[8];
  #pragma unroll
  for (int q = 0; q < 8; ++q) pv[q] = (f32x4){0.f,0.f,0.f,0.f};
  float den_acc[4] = {0.f,0.f,0.f,0.f};

  for (int tt = 0; tt <= sb; ++tt){
    int t0 = tt*32;
    __syncthreads();
    {
      int lr = tid >> 3, lc = tid & 7;
      const ushort* krow = kg + ((size_t)(bb*S_ + t0 + lr))*IN_ + hh*256 + lc*32;
      int rbase = lr*512, xr = (lr & 7) << 4;
      #pragma unroll
      for (int i = 0; i < 4; ++i){
        short8_t v8 = *(const short8_t*)(krow + i*8);
        *(short8_t*)((char*)ks + rbase + ((lc*64 + i*16) ^ xr)) = v8;
      }
    }
    {
      int dd = tid >> 4, tt2 = tid & 15;
      const ushort* v0r = vg + ((size_t)(bb*S_ + t0 + 2*tt2))*IN_ + hh*256 + dd*16;
      const ushort* v1r = v0r + IN_;
      short8_t va0 = *(const short8_t*)(v0r);
      short8_t va1 = *(const short8_t*)(v0r + 8);
      short8_t vb0 = *(const short8_t*)(v1r);
      short8_t vb1 = *(const short8_t*)(v1r + 8);
      #pragma unroll
      for (int j = 0; j < 8; ++j){
        uint p0 = (uint)(ushort)va0[j] | ((uint)(ushort)vb0[j] << 16);
        *(uint*)((char*)vst + (dd*16 + j)*80 + tt2*4) = p0;
        uint p1 = (uint)(ushort)va1[j] | ((uint)(ushort)vb1[j] << 16);
        *(uint*)((char*)vst + (dd*16 + 8 + j)*80 + tt2*4) = p1;
      }
    }
    if (tid < 32) asld[tid] = aarr[(size_t)bh*S_ + t0 + tid];
    __syncthreads();
    f32x4 sc = (f32x4){0.f,0.f,0.f,0.f};
    int rA = mt*16 + ln15, rB = nt*16 + ln15;
    int xA = (rA & 7) << 4, xB = (rB & 7) << 4;
    #pragma unroll
    for (int st = 0; st < 8; ++st){
      int cb = st*64 + hi*16;
      short8_t af = *(const short8_t*)((const char*)qs + rA*512 + (cb ^ xA));
      short8_t bf = *(const short8_t*)((const char*)ks + rB*512 + (cb ^ xB));
      sc = __builtin_amdgcn_mfma_f32_16x16x32_bf16(af, bf, sc, 0, 0, 0);
    }
    float av = asld[nt*16 + ln15];
    int tg = t0 + nt*16 + ln15;
    #pragma unroll
    for (int rg = 0; rg < 4; ++rg){
      int qr = mt*16 + hi*4 + rg;
      float wv = (tg <= s0 + qr) ? sc[rg]*0.0625f*__expf(av - pmld[qr]) : 0.0f;
      den_acc[rg] += wv;
      *((ushort*)((char*)wlds + qr*80 + (nt*16 + ln15)*2)) = f2b(wv);
    }
    __syncthreads();
    short8_t aw = *(const short8_t*)((const char*)wlds + (mt*16 + ln15)*80 + hi*16);
    #pragma unroll
    for (int q = 0; q < 8; ++q){
      int dr = (nt*8 + q)*16 + ln15;
      short8_t bv = *(const short8_t*)((const char*)vst + dr*80 + hi*16);
      pv[q] = __builtin_amdgcn_mfma_f32_16x16x32_bf16(aw, bv, pv[q], 0, 0, 0);
    }
  }
  #pragma unroll
  for (int rg = 0; rg < 4; ++rg){
    float d = den_acc[rg];
    d += __shfl_xor(d, 1); d += __shfl_xor(d, 2);
    d += __shfl_xor(d, 4); d += __shfl_xor(d, 8);
    if (ln15 == 0) denred[nt][mt*16 + hi*4 + rg] = d;
  }
  __syncthreads();
  float invr[4];
  #pragma unroll
  for (int rg = 0; rg < 4; ++rg){
    int qr = mt*16 + hi*4 + rg;
    float den = denred[0][qr] + denred[1][qr];
    invr[rg] = 1.0f / (fmaxf(fabsf(den), __expf(-mldld[qr])) + 1e-6f);
    float a1 = 0.f, a2 = 0.f;
    #pragma unroll
    for (int q = 0; q < 8; ++q){ float hv = pv[q][rg]; a1 += hv; a2 += hv*hv; }
    a1 += __shfl_xor(a1, 1); a1 += __shfl_xor(a1, 2); a1 += __shfl_xor(a1, 4); a1 += __shfl_xor(a1, 8);
    a2 += __shfl_xor(a2, 1); a2 += __shfl_xor(a2, 2); a2 += __shfl_xor(a2, 4); a2 += __shfl_xor(a2, 8);
    if (ln15 == 0){ smred[nt][qr] = a1; sqred[nt][qr] = a2; }
  }
  __syncthreads();
  const float* onp = onw + hh*256;
  #pragma unroll
  for (int rg = 0; rg < 4; ++rg){
    int qr = mt*16 + hi*4 + rg;
    float iv = invr[rg];
    float Sm = (smred[0][qr] + smred[1][qr]) * iv * (1.0f/256.0f);
    float Sq = (sqred[0][qr] + sqred[1][qr]) * iv * iv * (1.0f/256.0f);
    float lninv = rsqrtf(Sq - Sm*Sm + 1e-5f);
    float* orow = htil + ((size_t)(bb*S_ + s0 + qr))*IN_ + hh*256;
    #pragma unroll
    for (int q = 0; q < 8; ++q){
      int d = (nt*8 + q)*16 + ln15;
      float hv = pv[q][rg]*iv;
      orow[d] = (hv - Sm)*lninv*onp[d];
    }
  }
}

// ---------------- 9. hs = (htil + skip*xc) * silu(z) ----------------
__global__ __launch_bounds__(256) void k_hs(const float* __restrict__ xc,
                                            const float* __restrict__ up,
                                            const float* __restrict__ skw,
                                            float* __restrict__ ht){
  size_t idx = (size_t)blockIdx.x*256 + threadIdx.x;
  int c = (int)(idx & 1023);
  size_t row = idx >> 10;
  float z = up[row*2048 + 1024 + c];
  ht[idx] = (ht[idx] + skw[c]*xc[idx]) * siluf(z);
}

// ---------------- 10. 128x128 block-diagonal gate projections -> wx ----------------
__global__ __launch_bounds__(256) void k_headwise128(const float* __restrict__ xc,
                                                     const float* __restrict__ xn,
                                                     const float* __restrict__ wi,
                                                     const float* __restrict__ wf,
                                                     const float* __restrict__ wz,
                                                     const float* __restrict__ wo,
                                                     float* __restrict__ wx){
  int mt = blockIdx.x, slice = blockIdx.y;
  int gate = slice >> 2, hh = slice & 3;
  const float* in = (gate < 2) ? xc : xn;
  const float* wmat = (gate==0 ? wi : gate==1 ? wf : gate==2 ? wz : wo) + (size_t)hh*16384;
  __shared__ __align__(16) float ins[32][132];
  __shared__ __align__(16) float wsl[128][132];
  int tid = threadIdx.x, m0 = mt*32;
  #pragma unroll
  for (int i = 0; i < 4; ++i){
    int idx = tid + i*256;
    int rr = idx >> 5, c4 = (idx & 31)*4;
    *(float4*)&ins[rr][c4] = *(const float4*)&in[(size_t)(m0+rr)*512 + hh*128 + c4];
  }
  #pragma unroll
  for (int i = 0; i < 16; ++i){
    int idx = tid + i*256;
    int o = idx >> 5, d4 = (idx & 31)*4;
    *(float4*)&wsl[o][d4] = *(const float4*)&wmat[(size_t)o*128 + d4];
  }
  __syncthreads();
  int rg = tid >> 4, cg = tid & 15;
  float acc[2][8] = {};
  for (int k4 = 0; k4 < 32; ++k4){
    float4 a0 = *(const float4*)&ins[rg*2+0][k4*4];
    float4 a1 = *(const float4*)&ins[rg*2+1][k4*4];
    #pragma unroll
    for (int j = 0; j < 8; ++j){
      float4 w4 = *(const float4*)&wsl[cg*8+j][k4*4];
      acc[0][j] += a0.x*w4.x + a0.y*w4.y + a0.z*w4.z + a0.w*w4.w;
      acc[1][j] += a1.x*w4.x + a1.y*w4.y + a1.z*w4.z + a1.w*w4.w;
    }
  }
  #pragma unroll
  for (int r2 = 0; r2 < 2; ++r2){
    float* op = wx + (size_t)(m0 + rg*2 + r2)*2048 + gate*512 + hh*128 + cg*8;
    float4 o0 = { acc[r2][0], acc[r2][1], acc[r2][2], acc[r2][3] };
    float4 o1 = { acc[r2][4], acc[r2][5], acc[r2][6], acc[r2][7] };
    *(float4*)&op[0] = o0;
    *(float4*)&op[4] = o1;
  }
}

// ---------------- 11. sLSTM scan: 1 block per (batch,head), 32 blocks ----------------
// raw[n] = sum_k y[k]*R[n][k] via mfma_f32_16x16x32_bf16 with broadcast-A (all 16 rows = y)
// -> any lane's acc[0] is raw[col]. R held as 16 B-frags/wave in registers (64 VGPR, no spill).
// Gate math spread 16 lanes/wave (hi==0); wx prefetched 2 steps ahead; cheap exp/log/rcp.
__global__ __launch_bounds__(512) void k_sscan(const float* __restrict__ wx,
                                               const float* __restrict__ R,
                                               const float* __restrict__ cb,
                                               float* __restrict__ ylast){
  int bb = blockIdx.x >> 2, hh = blockIdx.x & 3;
  int tid = threadIdx.x;
  int lane = tid & 63, wid = tid >> 6;
  int ln15 = lane & 15, hi = lane >> 4;
  __shared__ __align__(16) ushort y_lds[128];   // y state, bf16
  __shared__ float raws[512];                   // [gate*128 + d]

  // prologue: R slice -> B-frags (once); wave wid owns n in [wid*64, wid*64+64)
  short8_t Rf[4][4];
  #pragma unroll
  for (int tile = 0; tile < 4; ++tile){
    int n = wid*64 + tile*16 + ln15;
    #pragma unroll
    for (int ks = 0; ks < 4; ++ks){
      const float* rr = R + ((size_t)hh*512 + n)*128 + ks*32 + hi*8;
      short8_t f;
      #pragma unroll
      for (int j = 0; j < 8; ++j) f[j] = (short)f2b(rr[j]);
      Rf[tile][ks] = f;
    }
  }
  if (tid < 64) ((uint*)y_lds)[tid] = 0u;

  // gate lane: d = wid*16 + ln15 (16 lanes per wave, hi==0) -> balanced across waves
  int gd = wid*16 + ln15;
  bool gact = (hi == 0);
  size_t wbase = ((size_t)bb*1024)*2048 + (size_t)hh*128 + gd;
  float bias[4], wc[4], w1[4], wn[4];
  float cst = 0.f, nst = 0.f, mst = 0.f;
  if (gact){
    #pragma unroll
    for (int g = 0; g < 4; ++g){
      bias[g] = cb[g*512 + hh*128 + gd];
      wc[g] = wx[wbase + (size_t)g*512];              // t = 0
      w1[g] = wx[wbase + 2048 + (size_t)g*512];       // t = 1
    }
  }
  __syncthreads();

  for (int t = 0; t < S_; ++t){
    if (gact){
      size_t toff = (size_t)((t+2 < S_) ? t+2 : S_-1) * 2048;   // depth-2 prefetch
      #pragma unroll
      for (int g = 0; g < 4; ++g) wn[g] = wx[wbase + toff + (size_t)g*512];
    }
    // matvec: A = broadcast y (LDS broadcast reads, free)
    short8_t a[4];
    #pragma unroll
    for (int ks = 0; ks < 4; ++ks)
      a[ks] = *(const short8_t*)((const char*)y_lds + ks*64 + hi*16);
    #pragma unroll
    for (int tile = 0; tile < 4; ++tile){
      f32x4 acc = (f32x4){0.f,0.f,0.f,0.f};
      #pragma unroll
      for (int ks = 0; ks < 4; ++ks)
        acc = __builtin_amdgcn_mfma_f32_16x16x32_bf16(a[ks], Rf[tile][ks], acc, 0, 0, 0);
      if (hi == 0) raws[wid*64 + tile*16 + ln15] = acc[0];
    }
    __syncthreads();
    if (gact){
      float ir = raws[gd]       + wc[0] + bias[0];
      float fr = raws[128 + gd] + wc[1] + bias[1];
      float zr = raws[256 + gd] + wc[2] + bias[2];
      float og = raws[384 + gd] + wc[3] + bias[3];
      float lfm = mst + fminf(fr, 0.0f) - __logf(1.0f + __expf(-fabsf(fr)));
      float mnew = (nst == 0.0f) ? ir : fmaxf(ir, lfm);
      float igt = __expf(ir - mnew), fgt = __expf(lfm - mnew);
      float e2 = __expf(2.0f * fminf(zr, 15.0f));
      float th = (e2 - 1.0f) * __builtin_amdgcn_rcpf(e2 + 1.0f);
      cst = fgt*cst + igt*th;
      nst = fgt*nst + igt;
      mst = mnew;
      float den = nst * (1.0f + __expf(-og));
      float yv = cst * __builtin_amdgcn_rcpf(den);
      *(ushort*)((char*)y_lds + gd*2) = f2b(yv);
      if (t == S_-1) ylast[(size_t)bb*512 + hh*128 + gd] = yv;
      #pragma unroll
      for (int g = 0; g < 4; ++g){ wc[g] = w1[g]; w1[g] = wn[g]; }
    }
    __syncthreads();
  }
}

// ---------------- 12. last-token epilogue ----------------
__global__ __launch_bounds__(256) void k_final(const float* __restrict__ h,
                                               const float* __restrict__ ylast,
                                               const float* __restrict__ gnw,
                                               const float* __restrict__ ln2w,
                                               const float* __restrict__ upw,
                                               const float* __restrict__ upb,
                                               const float* __restrict__ dnw,
                                               const float* __restrict__ dnb,
                                               const float* __restrict__ lnfw,
                                               const float* __restrict__ fcw,
                                               const float* __restrict__ fcb,
                                               float* __restrict__ out){
  int b = blockIdx.x, tid = threadIdx.x;
  __shared__ __align__(16) float hb[512];
  __shared__ __align__(16) float xb[512];
  __shared__ __align__(16) float ff[1408];
  __shared__ __align__(16) float act[704];
  __shared__ float rA[4], rB[4], hstat[4][2];
  int lane = tid & 63, wv = tid >> 6;
  float y0 = ylast[(size_t)b*512 + wv*128 + lane];
  float y1 = ylast[(size_t)b*512 + wv*128 + 64 + lane];
  {
    float s = y0 + y1, ss = y0*y0 + y1*y1;
    #pragma unroll
    for (int off = 32; off > 0; off >>= 1){ s += __shfl_down(s, off); ss += __shfl_down(ss, off); }
    if (lane == 0){ hstat[wv][0] = s*(1.0f/128.0f); hstat[wv][1] = ss*(1.0f/128.0f); }
  }
  __syncthreads();
  {
    float mu = hstat[wv][0];
    float inv = rsqrtf(hstat[wv][1] - mu*mu + 1e-5f);
    int d0 = wv*128 + lane, d1 = d0 + 64;
    const float* hrow = h + ((size_t)(b*S_ + S_-1))*512;
    hb[d0] = hrow[d0] + (y0 - mu)*inv*gnw[d0];
    hb[d1] = hrow[d1] + (y1 - mu)*inv*gnw[d1];
  }
  __syncthreads();
  {
    float v0 = hb[tid], v1 = hb[tid+256];
    float s = v0+v1, ss = v0*v0+v1*v1;
    #pragma unroll
    for (int off = 32; off > 0; off >>= 1){ s += __shfl_down(s, off); ss += __shfl_down(ss, off); }
    if (lane == 0){ rA[wv] = s; rB[wv] = ss; }
    __syncthreads();
    float S = rA[0]+rA[1]+rA[2]+rA[3], SS = rB[0]+rB[1]+rB[2]+rB[3];
    float mu = S*(1.0f/512.0f);
    float inv = rsqrtf(SS*(1.0f/512.0f) - mu*mu + 1e-5f);
    xb[tid]     = (v0 - mu)*inv*ln2w[tid];
    xb[tid+256] = (v1 - mu)*inv*ln2w[tid+256];
  }
  __syncthreads();
  for (int o = tid; o < 1408; o += 256){
    const float4* wr = (const float4*)(upw + (size_t)o*512);
    float acc = upb[o];
    for (int k4 = 0; k4 < 128; ++k4){
      float4 w4 = wr[k4]; float4 x4 = ((const float4*)xb)[k4];
      acc += w4.x*x4.x + w4.y*x4.y + w4.z*x4.z + w4.w*x4.w;
    }
    ff[o] = acc;
  }
  __syncthreads();
  for (int j = tid; j < 704; j += 256){
    float g = ff[j];
    act[j] = 0.5f*g*(1.0f + erff(g*0.70710678118654752f)) * ff[704+j];
  }
  __syncthreads();
  for (int d2 = tid; d2 < 512; d2 += 256){
    const float4* wr = (const float4*)(dnw + (size_t)d2*704);
    float acc = dnb[d2];
    for (int k4 = 0; k4 < 176; ++k4){
      float4 w4 = wr[k4]; float4 a4 = ((const float4*)act)[k4];
      acc += w4.x*a4.x + w4.y*a4.y + w4.z*a4.z + w4.w*a4.w;
    }
    hb[d2] += acc;
  }
  __syncthreads();
  {
    float v0 = hb[tid], v1 = hb[tid+256];
    float s = v0+v1, ss = v0*v0+v1*v1;
    #pragma unroll
    for (int off = 32; off > 0; off >>= 1){ s += __shfl_down(s, off); ss += __shfl_down(ss, off); }
    if (lane == 0){ rA[wv] = s; rB[wv] = ss; }
    __syncthreads();
    float S = rA[0]+rA[1]+rA[2]+rA[3], SS = rB[0]+rB[1]+rB[2]+rB[3];
    float mu = S*(1.0f/512.0f);
    float inv = rsqrtf(SS*(1.0f/512.0f) - mu*mu + 1e-5f);
    xb[tid]     = (v0 - mu)*inv*lnfw[tid];
    xb[tid+256] = (v1 - mu)*inv*lnfw[tid+256];
  }
  __syncthreads();
  {
    float val = xb[tid]*fcw[tid] + xb[tid+256]*fcw[tid+256];
    #pragma unroll
    for (int off = 32; off > 0; off >>= 1) val += __shfl_down(val, off);
    if (lane == 0) rA[wv] = val;
    __syncthreads();
    if (tid == 0) out[b] = rA[0]+rA[1]+rA[2]+rA[3] + fcb[0];
  }
}

// ---------------- launch ----------------
extern "C" void kernel_launch(void* const* d_in, const int* in_sizes, int n_in,
                              void* d_out, int out_size, void* d_ws, size_t ws_size,
                              hipStream_t stream) {
  const float* x      = (const float*)d_in[0];
  const float* w_in   = (const float*)d_in[1];
  const float* b_in   = (const float*)d_in[2];
  const float* ln0_w  = (const float*)d_in[3];
  const float* m_up_w = (const float*)d_in[4];
  const float* m_up_b = (const float*)d_in[5];
  const float* m_cv_k = (const float*)d_in[6];
  const float* m_cv_b = (const float*)d_in[7];
  const float* q_w    = (const float*)d_in[8];
  const float* q_b    = (const float*)d_in[9];
  const float* k_w    = (const float*)d_in[10];
  const float* k_b    = (const float*)d_in[11];
  const float* v_w    = (const float*)d_in[12];
  const float* v_b    = (const float*)d_in[13];
  const float* ig_w   = (const float*)d_in[14];
  const float* ig_b   = (const float*)d_in[15];
  const float* fg_w   = (const float*)d_in[16];
  const float* fg_b   = (const float*)d_in[17];
  const float* onormw = (const float*)d_in[18];
  const float* skip_w = (const float*)d_in[19];
  const float* m_dn_w = (const float*)d_in[20];
  const float* m_dn_b = (const float*)d_in[21];
  const float* ln1_w  = (const float*)d_in[22];
  const float* s_cv_k = (const float*)d_in[23];
  const float* s_cv_b = (const float*)d_in[24];
  const float* wi     = (const float*)d_in[25];
  const float* wf     = (const float*)d_in[26];
  const float* wz     = (const float*)d_in[27];
  const float* wo     = (const float*)d_in[28];
  const float* r_kern = (const float*)d_in[29];
  const float* cell_b = (const float*)d_in[30];
  const float* gn_w   = (const float*)d_in[31];
  const float* ln2_w  = (const float*)d_in[32];
  const float* ffup_w = (const float*)d_in[33];
  const float* ffup_b = (const float*)d_in[34];
  const float* ffdn_w = (const float*)d_in[35];
  const float* ffdn_b = (const float*)d_in[36];
  const float* lnf_w  = (const float*)d_in[37];
  const float* fc_w   = (const float*)d_in[38];
  const float* fc_b   = (const float*)d_in[39];

  float* ws   = (float*)d_ws;
  float* hb   = ws + OFF_H;
  float* up   = ws + OFF_UP;
  float* xc   = ws + OFF_XC;
  ushort* qbu = (ushort*)(ws + OFF_Q);
  ushort* kbu = (ushort*)(ws + OFF_K);
  ushort* vbu = (ushort*)(ws + OFF_V);
  float* ht   = ws + OFF_HT;
  float* xn   = ws + OFF_XN;
  float* igv  = ws + OFF_IG;
  float* fgv  = ws + OFF_FG;
  float* av   = ws + OFF_A;
  float* pmv  = ws + OFF_PM;
  float* mldv = ws + OFF_MLD;
  float* ylast= ws + OFF_YL;
  float* outp = (float*)d_out;

  // ---- block 0: mLSTM ----
  k_inproj<<<BS_, 256, 0, stream>>>(x, w_in, b_in, hb);
  k_ln<<<BS_, 256, 0, stream>>>(hb, ln0_w, xn);
  k_gemm<<<dim3(2048/64, BS_/64), 256, 0, stream>>>(xn, m_up_w, m_up_b, up, 2048, 512, 0);
  k_conv_silu<<<(BS_*1024)/256, 256, 0, stream>>>(up, m_cv_k, m_cv_b, xc, 1024, 2048, 1024);
  k_headwise4b<<<BS_, 256, 0, stream>>>(xc, q_w, q_b, qbu, 1024);
  k_headwise4b<<<BS_, 256, 0, stream>>>(xc, k_w, k_b, kbu, 1024);
  k_headwise4b<<<BS_, 256, 0, stream>>>(up, v_w, v_b, vbu, 2048);
  k_gates<<<BS_, 256, 0, stream>>>(qbu, kbu, vbu, ig_w, ig_b, fg_w, fg_b, igv, fgv);
  k_decay<<<1, 32, 0, stream>>>(igv, fgv, av, pmv, mldv);
  k_mcell<<<dim3(S_/32, 4, 8), 256, 0, stream>>>(qbu, kbu, vbu, av, pmv, mldv, onormw, ht);
  k_hs<<<(BS_*1024)/256, 256, 0, stream>>>(xc, up, skip_w, ht);
  k_gemm<<<dim3(512/64, BS_/64), 256, 0, stream>>>(ht, m_dn_w, m_dn_b, hb, 512, 1024, 1);

  // ---- block 1: sLSTM ----
  k_ln<<<BS_, 256, 0, stream>>>(hb, ln1_w, xn);
  k_conv_silu<<<(BS_*512)/256, 256, 0, stream>>>(xn, s_cv_k, s_cv_b, xc, 512, 512, 512);
  k_headwise128<<<dim3(BS_/32, 16), 256, 0, stream>>>(xc, xn, wi, wf, wz, wo, up);
  k_sscan<<<32, 512, 0, stream>>>(up, r_kern, cell_b, ylast);

  // ---- last-token epilogue ----
  k_final<<<B_, 256, 0, stream>>>(hb, ylast, gn_w, ln2_w, ffup_w, ffup_b,
                                  ffdn_w, ffdn_b, lnf_w, fc_w, fc_b, outp);
}

// Round 10
// 2259.374 us; speedup vs baseline: 1.9529x; 1.2163x over previous
//
#include <hip/hip_runtime.h>
#include <math.h>

// ---------------- problem constants ----------------
#define B_   8
#define S_   1024
#define BS_  8192        // B*S
#define D_   512
#define IN_  1024        // INNER
#define FIN_ 75

typedef __attribute__((ext_vector_type(8))) short short8_t;   // 8 bf16 (4 VGPRs) MFMA A/B frag
typedef __attribute__((ext_vector_type(4))) float f32x4;      // MFMA C/D frag

// ---------------- workspace layout (floats) ----------------
#define OFF_H    0UL          // h residual: BS*512 f32
#define OFF_UP   4194304UL    // [x_m | z] f32 BS*2048; later reused as wx
#define OFF_XC   20971520UL   // conv outputs f32 (stride 1024 then 512)
#define OFF_Q    29360128UL   // q bf16 BS*1024 (ushort); earlier aliased as xn_bf16
#define OFF_K    33554432UL   // k bf16; later aliased as hs_bf16
#define OFF_V    37748736UL   // v bf16
#define OFF_HT   41943040UL   // htil f32 BS*1024; first BS*512 doubles as xn
#define OFF_XN   OFF_HT
#define OFF_IG   50331648UL
#define OFF_FG   50364416UL
#define OFF_A    50397184UL
#define OFF_PM   50429952UL
#define OFF_MLD  50462720UL
#define OFF_YL   50495488UL
#define OFF_WUB  50499584UL   // m_up_w bf16: 1,048,576 ushorts = 524,288 floats
#define OFF_WDB  51023872UL   // m_dn_w bf16: 524,288 ushorts = 262,144 floats
// total 51,286,016 floats ~= 196 MiB (round-3 run proved >=209 MiB available)

static __device__ __forceinline__ float siluf(float x){ return x / (1.0f + __expf(-x)); }
static __device__ __forceinline__ float logsigf(float x){ return fminf(x, 0.0f) - log1pf(expf(-fabsf(x))); }
static __device__ __forceinline__ float b2f(ushort h){ union { uint u; float f; } v; v.u = ((uint)h) << 16; return v.f; }
static __device__ __forceinline__ ushort f2b(float x){
  union { float f; uint u; } v; v.f = x;
  uint r = v.u + 0x7FFFu + ((v.u >> 16) & 1u);
  return (ushort)(r >> 16);
}

// ---------------- 0. f32 -> bf16 convert (8 elts/thread) ----------------
__global__ __launch_bounds__(256) void k_cvt(const float* __restrict__ src,
                                             ushort* __restrict__ dst, int n8){
  int idx = blockIdx.x*256 + threadIdx.x;
  if (idx >= n8) return;
  float4 a = ((const float4*)src)[idx*2];
  float4 b = ((const float4*)src)[idx*2+1];
  ushort4 lo = { f2b(a.x), f2b(a.y), f2b(a.z), f2b(a.w) };
  ushort4 hi = { f2b(b.x), f2b(b.y), f2b(b.z), f2b(b.w) };
  ((ushort4*)dst)[idx*2]   = lo;
  ((ushort4*)dst)[idx*2+1] = hi;
}

// ---------------- 1. input projection ----------------
__global__ __launch_bounds__(256) void k_inproj(const float* __restrict__ x,
                                                const float* __restrict__ w,
                                                const float* __restrict__ b,
                                                float* __restrict__ out){
  int row = blockIdx.x;
  int tid = threadIdx.x;
  __shared__ float xs[FIN_];
  if (tid < FIN_) xs[tid] = x[(size_t)row*FIN_ + tid];
  __syncthreads();
  #pragma unroll
  for (int rep = 0; rep < 2; ++rep){
    int n = tid + rep*256;
    const float* wr = w + (size_t)n*FIN_;
    float acc = b[n];
    #pragma unroll 5
    for (int k2 = 0; k2 < FIN_; ++k2) acc += xs[k2]*wr[k2];
    out[(size_t)row*D_ + n] = acc;
  }
}

// ---------------- 2. LayerNorm over 512 ----------------
__global__ __launch_bounds__(256) void k_ln(const float* __restrict__ in,
                                            const float* __restrict__ w,
                                            float* __restrict__ out){
  int row = blockIdx.x;
  int tid = threadIdx.x;
  const float* ip = in + (size_t)row*D_;
  float2 v = ((const float2*)ip)[tid];
  float s = v.x + v.y, ss = v.x*v.x + v.y*v.y;
  #pragma unroll
  for (int off = 32; off > 0; off >>= 1){ s += __shfl_down(s, off); ss += __shfl_down(ss, off); }
  __shared__ float rA[4], rB[4];
  int lane = tid & 63, wv = tid >> 6;
  if (lane == 0){ rA[wv] = s; rB[wv] = ss; }
  __syncthreads();
  float S = rA[0]+rA[1]+rA[2]+rA[3];
  float SS = rB[0]+rB[1]+rB[2]+rB[3];
  float mu = S * (1.0f/D_);
  float inv = rsqrtf(SS * (1.0f/D_) - mu*mu + 1e-5f);
  float2 o;
  o.x = (v.x - mu)*inv*w[2*tid];
  o.y = (v.y - mu)*inv*w[2*tid+1];
  ((float2*)(out + (size_t)row*D_))[tid] = o;
}

// ---------------- 3. bf16 MFMA GEMM: C = A[M,K]bf16 @ W[N,K]bf16^T + bias (+C) ----------------
// 128x128 tile, BK=64, 4 waves (2x2), each wave 64x64 (4x4 acc tiles). Swizzled LDS
// (chunk ^= (row&7)<<4) -> 2-way-free ds_read_b128 frags. Pattern verified in k_mcell.
__global__ __launch_bounds__(256, 2) void k_bgemm(const ushort* __restrict__ A,
                                                  const ushort* __restrict__ W,
                                                  const float* __restrict__ bias,
                                                  float* __restrict__ C,
                                                  int N, int K, int accum){
  __shared__ ushort sA[128*64];   // 16KB
  __shared__ ushort sB[128*64];   // 16KB
  int bm = blockIdx.y*128, bn = blockIdx.x*128;
  int tid = threadIdx.x;
  int lane = tid & 63, wid = tid >> 6;
  int ln15 = lane & 15, hi = lane >> 4;
  int wr = wid >> 1, wc = wid & 1;
  f32x4 acc[4][4];
  #pragma unroll
  for (int i = 0; i < 4; ++i)
    #pragma unroll
    for (int j = 0; j < 4; ++j) acc[i][j] = (f32x4){0.f,0.f,0.f,0.f};

  for (int k0 = 0; k0 < K; k0 += 64){
    __syncthreads();
    #pragma unroll
    for (int i = 0; i < 4; ++i){
      int idx = tid + i*256;
      int row = idx >> 3, c8 = idx & 7;
      int dst = row*128 + ((c8*16) ^ ((row & 7) << 4));
      *(short8_t*)((char*)sA + dst) = *(const short8_t*)&A[(size_t)(bm+row)*K + k0 + c8*8];
      *(short8_t*)((char*)sB + dst) = *(const short8_t*)&W[(size_t)(bn+row)*K + k0 + c8*8];
    }
    __syncthreads();
    #pragma unroll
    for (int ks = 0; ks < 2; ++ks){
      short8_t af[4], bf[4];
      int cb = ks*64 + hi*16;
      #pragma unroll
      for (int t = 0; t < 4; ++t){
        int ra = wr*64 + t*16 + ln15;
        af[t] = *(const short8_t*)((const char*)sA + ra*128 + (cb ^ ((ra & 7) << 4)));
        int rb = wc*64 + t*16 + ln15;
        bf[t] = *(const short8_t*)((const char*)sB + rb*128 + (cb ^ ((rb & 7) << 4)));
      }
      #pragma unroll
      for (int tm = 0; tm < 4; ++tm)
        #pragma unroll
        for (int tn = 0; tn < 4; ++tn)
          acc[tm][tn] = __builtin_amdgcn_mfma_f32_16x16x32_bf16(af[tm], bf[tn], acc[tm][tn], 0, 0, 0);
    }
  }
  #pragma unroll
  for (int tm = 0; tm < 4; ++tm){
    #pragma unroll
    for (int rg = 0; rg < 4; ++rg){
      int m = bm + wr*64 + tm*16 + hi*4 + rg;
      #pragma unroll
      for (int tn = 0; tn < 4; ++tn){
        int n = bn + wc*64 + tn*16 + ln15;
        float v = acc[tm][tn][rg] + bias[n];
        size_t off = (size_t)m*N + n;
        if (accum) v += C[off];
        C[off] = v;
      }
    }
  }
}

// ---------------- 4. depthwise causal conv (K=4) + SiLU ----------------
__global__ __launch_bounds__(256) void k_conv_silu(const float* __restrict__ in,
                                                   const float* __restrict__ kern,
                                                   const float* __restrict__ bias,
                                                   float* __restrict__ out,
                                                   int C, int istride, int ostride){
  size_t idx = (size_t)blockIdx.x*256 + threadIdx.x;
  int c = (int)(idx % C);
  size_t rs = idx / C;
  int s = (int)(rs & 1023);
  int b = (int)(rs >> 10);
  const float* ip = in + ((size_t)b*S_)*istride + c;
  float acc = bias[c];
  #pragma unroll
  for (int j = 0; j < 4; ++j){
    int sp = s - 3 + j;
    if (sp >= 0) acc += ip[(size_t)sp*istride] * kern[j*C + c];
  }
  out[((size_t)b*S_ + s)*ostride + c] = siluf(acc);
}

// ---------------- 5. 4x4 block-diagonal -> bf16 output ----------------
__global__ __launch_bounds__(256) void k_headwise4b(const float* __restrict__ in,
                                                    const float* __restrict__ w,
                                                    const float* __restrict__ bias,
                                                    ushort* __restrict__ out,
                                                    int istride){
  int row = blockIdx.x;
  int ph = threadIdx.x;
  float4 iv = *(const float4*)&in[(size_t)row*istride + ph*4];
  const float* wp = w + ph*16;
  float o0 = bias[ph*4+0] + wp[0] *iv.x + wp[1] *iv.y + wp[2] *iv.z + wp[3] *iv.w;
  float o1 = bias[ph*4+1] + wp[4] *iv.x + wp[5] *iv.y + wp[6] *iv.z + wp[7] *iv.w;
  float o2 = bias[ph*4+2] + wp[8] *iv.x + wp[9] *iv.y + wp[10]*iv.z + wp[11]*iv.w;
  float o3 = bias[ph*4+3] + wp[12]*iv.x + wp[13]*iv.y + wp[14]*iv.z + wp[15]*iv.w;
  ushort4 ov = { f2b(o0), f2b(o1), f2b(o2), f2b(o3) };
  *(ushort4*)&out[(size_t)row*1024 + ph*4] = ov;
}

// ---------------- 6. mLSTM i/f gate projections (bf16 inputs) ----------------
__global__ __launch_bounds__(256) void k_gates(const ushort* __restrict__ q,
                                               const ushort* __restrict__ k,
                                               const ushort* __restrict__ v,
                                               const float* __restrict__ igw,
                                               const float* __restrict__ igb,
                                               const float* __restrict__ fgw,
                                               const float* __restrict__ fgb,
                                               float* __restrict__ ig,
                                               float* __restrict__ fg){
  int row = blockIdx.x, tid = threadIdx.x;
  float pi0=0,pi1=0,pi2=0,pi3=0, pf0=0,pf1=0,pf2=0,pf3=0;
  for (int c = tid; c < 3072; c += 256){
    float xv;
    if (c < 1024)      xv = b2f(q[(size_t)row*1024 + c]);
    else if (c < 2048) xv = b2f(k[(size_t)row*1024 + c - 1024]);
    else               xv = b2f(v[(size_t)row*1024 + c - 2048]);
    pi0 += igw[c]*xv;        pf0 += fgw[c]*xv;
    pi1 += igw[3072+c]*xv;   pf1 += fgw[3072+c]*xv;
    pi2 += igw[6144+c]*xv;   pf2 += fgw[6144+c]*xv;
    pi3 += igw[9216+c]*xv;   pf3 += fgw[9216+c]*xv;
  }
  #pragma unroll
  for (int off = 32; off > 0; off >>= 1){
    pi0 += __shfl_down(pi0,off); pi1 += __shfl_down(pi1,off);
    pi2 += __shfl_down(pi2,off); pi3 += __shfl_down(pi3,off);
    pf0 += __shfl_down(pf0,off); pf1 += __shfl_down(pf1,off);
    pf2 += __shfl_down(pf2,off); pf3 += __shfl_down(pf3,off);
  }
  __shared__ float red[8][4];
  int lane = tid & 63, wv = tid >> 6;
  if (lane == 0){
    red[0][wv]=pi0; red[1][wv]=pi1; red[2][wv]=pi2; red[3][wv]=pi3;
    red[4][wv]=pf0; red[5][wv]=pf1; red[6][wv]=pf2; red[7][wv]=pf3;
  }
  __syncthreads();
  if (tid < 8){
    float sv = red[tid][0]+red[tid][1]+red[tid][2]+red[tid][3];
    int b2 = row >> 10, s2 = row & 1023;
    if (tid < 4) ig[((size_t)(b2*4 + tid))*S_ + s2] = sv + igb[tid];
    else         fg[((size_t)(b2*4 + (tid-4)))*S_ + s2] = sv + fgb[tid-4];
  }
}

// ---------------- 7. per-(b,h) decay scans ----------------
__global__ void k_decay(const float* __restrict__ ig, const float* __restrict__ fg,
                        float* __restrict__ a, float* __restrict__ pm, float* __restrict__ mld){
  int bh = threadIdx.x;
  if (bh >= 32) return;
  const float* igp = ig + (size_t)bh*S_;
  const float* fgp = fg + (size_t)bh*S_;
  float cum = 0.0f, pmax = -INFINITY;
  for (int t = 0; t < S_; ++t){
    cum += logsigf(fgp[t]);
    float av = igp[t] - cum;
    pmax = fmaxf(pmax, av);
    a[(size_t)bh*S_ + t]   = av;
    pm[(size_t)bh*S_ + t]  = pmax;
    mld[(size_t)bh*S_ + t] = cum + pmax;
  }
}

// ---------------- 8. mLSTM cell via bf16 MFMA (unchanged, passing) ----------------
__global__ __launch_bounds__(256, 2) void k_mcell(const ushort* __restrict__ qg,
                                                  const ushort* __restrict__ kg,
                                                  const ushort* __restrict__ vg,
                                                  const float* __restrict__ aarr,
                                                  const float* __restrict__ pmarr,
                                                  const float* __restrict__ mldarr,
                                                  const float* __restrict__ onw,
                                                  float* __restrict__ htil){
  int sb = blockIdx.x, hh = blockIdx.y, bb = blockIdx.z;
  int tid = threadIdx.x;
  __shared__ ushort qs[32*256];    // 16KB, swizzled bf16
  __shared__ ushort ks[32*256];    // 16KB, swizzled bf16
  __shared__ ushort vst[256*40];   // 20KB, V transposed [d][t], 80B rows
  __shared__ ushort wlds[32*40];   // 2.5KB, weights [qr][t], 80B rows
  __shared__ float asld[32], pmld[32], mldld[32];
  __shared__ float denred[2][32], smred[2][32], sqred[2][32];
  int s0 = sb*32, bh = bb*4 + hh;
  int lane = tid & 63, wid = tid >> 6;
  int ln15 = lane & 15, hi = lane >> 4;
  int mt = wid >> 1, nt = wid & 1;

  {
    int lr = tid >> 3, lc = tid & 7;
    const ushort* qrow = qg + ((size_t)(bb*S_ + s0 + lr))*IN_ + hh*256 + lc*32;
    int rbase = lr*512, xr = (lr & 7) << 4;
    #pragma unroll
    for (int i = 0; i < 4; ++i){
      short8_t v8 = *(const short8_t*)(qrow + i*8);
      *(short8_t*)((char*)qs + rbase + ((lc*64 + i*16) ^ xr)) = v8;
    }
  }
  if (tid < 32){
    pmld[tid]  = pmarr[(size_t)bh*S_ + s0 + tid];
    mldld[tid] = mldarr[(size_t)bh*S_ + s0 + tid];
  }

  f32x4 pv[8];
  #pragma unroll
  for (int q = 0; q < 8; ++q) pv[q] = (f32x4){0.f,0.f,0.f,0.f};
  float den_acc[4] = {0.f,0.f,0.f,0.f};

  for (int tt = 0; tt <= sb; ++tt){
    int t0 = tt*32;
    __syncthreads();
    {
      int lr = tid >> 3, lc = tid & 7;
      const ushort* krow = kg + ((size_t)(bb*S_ + t0 + lr))*IN_ + hh*256 + lc*32;
      int rbase = lr*512, xr = (lr & 7) << 4;
      #pragma unroll
      for (int i = 0; i < 4; ++i){
        short8_t v8 = *(const short8_t*)(krow + i*8);
        *(short8_t*)((char*)ks + rbase + ((lc*64 + i*16) ^ xr)) = v8;
      }
    }
    {
      int dd = tid >> 4, tt2 = tid & 15;
      const ushort* v0r = vg + ((size_t)(bb*S_ + t0 + 2*tt2))*IN_ + hh*256 + dd*16;
      const ushort* v1r = v0r + IN_;
      short8_t va0 = *(const short8_t*)(v0r);
      short8_t va1 = *(const short8_t*)(v0r + 8);
      short8_t vb0 = *(const short8_t*)(v1r);
      short8_t vb1 = *(const short8_t*)(v1r + 8);
      #pragma unroll
      for (int j = 0; j < 8; ++j){
        uint p0 = (uint)(ushort)va0[j] | ((uint)(ushort)vb0[j] << 16);
        *(uint*)((char*)vst + (dd*16 + j)*80 + tt2*4) = p0;
        uint p1 = (uint)(ushort)va1[j] | ((uint)(ushort)vb1[j] << 16);
        *(uint*)((char*)vst + (dd*16 + 8 + j)*80 + tt2*4) = p1;
      }
    }
    if (tid < 32) asld[tid] = aarr[(size_t)bh*S_ + t0 + tid];
    __syncthreads();
    f32x4 sc = (f32x4){0.f,0.f,0.f,0.f};
    int rA = mt*16 + ln15, rB = nt*16 + ln15;
    int xA = (rA & 7) << 4, xB = (rB & 7) << 4;
    #pragma unroll
    for (int st = 0; st < 8; ++st){
      int cb = st*64 + hi*16;
      short8_t af = *(const short8_t*)((const char*)qs + rA*512 + (cb ^ xA));
      short8_t bf = *(const short8_t*)((const char*)ks + rB*512 + (cb ^ xB));
      sc = __builtin_amdgcn_mfma_f32_16x16x32_bf16(af, bf, sc, 0, 0, 0);
    }
    float av = asld[nt*16 + ln15];
    int tg = t0 + nt*16 + ln15;
    #pragma unroll
    for (int rg = 0; rg < 4; ++rg){
      int qr = mt*16 + hi*4 + rg;
      float wv = (tg <= s0 + qr) ? sc[rg]*0.0625f*__expf(av - pmld[qr]) : 0.0f;
      den_acc[rg] += wv;
      *((ushort*)((char*)wlds + qr*80 + (nt*16 + ln15)*2)) = f2b(wv);
    }
    __syncthreads();
    short8_t aw = *(const short8_t*)((const char*)wlds + (mt*16 + ln15)*80 + hi*16);
    #pragma unroll
    for (int q = 0; q < 8; ++q){
      int dr = (nt*8 + q)*16 + ln15;
      short8_t bv = *(const short8_t*)((const char*)vst + dr*80 + hi*16);
      pv[q] = __builtin_amdgcn_mfma_f32_16x16x32_bf16(aw, bv, pv[q], 0, 0, 0);
    }
  }
  #pragma unroll
  for (int rg = 0; rg < 4; ++rg){
    float d = den_acc[rg];
    d += __shfl_xor(d, 1); d += __shfl_xor(d, 2);
    d += __shfl_xor(d, 4); d += __shfl_xor(d, 8);
    if (ln15 == 0) denred[nt][mt*16 + hi*4 + rg] = d;
  }
  __syncthreads();
  float invr[4];
  #pragma unroll
  for (int rg = 0; rg < 4; ++rg){
    int qr = mt*16 + hi*4 + rg;
    float den = denred[0][qr] + denred[1][qr];
    invr[rg] = 1.0f / (fmaxf(fabsf(den), __expf(-mldld[qr])) + 1e-6f);
    float a1 = 0.f, a2 = 0.f;
    #pragma unroll
    for (int q = 0; q < 8; ++q){ float hv = pv[q][rg]; a1 += hv; a2 += hv*hv; }
    a1 += __shfl_xor(a1, 1); a1 += __shfl_xor(a1, 2); a1 += __shfl_xor(a1, 4); a1 += __shfl_xor(a1, 8);
    a2 += __shfl_xor(a2, 1); a2 += __shfl_xor(a2, 2); a2 += __shfl_xor(a2, 4); a2 += __shfl_xor(a2, 8);
    if (ln15 == 0){ smred[nt][qr] = a1; sqred[nt][qr] = a2; }
  }
  __syncthreads();
  const float* onp = onw + hh*256;
  #pragma unroll
  for (int rg = 0; rg < 4; ++rg){
    int qr = mt*16 + hi*4 + rg;
    float iv = invr[rg];
    float Sm = (smred[0][qr] + smred[1][qr]) * iv * (1.0f/256.0f);
    float Sq = (sqred[0][qr] + sqred[1][qr]) * iv * iv * (1.0f/256.0f);
    float lninv = rsqrtf(Sq - Sm*Sm + 1e-5f);
    float* orow = htil + ((size_t)(bb*S_ + s0 + qr))*IN_ + hh*256;
    #pragma unroll
    for (int q = 0; q < 8; ++q){
      int d = (nt*8 + q)*16 + ln15;
      float hv = pv[q][rg]*iv;
      orow[d] = (hv - Sm)*lninv*onp[d];
    }
  }
}

// ---------------- 9. hs = (htil + skip*xc) * silu(z) -> bf16 ----------------
__global__ __launch_bounds__(256) void k_hsb(const float* __restrict__ xc,
                                             const float* __restrict__ up,
                                             const float* __restrict__ skw,
                                             const float* __restrict__ ht,
                                             ushort* __restrict__ hsb){
  size_t idx = (size_t)blockIdx.x*256 + threadIdx.x;
  int c = (int)(idx & 1023);
  size_t row = idx >> 10;
  float z = up[row*2048 + 1024 + c];
  hsb[idx] = f2b((ht[idx] + skw[c]*xc[idx]) * siluf(z));
}

// ---------------- 10. 128x128 block-diagonal gate projections -> wx ----------------
__global__ __launch_bounds__(256) void k_headwise128(const float* __restrict__ xc,
                                                     const float* __restrict__ xn,
                                                     const float* __restrict__ wi,
                                                     const float* __restrict__ wf,
                                                     const float* __restrict__ wz,
                                                     const float* __restrict__ wo,
                                                     float* __restrict__ wx){
  int mt = blockIdx.x, slice = blockIdx.y;
  int gate = slice >> 2, hh = slice & 3;
  const float* in = (gate < 2) ? xc : xn;
  const float* wmat = (gate==0 ? wi : gate==1 ? wf : gate==2 ? wz : wo) + (size_t)hh*16384;
  __shared__ __align__(16) float ins[32][132];
  __shared__ __align__(16) float wsl[128][132];
  int tid = threadIdx.x, m0 = mt*32;
  #pragma unroll
  for (int i = 0; i < 4; ++i){
    int idx = tid + i*256;
    int rr = idx >> 5, c4 = (idx & 31)*4;
    *(float4*)&ins[rr][c4] = *(const float4*)&in[(size_t)(m0+rr)*512 + hh*128 + c4];
  }
  #pragma unroll
  for (int i = 0; i < 16; ++i){
    int idx = tid + i*256;
    int o = idx >> 5, d4 = (idx & 31)*4;
    *(float4*)&wsl[o][d4] = *(const float4*)&wmat[(size_t)o*128 + d4];
  }
  __syncthreads();
  int rg = tid >> 4, cg = tid & 15;
  float acc[2][8] = {};
  for (int k4 = 0; k4 < 32; ++k4){
    float4 a0 = *(const float4*)&ins[rg*2+0][k4*4];
    float4 a1 = *(const float4*)&ins[rg*2+1][k4*4];
    #pragma unroll
    for (int j = 0; j < 8; ++j){
      float4 w4 = *(const float4*)&wsl[cg*8+j][k4*4];
      acc[0][j] += a0.x*w4.x + a0.y*w4.y + a0.z*w4.z + a0.w*w4.w;
      acc[1][j] += a1.x*w4.x + a1.y*w4.y + a1.z*w4.z + a1.w*w4.w;
    }
  }
  #pragma unroll
  for (int r2 = 0; r2 < 2; ++r2){
    float* op = wx + (size_t)(m0 + rg*2 + r2)*2048 + gate*512 + hh*128 + cg*8;
    float4 o0 = { acc[r2][0], acc[r2][1], acc[r2][2], acc[r2][3] };
    float4 o1 = { acc[r2][4], acc[r2][5], acc[r2][6], acc[r2][7] };
    *(float4*)&op[0] = o0;
    *(float4*)&op[4] = o1;
  }
}

// ---------------- 11. sLSTM scan: 1 block/(b,h); wave owns 16 d's x 4 gates ----------------
// Tile g of wave wid covers R rows g*128 + wid*16 + ln15 -> after broadcast-A MFMA,
// gate lane (hi==0, ln15) holds ir/fr/zr/og in acc[g][0] directly: no raws LDS, ONE
// barrier/step. y double-buffered (read buf[t&1], write buf[(t+1)&1]).
__global__ __launch_bounds__(512) void k_sscan(const float* __restrict__ wx,
                                               const float* __restrict__ R,
                                               const float* __restrict__ cb,
                                               float* __restrict__ ylast){
  int bb = blockIdx.x >> 2, hh = blockIdx.x & 3;
  int tid = threadIdx.x;
  int lane = tid & 63, wid = tid >> 6;
  int ln15 = lane & 15, hi = lane >> 4;
  __shared__ __align__(16) ushort y_lds[2][128];   // double-buffered y state, bf16

  // prologue: B-frags for 4 gate-tiles x 4 ksteps (64 VGPR, register-resident)
  short8_t Rf[4][4];
  #pragma unroll
  for (int g = 0; g < 4; ++g){
    int n = g*128 + wid*16 + ln15;
    #pragma unroll
    for (int ks = 0; ks < 4; ++ks){
      const float* rr = R + ((size_t)hh*512 + n)*128 + ks*32 + hi*8;
      short8_t f;
      #pragma unroll
      for (int j = 0; j < 8; ++j) f[j] = (short)f2b(rr[j]);
      Rf[g][ks] = f;
    }
  }
  if (tid < 128) ((uint*)y_lds)[tid] = 0u;   // zero both buffers

  int gd = wid*16 + ln15;          // this wave's d-range: 16 lanes (hi==0) -> d in [wid*16, +16)
  bool gact = (hi == 0);
  size_t wbase = ((size_t)bb*1024)*2048 + (size_t)hh*128 + gd;
  float bias[4], wc[4], w1[4], wn[4];
  float cst = 0.f, nst = 0.f, mst = 0.f;
  if (gact){
    #pragma unroll
    for (int g = 0; g < 4; ++g){
      bias[g] = cb[g*512 + hh*128 + gd];
      wc[g] = wx[wbase + (size_t)g*512];              // t = 0
      w1[g] = wx[wbase + 2048 + (size_t)g*512];       // t = 1
    }
  }
  __syncthreads();

  for (int t = 0; t < S_; ++t){
    if (gact){
      size_t toff = (size_t)((t+2 < S_) ? t+2 : S_-1) * 2048;   // depth-2 prefetch
      #pragma unroll
      for (int g = 0; g < 4; ++g) wn[g] = wx[wbase + toff + (size_t)g*512];
    }
    const char* ybuf = (const char*)y_lds[t & 1];
    short8_t a[4];
    #pragma unroll
    for (int ks = 0; ks < 4; ++ks)
      a[ks] = *(const short8_t*)(ybuf + ks*64 + hi*16);       // broadcast read
    f32x4 accg[4];
    #pragma unroll
    for (int g = 0; g < 4; ++g){
      f32x4 acc = (f32x4){0.f,0.f,0.f,0.f};
      #pragma unroll
      for (int ks = 0; ks < 4; ++ks)
        acc = __builtin_amdgcn_mfma_f32_16x16x32_bf16(a[ks], Rf[g][ks], acc, 0, 0, 0);
      accg[g] = acc;
    }
    if (gact){
      float ir = accg[0][0] + wc[0] + bias[0];
      float fr = accg[1][0] + wc[1] + bias[1];
      float zr = accg[2][0] + wc[2] + bias[2];
      float og = accg[3][0] + wc[3] + bias[3];
      float lfm = mst + fminf(fr, 0.0f) - __logf(1.0f + __expf(-fabsf(fr)));
      float mnew = (nst == 0.0f) ? ir : fmaxf(ir, lfm);
      float igt = __expf(ir - mnew), fgt = __expf(lfm - mnew);
      float e2 = __expf(2.0f * fminf(zr, 15.0f));
      float th = (e2 - 1.0f) * __builtin_amdgcn_rcpf(e2 + 1.0f);
      cst = fgt*cst + igt*th;
      nst = fgt*nst + igt;
      mst = mnew;
      float den = nst * (1.0f + __expf(-og));
      float yv = cst * __builtin_amdgcn_rcpf(den);
      y_lds[(t+1) & 1][gd] = f2b(yv);
      if (t == S_-1) ylast[(size_t)bb*512 + hh*128 + gd] = yv;
      #pragma unroll
      for (int g = 0; g < 4; ++g){ wc[g] = w1[g]; w1[g] = wn[g]; }
    }
    __syncthreads();   // single barrier: y(t+1) complete; buf[t&1] reads done before its next overwrite
  }
}

// ---------------- 12. last-token epilogue ----------------
__global__ __launch_bounds__(256) void k_final(const float* __restrict__ h,
                                               const float* __restrict__ ylast,
                                               const float* __restrict__ gnw,
                                               const float* __restrict__ ln2w,
                                               const float* __restrict__ upw,
                                               const float* __restrict__ upb,
                                               const float* __restrict__ dnw,
                                               const float* __restrict__ dnb,
                                               const float* __restrict__ lnfw,
                                               const float* __restrict__ fcw,
                                               const float* __restrict__ fcb,
                                               float* __restrict__ out){
  int b = blockIdx.x, tid = threadIdx.x;
  __shared__ __align__(16) float hb[512];
  __shared__ __align__(16) float xb[512];
  __shared__ __align__(16) float ff[1408];
  __shared__ __align__(16) float act[704];
  __shared__ float rA[4], rB[4], hstat[4][2];
  int lane = tid & 63, wv = tid >> 6;
  float y0 = ylast[(size_t)b*512 + wv*128 + lane];
  float y1 = ylast[(size_t)b*512 + wv*128 + 64 + lane];
  {
    float s = y0 + y1, ss = y0*y0 + y1*y1;
    #pragma unroll
    for (int off = 32; off > 0; off >>= 1){ s += __shfl_down(s, off); ss += __shfl_down(ss, off); }
    if (lane == 0){ hstat[wv][0] = s*(1.0f/128.0f); hstat[wv][1] = ss*(1.0f/128.0f); }
  }
  __syncthreads();
  {
    float mu = hstat[wv][0];
    float inv = rsqrtf(hstat[wv][1] - mu*mu + 1e-5f);
    int d0 = wv*128 + lane, d1 = d0 + 64;
    const float* hrow = h + ((size_t)(b*S_ + S_-1))*512;
    hb[d0] = hrow[d0] + (y0 - mu)*inv*gnw[d0];
    hb[d1] = hrow[d1] + (y1 - mu)*inv*gnw[d1];
  }
  __syncthreads();
  {
    float v0 = hb[tid], v1 = hb[tid+256];
    float s = v0+v1, ss = v0*v0+v1*v1;
    #pragma unroll
    for (int off = 32; off > 0; off >>= 1){ s += __shfl_down(s, off); ss += __shfl_down(ss, off); }
    if (lane == 0){ rA[wv] = s; rB[wv] = ss; }
    __syncthreads();
    float S = rA[0]+rA[1]+rA[2]+rA[3], SS = rB[0]+rB[1]+rB[2]+rB[3];
    float mu = S*(1.0f/512.0f);
    float inv = rsqrtf(SS*(1.0f/512.0f) - mu*mu + 1e-5f);
    xb[tid]     = (v0 - mu)*inv*ln2w[tid];
    xb[tid+256] = (v1 - mu)*inv*ln2w[tid+256];
  }
  __syncthreads();
  for (int o = tid; o < 1408; o += 256){
    const float4* wr = (const float4*)(upw + (size_t)o*512);
    float acc = upb[o];
    for (int k4 = 0; k4 < 128; ++k4){
      float4 w4 = wr[k4]; float4 x4 = ((const float4*)xb)[k4];
      acc += w4.x*x4.x + w4.y*x4.y + w4.z*x4.z + w4.w*x4.w;
    }
    ff[o] = acc;
  }
  __syncthreads();
  for (int j = tid; j < 704; j += 256){
    float g = ff[j];
    act[j] = 0.5f*g*(1.0f + erff(g*0.70710678118654752f)) * ff[704+j];
  }
  __syncthreads();
  for (int d2 = tid; d2 < 512; d2 += 256){
    const float4* wr = (const float4*)(dnw + (size_t)d2*704);
    float acc = dnb[d2];
    for (int k4 = 0; k4 < 176; ++k4){
      float4 w4 = wr[k4]; float4 a4 = ((const float4*)act)[k4];
      acc += w4.x*a4.x + w4.y*a4.y + w4.z*a4.z + w4.w*a4.w;
    }
    hb[d2] += acc;
  }
  __syncthreads();
  {
    float v0 = hb[tid], v1 = hb[tid+256];
    float s = v0+v1, ss = v0*v0+v1*v1;
    #pragma unroll
    for (int off = 32; off > 0; off >>= 1){ s += __shfl_down(s, off); ss += __shfl_down(ss, off); }
    if (lane == 0){ rA[wv] = s; rB[wv] = ss; }
    __syncthreads();
    float S = rA[0]+rA[1]+rA[2]+rA[3], SS = rB[0]+rB[1]+rB[2]+rB[3];
    float mu = S*(1.0f/512.0f);
    float inv = rsqrtf(SS*(1.0f/512.0f) - mu*mu + 1e-5f);
    xb[tid]     = (v0 - mu)*inv*lnfw[tid];
    xb[tid+256] = (v1 - mu)*inv*lnfw[tid+256];
  }
  __syncthreads();
  {
    float val = xb[tid]*fcw[tid] + xb[tid+256]*fcw[tid+256];
    #pragma unroll
    for (int off = 32; off > 0; off >>= 1) val += __shfl_down(val, off);
    if (lane == 0) rA[wv] = val;
    __syncthreads();
    if (tid == 0) out[b] = rA[0]+rA[1]+rA[2]+rA[3] + fcb[0];
  }
}

// ---------------- launch ----------------
extern "C" void kernel_launch(void* const* d_in, const int* in_sizes, int n_in,
                              void* d_out, int out_size, void* d_ws, size_t ws_size,
                              hipStream_t stream) {
  const float* x      = (const float*)d_in[0];
  const float* w_in   = (const float*)d_in[1];
  const float* b_in   = (const float*)d_in[2];
  const float* ln0_w  = (const float*)d_in[3];
  const float* m_up_w = (const float*)d_in[4];
  const float* m_up_b = (const float*)d_in[5];
  const float* m_cv_k = (const float*)d_in[6];
  const float* m_cv_b = (const float*)d_in[7];
  const float* q_w    = (const float*)d_in[8];
  const float* q_b    = (const float*)d_in[9];
  const float* k_w    = (const float*)d_in[10];
  const float* k_b    = (const float*)d_in[11];
  const float* v_w    = (const float*)d_in[12];
  const float* v_b    = (const float*)d_in[13];
  const float* ig_w   = (const float*)d_in[14];
  const float* ig_b   = (const float*)d_in[15];
  const float* fg_w   = (const float*)d_in[16];
  const float* fg_b   = (const float*)d_in[17];
  const float* onormw = (const float*)d_in[18];
  const float* skip_w = (const float*)d_in[19];
  const float* m_dn_w = (const float*)d_in[20];
  const float* m_dn_b = (const float*)d_in[21];
  const float* ln1_w  = (const float*)d_in[22];
  const float* s_cv_k = (const float*)d_in[23];
  const float* s_cv_b = (const float*)d_in[24];
  const float* wi     = (const float*)d_in[25];
  const float* wf     = (const float*)d_in[26];
  const float* wz     = (const float*)d_in[27];
  const float* wo     = (const float*)d_in[28];
  const float* r_kern = (const float*)d_in[29];
  const float* cell_b = (const float*)d_in[30];
  const float* gn_w   = (const float*)d_in[31];
  const float* ln2_w  = (const float*)d_in[32];
  const float* ffup_w = (const float*)d_in[33];
  const float* ffup_b = (const float*)d_in[34];
  const float* ffdn_w = (const float*)d_in[35];
  const float* ffdn_b = (const float*)d_in[36];
  const float* lnf_w  = (const float*)d_in[37];
  const float* fc_w   = (const float*)d_in[38];
  const float* fc_b   = (const float*)d_in[39];

  float* ws   = (float*)d_ws;
  float* hb   = ws + OFF_H;
  float* up   = ws + OFF_UP;
  float* xc   = ws + OFF_XC;
  ushort* qbu = (ushort*)(ws + OFF_Q);
  ushort* xnb = qbu;                       // alias: xn bf16 lives here until qbu written
  ushort* kbu = (ushort*)(ws + OFF_K);
  ushort* hsb = kbu;                       // alias: hs bf16 after k_mcell is done with k
  ushort* vbu = (ushort*)(ws + OFF_V);
  float* ht   = ws + OFF_HT;
  float* xn   = ws + OFF_XN;
  float* igv  = ws + OFF_IG;
  float* fgv  = ws + OFF_FG;
  float* av   = ws + OFF_A;
  float* pmv  = ws + OFF_PM;
  float* mldv = ws + OFF_MLD;
  float* ylast= ws + OFF_YL;
  ushort* wub = (ushort*)(ws + OFF_WUB);
  ushort* wdb = (ushort*)(ws + OFF_WDB);
  float* outp = (float*)d_out;

  // weight conversions (independent, tiny)
  k_cvt<<<(2048*512/8 + 255)/256, 256, 0, stream>>>(m_up_w, wub, 2048*512/8);
  k_cvt<<<(512*1024/8 + 255)/256, 256, 0, stream>>>(m_dn_w, wdb, 512*1024/8);

  // ---- block 0: mLSTM ----
  k_inproj<<<BS_, 256, 0, stream>>>(x, w_in, b_in, hb);
  k_ln<<<BS_, 256, 0, stream>>>(hb, ln0_w, xn);
  k_cvt<<<(BS_*512/8 + 255)/256, 256, 0, stream>>>(xn, xnb, BS_*512/8);
  k_bgemm<<<dim3(2048/128, BS_/128), 256, 0, stream>>>(xnb, wub, m_up_b, up, 2048, 512, 0);
  k_conv_silu<<<(BS_*1024)/256, 256, 0, stream>>>(up, m_cv_k, m_cv_b, xc, 1024, 2048, 1024);
  k_headwise4b<<<BS_, 256, 0, stream>>>(xc, q_w, q_b, qbu, 1024);   // overwrites xnb (done)
  k_headwise4b<<<BS_, 256, 0, stream>>>(xc, k_w, k_b, kbu, 1024);
  k_headwise4b<<<BS_, 256, 0, stream>>>(up, v_w, v_b, vbu, 2048);
  k_gates<<<BS_, 256, 0, stream>>>(qbu, kbu, vbu, ig_w, ig_b, fg_w, fg_b, igv, fgv);
  k_decay<<<1, 32, 0, stream>>>(igv, fgv, av, pmv, mldv);
  k_mcell<<<dim3(S_/32, 4, 8), 256, 0, stream>>>(qbu, kbu, vbu, av, pmv, mldv, onormw, ht);
  k_hsb<<<(BS_*1024)/256, 256, 0, stream>>>(xc, up, skip_w, ht, hsb);  // overwrites kbu (done)
  k_bgemm<<<dim3(512/128, BS_/128), 256, 0, stream>>>(hsb, wdb, m_dn_b, hb, 512, 1024, 1);

  // ---- block 1: sLSTM ----
  k_ln<<<BS_, 256, 0, stream>>>(hb, ln1_w, xn);
  k_conv_silu<<<(BS_*512)/256, 256, 0, stream>>>(xn, s_cv_k, s_cv_b, xc, 512, 512, 512);
  k_headwise128<<<dim3(BS_/32, 16), 256, 0, stream>>>(xc, xn, wi, wf, wz, wo, up);
  k_sscan<<<32, 512, 0, stream>>>(up, r_kern, cell_b, ylast);

  // ---- last-token epilogue ----
  k_final<<<B_, 256, 0, stream>>>(hb, ylast, gn_w, ln2_w, ffup_w, ffup_b,
                                  ffdn_w, ffdn_b, lnf_w, fc_w, fc_b, outp);
}

// Round 11
// 2148.356 us; speedup vs baseline: 2.0538x; 1.0517x over previous
//
#include <hip/hip_runtime.h>
#include <math.h>

// ---------------- problem constants ----------------
#define B_   8
#define S_   1024
#define BS_  8192        // B*S
#define D_   512
#define IN_  1024        // INNER
#define FIN_ 75

typedef __attribute__((ext_vector_type(8))) short short8_t;   // 8 bf16 (4 VGPRs) MFMA A/B frag
typedef __attribute__((ext_vector_type(4))) float f32x4;      // MFMA C/D frag

// ---------------- workspace layout (floats) ----------------
#define OFF_H    0UL          // h residual: BS*512 f32
#define OFF_UP   4194304UL    // [x_m | z] f32 BS*2048; later reused as wx
#define OFF_XC   20971520UL   // conv outputs f32 (stride 1024 then 512)
#define OFF_Q    29360128UL   // q bf16 BS*1024 (ushort); earlier aliased as xn_bf16
#define OFF_K    33554432UL   // k bf16; later aliased as hs_bf16
#define OFF_V    37748736UL   // v bf16
#define OFF_HT   41943040UL   // htil f32 BS*1024; first BS*512 doubles as xn
#define OFF_XN   OFF_HT
#define OFF_IG   50331648UL
#define OFF_FG   50364416UL
#define OFF_A    50397184UL
#define OFF_PM   50429952UL
#define OFF_MLD  50462720UL
#define OFF_YL   50495488UL
#define OFF_WUB  50499584UL   // m_up_w bf16: 1,048,576 ushorts = 524,288 floats
#define OFF_WDB  51023872UL   // m_dn_w bf16: 524,288 ushorts = 262,144 floats
// total 51,286,016 floats ~= 196 MiB

static __device__ __forceinline__ float siluf(float x){ return x / (1.0f + __expf(-x)); }
static __device__ __forceinline__ float logsigf(float x){ return fminf(x, 0.0f) - log1pf(expf(-fabsf(x))); }
static __device__ __forceinline__ float b2f(ushort h){ union { uint u; float f; } v; v.u = ((uint)h) << 16; return v.f; }
static __device__ __forceinline__ ushort f2b(float x){
  union { float f; uint u; } v; v.f = x;
  uint r = v.u + 0x7FFFu + ((v.u >> 16) & 1u);
  return (ushort)(r >> 16);
}

// ---------------- 0. f32 -> bf16 convert (weights) ----------------
__global__ __launch_bounds__(256) void k_cvt(const float* __restrict__ src,
                                             ushort* __restrict__ dst, int n8){
  int idx = blockIdx.x*256 + threadIdx.x;
  if (idx >= n8) return;
  float4 a = ((const float4*)src)[idx*2];
  float4 b = ((const float4*)src)[idx*2+1];
  ushort4 lo = { f2b(a.x), f2b(a.y), f2b(a.z), f2b(a.w) };
  ushort4 hi = { f2b(b.x), f2b(b.y), f2b(b.z), f2b(b.w) };
  ((ushort4*)dst)[idx*2]   = lo;
  ((ushort4*)dst)[idx*2+1] = hi;
}

// ---------------- 1. input projection ----------------
__global__ __launch_bounds__(256) void k_inproj(const float* __restrict__ x,
                                                const float* __restrict__ w,
                                                const float* __restrict__ b,
                                                float* __restrict__ out){
  int row = blockIdx.x;
  int tid = threadIdx.x;
  __shared__ float xs[FIN_];
  if (tid < FIN_) xs[tid] = x[(size_t)row*FIN_ + tid];
  __syncthreads();
  #pragma unroll
  for (int rep = 0; rep < 2; ++rep){
    int n = tid + rep*256;
    const float* wr = w + (size_t)n*FIN_;
    float acc = b[n];
    #pragma unroll 5
    for (int k2 = 0; k2 < FIN_; ++k2) acc += xs[k2]*wr[k2];
    out[(size_t)row*D_ + n] = acc;
  }
}

// ---------------- 2a. LayerNorm over 512 -> f32 ----------------
__global__ __launch_bounds__(256) void k_ln(const float* __restrict__ in,
                                            const float* __restrict__ w,
                                            float* __restrict__ out){
  int row = blockIdx.x;
  int tid = threadIdx.x;
  const float* ip = in + (size_t)row*D_;
  float2 v = ((const float2*)ip)[tid];
  float s = v.x + v.y, ss = v.x*v.x + v.y*v.y;
  #pragma unroll
  for (int off = 32; off > 0; off >>= 1){ s += __shfl_down(s, off); ss += __shfl_down(ss, off); }
  __shared__ float rA[4], rB[4];
  int lane = tid & 63, wv = tid >> 6;
  if (lane == 0){ rA[wv] = s; rB[wv] = ss; }
  __syncthreads();
  float S = rA[0]+rA[1]+rA[2]+rA[3];
  float SS = rB[0]+rB[1]+rB[2]+rB[3];
  float mu = S * (1.0f/D_);
  float inv = rsqrtf(SS * (1.0f/D_) - mu*mu + 1e-5f);
  float2 o;
  o.x = (v.x - mu)*inv*w[2*tid];
  o.y = (v.y - mu)*inv*w[2*tid+1];
  ((float2*)(out + (size_t)row*D_))[tid] = o;
}

// ---------------- 2b. LayerNorm over 512 -> bf16 ----------------
__global__ __launch_bounds__(256) void k_lnb(const float* __restrict__ in,
                                             const float* __restrict__ w,
                                             ushort* __restrict__ out){
  int row = blockIdx.x;
  int tid = threadIdx.x;
  const float* ip = in + (size_t)row*D_;
  float2 v = ((const float2*)ip)[tid];
  float s = v.x + v.y, ss = v.x*v.x + v.y*v.y;
  #pragma unroll
  for (int off = 32; off > 0; off >>= 1){ s += __shfl_down(s, off); ss += __shfl_down(ss, off); }
  __shared__ float rA[4], rB[4];
  int lane = tid & 63, wv = tid >> 6;
  if (lane == 0){ rA[wv] = s; rB[wv] = ss; }
  __syncthreads();
  float S = rA[0]+rA[1]+rA[2]+rA[3];
  float SS = rB[0]+rB[1]+rB[2]+rB[3];
  float mu = S * (1.0f/D_);
  float inv = rsqrtf(SS * (1.0f/D_) - mu*mu + 1e-5f);
  ushort o0 = f2b((v.x - mu)*inv*w[2*tid]);
  ushort o1 = f2b((v.y - mu)*inv*w[2*tid+1]);
  ((uint*)(out + (size_t)row*D_))[tid] = (uint)o0 | ((uint)o1 << 16);
}

// ---------------- 3. bf16 MFMA GEMM (verified round 10) ----------------
__global__ __launch_bounds__(256, 2) void k_bgemm(const ushort* __restrict__ A,
                                                  const ushort* __restrict__ W,
                                                  const float* __restrict__ bias,
                                                  float* __restrict__ C,
                                                  int N, int K, int accum){
  __shared__ ushort sA[128*64];   // 16KB
  __shared__ ushort sB[128*64];   // 16KB
  int bm = blockIdx.y*128, bn = blockIdx.x*128;
  int tid = threadIdx.x;
  int lane = tid & 63, wid = tid >> 6;
  int ln15 = lane & 15, hi = lane >> 4;
  int wr = wid >> 1, wc = wid & 1;
  f32x4 acc[4][4];
  #pragma unroll
  for (int i = 0; i < 4; ++i)
    #pragma unroll
    for (int j = 0; j < 4; ++j) acc[i][j] = (f32x4){0.f,0.f,0.f,0.f};

  for (int k0 = 0; k0 < K; k0 += 64){
    __syncthreads();
    #pragma unroll
    for (int i = 0; i < 4; ++i){
      int idx = tid + i*256;
      int row = idx >> 3, c8 = idx & 7;
      int dst = row*128 + ((c8*16) ^ ((row & 7) << 4));
      *(short8_t*)((char*)sA + dst) = *(const short8_t*)&A[(size_t)(bm+row)*K + k0 + c8*8];
      *(short8_t*)((char*)sB + dst) = *(const short8_t*)&W[(size_t)(bn+row)*K + k0 + c8*8];
    }
    __syncthreads();
    #pragma unroll
    for (int ks = 0; ks < 2; ++ks){
      short8_t af[4], bf[4];
      int cb = ks*64 + hi*16;
      #pragma unroll
      for (int t = 0; t < 4; ++t){
        int ra = wr*64 + t*16 + ln15;
        af[t] = *(const short8_t*)((const char*)sA + ra*128 + (cb ^ ((ra & 7) << 4)));
        int rb = wc*64 + t*16 + ln15;
        bf[t] = *(const short8_t*)((const char*)sB + rb*128 + (cb ^ ((rb & 7) << 4)));
      }
      #pragma unroll
      for (int tm = 0; tm < 4; ++tm)
        #pragma unroll
        for (int tn = 0; tn < 4; ++tn)
          acc[tm][tn] = __builtin_amdgcn_mfma_f32_16x16x32_bf16(af[tm], bf[tn], acc[tm][tn], 0, 0, 0);
    }
  }
  #pragma unroll
  for (int tm = 0; tm < 4; ++tm){
    #pragma unroll
    for (int rg = 0; rg < 4; ++rg){
      int m = bm + wr*64 + tm*16 + hi*4 + rg;
      #pragma unroll
      for (int tn = 0; tn < 4; ++tn){
        int n = bn + wc*64 + tn*16 + ln15;
        float v = acc[tm][tn][rg] + bias[n];
        size_t off = (size_t)m*N + n;
        if (accum) v += C[off];
        C[off] = v;
      }
    }
  }
}

// ---------------- 4. fused causal-conv(K=4)+SiLU + q/k/v 4x4 headwise -> bf16 ----------------
// thread ph owns channels c4=4ph of row (b,s): conv over x_m (up stride 2048), then
// q,k = W4x4 @ xc-group; v = W4x4 @ x_m-group. Replaces conv + 3 headwise passes.
__global__ __launch_bounds__(256) void k_convqkv(const float* __restrict__ up,
                                                 const float* __restrict__ kern,
                                                 const float* __restrict__ cbias,
                                                 const float* __restrict__ qw, const float* __restrict__ qb,
                                                 const float* __restrict__ kw, const float* __restrict__ kb,
                                                 const float* __restrict__ vw, const float* __restrict__ vb,
                                                 float* __restrict__ xc,
                                                 ushort* __restrict__ qo,
                                                 ushort* __restrict__ ko,
                                                 ushort* __restrict__ vo){
  int row = blockIdx.x;
  int s = row & 1023;
  int ph = threadIdx.x;
  int c4 = ph*4;
  const float* base = up + (size_t)(row - s)*2048 + c4;
  float4 x3 = *(const float4*)(base + (size_t)s*2048);     // j=3 tap = x_m[s]
  float4 acc = *(const float4*)&cbias[c4];
  {
    float4 k3 = *(const float4*)&kern[3*1024 + c4];
    acc.x += x3.x*k3.x; acc.y += x3.y*k3.y; acc.z += x3.z*k3.z; acc.w += x3.w*k3.w;
  }
  #pragma unroll
  for (int j = 0; j < 3; ++j){
    int sp = s - 3 + j;
    if (sp >= 0){
      float4 xj = *(const float4*)(base + (size_t)sp*2048);
      float4 kj = *(const float4*)&kern[j*1024 + c4];
      acc.x += xj.x*kj.x; acc.y += xj.y*kj.y; acc.z += xj.z*kj.z; acc.w += xj.w*kj.w;
    }
  }
  float4 xcv;
  xcv.x = siluf(acc.x); xcv.y = siluf(acc.y); xcv.z = siluf(acc.z); xcv.w = siluf(acc.w);
  *(float4*)&xc[(size_t)row*1024 + c4] = xcv;
  const float* wp;
  // q from xc
  wp = qw + ph*16;
  {
    float o0 = qb[c4+0] + wp[0] *xcv.x + wp[1] *xcv.y + wp[2] *xcv.z + wp[3] *xcv.w;
    float o1 = qb[c4+1] + wp[4] *xcv.x + wp[5] *xcv.y + wp[6] *xcv.z + wp[7] *xcv.w;
    float o2 = qb[c4+2] + wp[8] *xcv.x + wp[9] *xcv.y + wp[10]*xcv.z + wp[11]*xcv.w;
    float o3 = qb[c4+3] + wp[12]*xcv.x + wp[13]*xcv.y + wp[14]*xcv.z + wp[15]*xcv.w;
    ushort4 ov = { f2b(o0), f2b(o1), f2b(o2), f2b(o3) };
    *(ushort4*)&qo[(size_t)row*1024 + c4] = ov;
  }
  // k from xc
  wp = kw + ph*16;
  {
    float o0 = kb[c4+0] + wp[0] *xcv.x + wp[1] *xcv.y + wp[2] *xcv.z + wp[3] *xcv.w;
    float o1 = kb[c4+1] + wp[4] *xcv.x + wp[5] *xcv.y + wp[6] *xcv.z + wp[7] *xcv.w;
    float o2 = kb[c4+2] + wp[8] *xcv.x + wp[9] *xcv.y + wp[10]*xcv.z + wp[11]*xcv.w;
    float o3 = kb[c4+3] + wp[12]*xcv.x + wp[13]*xcv.y + wp[14]*xcv.z + wp[15]*xcv.w;
    ushort4 ov = { f2b(o0), f2b(o1), f2b(o2), f2b(o3) };
    *(ushort4*)&ko[(size_t)row*1024 + c4] = ov;
  }
  // v from x_m (un-convolved row s)
  wp = vw + ph*16;
  {
    float o0 = vb[c4+0] + wp[0] *x3.x + wp[1] *x3.y + wp[2] *x3.z + wp[3] *x3.w;
    float o1 = vb[c4+1] + wp[4] *x3.x + wp[5] *x3.y + wp[6] *x3.z + wp[7] *x3.w;
    float o2 = vb[c4+2] + wp[8] *x3.x + wp[9] *x3.y + wp[10]*x3.z + wp[11]*x3.w;
    float o3 = vb[c4+3] + wp[12]*x3.x + wp[13]*x3.y + wp[14]*x3.z + wp[15]*x3.w;
    ushort4 ov = { f2b(o0), f2b(o1), f2b(o2), f2b(o3) };
    *(ushort4*)&vo[(size_t)row*1024 + c4] = ov;
  }
}

// ---------------- 4b. depthwise causal conv (K=4) + SiLU (block 1, C=512) ----------------
__global__ __launch_bounds__(256) void k_conv_silu(const float* __restrict__ in,
                                                   const float* __restrict__ kern,
                                                   const float* __restrict__ bias,
                                                   float* __restrict__ out,
                                                   int C, int istride, int ostride){
  size_t idx = (size_t)blockIdx.x*256 + threadIdx.x;
  int c = (int)(idx % C);
  size_t rs = idx / C;
  int s = (int)(rs & 1023);
  int b = (int)(rs >> 10);
  const float* ip = in + ((size_t)b*S_)*istride + c;
  float acc = bias[c];
  #pragma unroll
  for (int j = 0; j < 4; ++j){
    int sp = s - 3 + j;
    if (sp >= 0) acc += ip[(size_t)sp*istride] * kern[j*C + c];
  }
  out[((size_t)b*S_ + s)*ostride + c] = siluf(acc);
}

// ---------------- 6. mLSTM i/f gate projections (bf16 inputs) ----------------
__global__ __launch_bounds__(256) void k_gates(const ushort* __restrict__ q,
                                               const ushort* __restrict__ k,
                                               const ushort* __restrict__ v,
                                               const float* __restrict__ igw,
                                               const float* __restrict__ igb,
                                               const float* __restrict__ fgw,
                                               const float* __restrict__ fgb,
                                               float* __restrict__ ig,
                                               float* __restrict__ fg){
  int row = blockIdx.x, tid = threadIdx.x;
  float pi0=0,pi1=0,pi2=0,pi3=0, pf0=0,pf1=0,pf2=0,pf3=0;
  for (int c = tid; c < 3072; c += 256){
    float xv;
    if (c < 1024)      xv = b2f(q[(size_t)row*1024 + c]);
    else if (c < 2048) xv = b2f(k[(size_t)row*1024 + c - 1024]);
    else               xv = b2f(v[(size_t)row*1024 + c - 2048]);
    pi0 += igw[c]*xv;        pf0 += fgw[c]*xv;
    pi1 += igw[3072+c]*xv;   pf1 += fgw[3072+c]*xv;
    pi2 += igw[6144+c]*xv;   pf2 += fgw[6144+c]*xv;
    pi3 += igw[9216+c]*xv;   pf3 += fgw[9216+c]*xv;
  }
  #pragma unroll
  for (int off = 32; off > 0; off >>= 1){
    pi0 += __shfl_down(pi0,off); pi1 += __shfl_down(pi1,off);
    pi2 += __shfl_down(pi2,off); pi3 += __shfl_down(pi3,off);
    pf0 += __shfl_down(pf0,off); pf1 += __shfl_down(pf1,off);
    pf2 += __shfl_down(pf2,off); pf3 += __shfl_down(pf3,off);
  }
  __shared__ float red[8][4];
  int lane = tid & 63, wv = tid >> 6;
  if (lane == 0){
    red[0][wv]=pi0; red[1][wv]=pi1; red[2][wv]=pi2; red[3][wv]=pi3;
    red[4][wv]=pf0; red[5][wv]=pf1; red[6][wv]=pf2; red[7][wv]=pf3;
  }
  __syncthreads();
  if (tid < 8){
    float sv = red[tid][0]+red[tid][1]+red[tid][2]+red[tid][3];
    int b2 = row >> 10, s2 = row & 1023;
    if (tid < 4) ig[((size_t)(b2*4 + tid))*S_ + s2] = sv + igb[tid];
    else         fg[((size_t)(b2*4 + (tid-4)))*S_ + s2] = sv + fgb[tid-4];
  }
}

// ---------------- 7. per-(b,h) decay scans ----------------
__global__ void k_decay(const float* __restrict__ ig, const float* __restrict__ fg,
                        float* __restrict__ a, float* __restrict__ pm, float* __restrict__ mld){
  int bh = threadIdx.x;
  if (bh >= 32) return;
  const float* igp = ig + (size_t)bh*S_;
  const float* fgp = fg + (size_t)bh*S_;
  float cum = 0.0f, pmax = -INFINITY;
  for (int t = 0; t < S_; ++t){
    cum += logsigf(fgp[t]);
    float av = igp[t] - cum;
    pmax = fmaxf(pmax, av);
    a[(size_t)bh*S_ + t]   = av;
    pm[(size_t)bh*S_ + t]  = pmax;
    mld[(size_t)bh*S_ + t] = cum + pmax;
  }
}

// ---------------- 8. mLSTM cell via bf16 MFMA (unchanged, passing) ----------------
__global__ __launch_bounds__(256, 2) void k_mcell(const ushort* __restrict__ qg,
                                                  const ushort* __restrict__ kg,
                                                  const ushort* __restrict__ vg,
                                                  const float* __restrict__ aarr,
                                                  const float* __restrict__ pmarr,
                                                  const float* __restrict__ mldarr,
                                                  const float* __restrict__ onw,
                                                  float* __restrict__ htil){
  int sb = blockIdx.x, hh = blockIdx.y, bb = blockIdx.z;
  int tid = threadIdx.x;
  __shared__ ushort qs[32*256];    // 16KB, swizzled bf16
  __shared__ ushort ks[32*256];    // 16KB, swizzled bf16
  __shared__ ushort vst[256*40];   // 20KB, V transposed [d][t], 80B rows
  __shared__ ushort wlds[32*40];   // 2.5KB, weights [qr][t], 80B rows
  __shared__ float asld[32], pmld[32], mldld[32];
  __shared__ float denred[2][32], smred[2][32], sqred[2][32];
  int s0 = sb*32, bh = bb*4 + hh;
  int lane = tid & 63, wid = tid >> 6;
  int ln15 = lane & 15, hi = lane >> 4;
  int mt = wid >> 1, nt = wid & 1;

  {
    int lr = tid >> 3, lc = tid & 7;
    const ushort* qrow = qg + ((size_t)(bb*S_ + s0 + lr))*IN_ + hh*256 + lc*32;
    int rbase = lr*512, xr = (lr & 7) << 4;
    #pragma unroll
    for (int i = 0; i < 4; ++i){
      short8_t v8 = *(const short8_t*)(qrow + i*8);
      *(short8_t*)((char*)qs + rbase + ((lc*64 + i*16) ^ xr)) = v8;
    }
  }
  if (tid < 32){
    pmld[tid]  = pmarr[(size_t)bh*S_ + s0 + tid];
    mldld[tid] = mldarr[(size_t)bh*S_ + s0 + tid];
  }

  f32x4 pv[8];
  #pragma unroll
  for (int q = 0; q < 8; ++q) pv[q] = (f32x4){0.f,0.f,0.f,0.f};
  float den_acc[4] = {0.f,0.f,0.f,0.f};

  for (int tt = 0; tt <= sb; ++tt){
    int t0 = tt*32;
    __syncthreads();
    {
      int lr = tid >> 3, lc = tid & 7;
      const ushort* krow = kg + ((size_t)(bb*S_ + t0 + lr))*IN_ + hh*256 + lc*32;
      int rbase = lr*512, xr = (lr & 7) << 4;
      #pragma unroll
      for (int i = 0; i < 4; ++i){
        short8_t v8 = *(const short8_t*)(krow + i*8);
        *(short8_t*)((char*)ks + rbase + ((lc*64 + i*16) ^ xr)) = v8;
      }
    }
    {
      int dd = tid >> 4, tt2 = tid & 15;
      const ushort* v0r = vg + ((size_t)(bb*S_ + t0 + 2*tt2))*IN_ + hh*256 + dd*16;
      const ushort* v1r = v0r + IN_;
      short8_t va0 = *(const short8_t*)(v0r);
      short8_t va1 = *(const short8_t*)(v0r + 8);
      short8_t vb0 = *(const short8_t*)(v1r);
      short8_t vb1 = *(const short8_t*)(v1r + 8);
      #pragma unroll
      for (int j = 0; j < 8; ++j){
        uint p0 = (uint)(ushort)va0[j] | ((uint)(ushort)vb0[j] << 16);
        *(uint*)((char*)vst + (dd*16 + j)*80 + tt2*4) = p0;
        uint p1 = (uint)(ushort)va1[j] | ((uint)(ushort)vb1[j] << 16);
        *(uint*)((char*)vst + (dd*16 + 8 + j)*80 + tt2*4) = p1;
      }
    }
    if (tid < 32) asld[tid] = aarr[(size_t)bh*S_ + t0 + tid];
    __syncthreads();
    f32x4 sc = (f32x4){0.f,0.f,0.f,0.f};
    int rA = mt*16 + ln15, rB = nt*16 + ln15;
    int xA = (rA & 7) << 4, xB = (rB & 7) << 4;
    #pragma unroll
    for (int st = 0; st < 8; ++st){
      int cb = st*64 + hi*16;
      short8_t af = *(const short8_t*)((const char*)qs + rA*512 + (cb ^ xA));
      short8_t bf = *(const short8_t*)((const char*)ks + rB*512 + (cb ^ xB));
      sc = __builtin_amdgcn_mfma_f32_16x16x32_bf16(af, bf, sc, 0, 0, 0);
    }
    float av = asld[nt*16 + ln15];
    int tg = t0 + nt*16 + ln15;
    #pragma unroll
    for (int rg = 0; rg < 4; ++rg){
      int qr = mt*16 + hi*4 + rg;
      float wv = (tg <= s0 + qr) ? sc[rg]*0.0625f*__expf(av - pmld[qr]) : 0.0f;
      den_acc[rg] += wv;
      *((ushort*)((char*)wlds + qr*80 + (nt*16 + ln15)*2)) = f2b(wv);
    }
    __syncthreads();
    short8_t aw = *(const short8_t*)((const char*)wlds + (mt*16 + ln15)*80 + hi*16);
    #pragma unroll
    for (int q = 0; q < 8; ++q){
      int dr = (nt*8 + q)*16 + ln15;
      short8_t bv = *(const short8_t*)((const char*)vst + dr*80 + hi*16);
      pv[q] = __builtin_amdgcn_mfma_f32_16x16x32_bf16(aw, bv, pv[q], 0, 0, 0);
    }
  }
  #pragma unroll
  for (int rg = 0; rg < 4; ++rg){
    float d = den_acc[rg];
    d += __shfl_xor(d, 1); d += __shfl_xor(d, 2);
    d += __shfl_xor(d, 4); d += __shfl_xor(d, 8);
    if (ln15 == 0) denred[nt][mt*16 + hi*4 + rg] = d;
  }
  __syncthreads();
  float invr[4];
  #pragma unroll
  for (int rg = 0; rg < 4; ++rg){
    int qr = mt*16 + hi*4 + rg;
    float den = denred[0][qr] + denred[1][qr];
    invr[rg] = 1.0f / (fmaxf(fabsf(den), __expf(-mldld[qr])) + 1e-6f);
    float a1 = 0.f, a2 = 0.f;
    #pragma unroll
    for (int q = 0; q < 8; ++q){ float hv = pv[q][rg]; a1 += hv; a2 += hv*hv; }
    a1 += __shfl_xor(a1, 1); a1 += __shfl_xor(a1, 2); a1 += __shfl_xor(a1, 4); a1 += __shfl_xor(a1, 8);
    a2 += __shfl_xor(a2, 1); a2 += __shfl_xor(a2, 2); a2 += __shfl_xor(a2, 4); a2 += __shfl_xor(a2, 8);
    if (ln15 == 0){ smred[nt][qr] = a1; sqred[nt][qr] = a2; }
  }
  __syncthreads();
  const float* onp = onw + hh*256;
  #pragma unroll
  for (int rg = 0; rg < 4; ++rg){
    int qr = mt*16 + hi*4 + rg;
    float iv = invr[rg];
    float Sm = (smred[0][qr] + smred[1][qr]) * iv * (1.0f/256.0f);
    float Sq = (sqred[0][qr] + sqred[1][qr]) * iv * iv * (1.0f/256.0f);
    float lninv = rsqrtf(Sq - Sm*Sm + 1e-5f);
    float* orow = htil + ((size_t)(bb*S_ + s0 + qr))*IN_ + hh*256;
    #pragma unroll
    for (int q = 0; q < 8; ++q){
      int d = (nt*8 + q)*16 + ln15;
      float hv = pv[q][rg]*iv;
      orow[d] = (hv - Sm)*lninv*onp[d];
    }
  }
}

// ---------------- 9. hs = (htil + skip*xc) * silu(z) -> bf16 ----------------
__global__ __launch_bounds__(256) void k_hsb(const float* __restrict__ xc,
                                             const float* __restrict__ up,
                                             const float* __restrict__ skw,
                                             const float* __restrict__ ht,
                                             ushort* __restrict__ hsb){
  size_t idx = (size_t)blockIdx.x*256 + threadIdx.x;
  int c = (int)(idx & 1023);
  size_t row = idx >> 10;
  float z = up[row*2048 + 1024 + c];
  hsb[idx] = f2b((ht[idx] + skw[c]*xc[idx]) * siluf(z));
}

// ---------------- 10. 128x128 block-diagonal gate projections -> wx ----------------
__global__ __launch_bounds__(256) void k_headwise128(const float* __restrict__ xc,
                                                     const float* __restrict__ xn,
                                                     const float* __restrict__ wi,
                                                     const float* __restrict__ wf,
                                                     const float* __restrict__ wz,
                                                     const float* __restrict__ wo,
                                                     float* __restrict__ wx){
  int mt = blockIdx.x, slice = blockIdx.y;
  int gate = slice >> 2, hh = slice & 3;
  const float* in = (gate < 2) ? xc : xn;
  const float* wmat = (gate==0 ? wi : gate==1 ? wf : gate==2 ? wz : wo) + (size_t)hh*16384;
  __shared__ __align__(16) float ins[32][132];
  __shared__ __align__(16) float wsl[128][132];
  int tid = threadIdx.x, m0 = mt*32;
  #pragma unroll
  for (int i = 0; i < 4; ++i){
    int idx = tid + i*256;
    int rr = idx >> 5, c4 = (idx & 31)*4;
    *(float4*)&ins[rr][c4] = *(const float4*)&in[(size_t)(m0+rr)*512 + hh*128 + c4];
  }
  #pragma unroll
  for (int i = 0; i < 16; ++i){
    int idx = tid + i*256;
    int o = idx >> 5, d4 = (idx & 31)*4;
    *(float4*)&wsl[o][d4] = *(const float4*)&wmat[(size_t)o*128 + d4];
  }
  __syncthreads();
  int rg = tid >> 4, cg = tid & 15;
  float acc[2][8] = {};
  for (int k4 = 0; k4 < 32; ++k4){
    float4 a0 = *(const float4*)&ins[rg*2+0][k4*4];
    float4 a1 = *(const float4*)&ins[rg*2+1][k4*4];
    #pragma unroll
    for (int j = 0; j < 8; ++j){
      float4 w4 = *(const float4*)&wsl[cg*8+j][k4*4];
      acc[0][j] += a0.x*w4.x + a0.y*w4.y + a0.z*w4.z + a0.w*w4.w;
      acc[1][j] += a1.x*w4.x + a1.y*w4.y + a1.z*w4.z + a1.w*w4.w;
    }
  }
  #pragma unroll
  for (int r2 = 0; r2 < 2; ++r2){
    float* op = wx + (size_t)(m0 + rg*2 + r2)*2048 + gate*512 + hh*128 + cg*8;
    float4 o0 = { acc[r2][0], acc[r2][1], acc[r2][2], acc[r2][3] };
    float4 o1 = { acc[r2][4], acc[r2][5], acc[r2][6], acc[r2][7] };
    *(float4*)&op[0] = o0;
    *(float4*)&op[4] = o1;
  }
}

// ---------------- 11. sLSTM scan: raw barriers (no vmcnt drain) + depth-4 prefetch ----------------
// Per step: ds_read y -> 16 MFMAs (2+2 chains) -> gate math (hi==0 lanes) -> ds_write y ->
// lgkmcnt(0) + raw s_barrier + sched_barrier (T3/T4: wx prefetch loads stay in flight).
// 4-step unroll, 4 named wx register sets: vmcnt wait lands 4 steps after issue.
__global__ __launch_bounds__(512) void k_sscan(const float* __restrict__ wx,
                                               const float* __restrict__ R,
                                               const float* __restrict__ cb,
                                               float* __restrict__ ylast){
  int bb = blockIdx.x >> 2, hh = blockIdx.x & 3;
  int tid = threadIdx.x;
  int lane = tid & 63, wid = tid >> 6;
  int ln15 = lane & 15, hi = lane >> 4;
  __shared__ __align__(16) ushort y_lds[2][128];   // double-buffered y state, bf16

  short8_t Rf[4][4];
  #pragma unroll
  for (int g = 0; g < 4; ++g){
    int n = g*128 + wid*16 + ln15;
    #pragma unroll
    for (int ks = 0; ks < 4; ++ks){
      const float* rr = R + ((size_t)hh*512 + n)*128 + ks*32 + hi*8;
      short8_t f;
      #pragma unroll
      for (int j = 0; j < 8; ++j) f[j] = (short)f2b(rr[j]);
      Rf[g][ks] = f;
    }
  }
  if (tid < 128) ((uint*)y_lds)[tid] = 0u;   // zero both buffers (2*128 bf16 = 128 uints)

  int gd = wid*16 + ln15;
  bool gact = (hi == 0);
  size_t wbase = ((size_t)bb*1024)*2048 + (size_t)hh*128 + gd;
  float bias[4], w0[4], w1[4], w2[4], w3[4];
  float cst = 0.f, nst = 0.f, mst = 0.f;
  if (gact){
    #pragma unroll
    for (int g = 0; g < 4; ++g){
      bias[g] = cb[g*512 + hh*128 + gd];
      w0[g] = wx[wbase + 0*2048 + (size_t)g*512];
      w1[g] = wx[wbase + 1*2048 + (size_t)g*512];
      w2[g] = wx[wbase + 2*2048 + (size_t)g*512];
      w3[g] = wx[wbase + 3*2048 + (size_t)g*512];
    }
  }
  __syncthreads();

#define SSTEP(T, PAR, WREG)                                                              \
  {                                                                                      \
    const char* ybuf = (const char*)y_lds[PAR];                                          \
    short8_t a0 = *(const short8_t*)(ybuf + 0  + hi*16);                                 \
    short8_t a1 = *(const short8_t*)(ybuf + 64 + hi*16);                                 \
    short8_t a2 = *(const short8_t*)(ybuf + 128 + hi*16);                                \
    short8_t a3 = *(const short8_t*)(ybuf + 192 + hi*16);                                \
    f32x4 z4 = (f32x4){0.f,0.f,0.f,0.f};                                                 \
    float rawv[4];                                                                       \
    _Pragma("unroll")                                                                    \
    for (int g = 0; g < 4; ++g){                                                         \
      f32x4 pA = __builtin_amdgcn_mfma_f32_16x16x32_bf16(a0, Rf[g][0], z4, 0, 0, 0);     \
      pA = __builtin_amdgcn_mfma_f32_16x16x32_bf16(a1, Rf[g][1], pA, 0, 0, 0);           \
      f32x4 pB = __builtin_amdgcn_mfma_f32_16x16x32_bf16(a2, Rf[g][2], z4, 0, 0, 0);     \
      pB = __builtin_amdgcn_mfma_f32_16x16x32_bf16(a3, Rf[g][3], pB, 0, 0, 0);           \
      rawv[g] = pA[0] + pB[0];                                                           \
    }                                                                                    \
    if (gact){                                                                           \
      float ir = rawv[0] + WREG[0] + bias[0];                                            \
      float fr = rawv[1] + WREG[1] + bias[1];                                            \
      float zr = rawv[2] + WREG[2] + bias[2];                                            \
      float og = rawv[3] + WREG[3] + bias[3];                                            \
      float lfm = mst + fminf(fr, 0.0f) - __logf(1.0f + __expf(-fabsf(fr)));             \
      float mnew = (nst == 0.0f) ? ir : fmaxf(ir, lfm);                                  \
      float igt = __expf(ir - mnew), fgt = __expf(lfm - mnew);                           \
      float e2 = __expf(2.0f * fminf(zr, 15.0f));                                        \
      float th = (e2 - 1.0f) * __builtin_amdgcn_rcpf(e2 + 1.0f);                         \
      cst = fgt*cst + igt*th;                                                            \
      nst = fgt*nst + igt;                                                               \
      mst = mnew;                                                                        \
      float den = nst * (1.0f + __expf(-og));                                            \
      float yv = cst * __builtin_amdgcn_rcpf(den);                                       \
      y_lds[(PAR) ^ 1][gd] = f2b(yv);                                                    \
      if ((T) == S_-1) ylast[(size_t)bb*512 + hh*128 + gd] = yv;                         \
      int tp = (T) + 4; if (tp >= S_) tp = S_-1;                                         \
      _Pragma("unroll")                                                                  \
      for (int g = 0; g < 4; ++g) WREG[g] = wx[wbase + (size_t)tp*2048 + (size_t)g*512]; \
    }                                                                                    \
    asm volatile("s_waitcnt lgkmcnt(0)" ::: "memory");                                   \
    __builtin_amdgcn_s_barrier();                                                        \
    __builtin_amdgcn_sched_barrier(0);                                                   \
  }

  for (int t0 = 0; t0 < S_; t0 += 4){
    SSTEP(t0+0, 0, w0)
    SSTEP(t0+1, 1, w1)
    SSTEP(t0+2, 0, w2)
    SSTEP(t0+3, 1, w3)
  }
#undef SSTEP
}

// ---------------- 12. last-token epilogue ----------------
__global__ __launch_bounds__(256) void k_final(const float* __restrict__ h,
                                               const float* __restrict__ ylast,
                                               const float* __restrict__ gnw,
                                               const float* __restrict__ ln2w,
                                               const float* __restrict__ upw,
                                               const float* __restrict__ upb,
                                               const float* __restrict__ dnw,
                                               const float* __restrict__ dnb,
                                               const float* __restrict__ lnfw,
                                               const float* __restrict__ fcw,
                                               const float* __restrict__ fcb,
                                               float* __restrict__ out){
  int b = blockIdx.x, tid = threadIdx.x;
  __shared__ __align__(16) float hb[512];
  __shared__ __align__(16) float xb[512];
  __shared__ __align__(16) float ff[1408];
  __shared__ __align__(16) float act[704];
  __shared__ float rA[4], rB[4], hstat[4][2];
  int lane = tid & 63, wv = tid >> 6;
  float y0 = ylast[(size_t)b*512 + wv*128 + lane];
  float y1 = ylast[(size_t)b*512 + wv*128 + 64 + lane];
  {
    float s = y0 + y1, ss = y0*y0 + y1*y1;
    #pragma unroll
    for (int off = 32; off > 0; off >>= 1){ s += __shfl_down(s, off); ss += __shfl_down(ss, off); }
    if (lane == 0){ hstat[wv][0] = s*(1.0f/128.0f); hstat[wv][1] = ss*(1.0f/128.0f); }
  }
  __syncthreads();
  {
    float mu = hstat[wv][0];
    float inv = rsqrtf(hstat[wv][1] - mu*mu + 1e-5f);
    int d0 = wv*128 + lane, d1 = d0 + 64;
    const float* hrow = h + ((size_t)(b*S_ + S_-1))*512;
    hb[d0] = hrow[d0] + (y0 - mu)*inv*gnw[d0];
    hb[d1] = hrow[d1] + (y1 - mu)*inv*gnw[d1];
  }
  __syncthreads();
  {
    float v0 = hb[tid], v1 = hb[tid+256];
    float s = v0+v1, ss = v0*v0+v1*v1;
    #pragma unroll
    for (int off = 32; off > 0; off >>= 1){ s += __shfl_down(s, off); ss += __shfl_down(ss, off); }
    if (lane == 0){ rA[wv] = s; rB[wv] = ss; }
    __syncthreads();
    float S = rA[0]+rA[1]+rA[2]+rA[3], SS = rB[0]+rB[1]+rB[2]+rB[3];
    float mu = S*(1.0f/512.0f);
    float inv = rsqrtf(SS*(1.0f/512.0f) - mu*mu + 1e-5f);
    xb[tid]     = (v0 - mu)*inv*ln2w[tid];
    xb[tid+256] = (v1 - mu)*inv*ln2w[tid+256];
  }
  __syncthreads();
  for (int o = tid; o < 1408; o += 256){
    const float4* wr = (const float4*)(upw + (size_t)o*512);
    float acc = upb[o];
    for (int k4 = 0; k4 < 128; ++k4){
      float4 w4 = wr[k4]; float4 x4 = ((const float4*)xb)[k4];
      acc += w4.x*x4.x + w4.y*x4.y + w4.z*x4.z + w4.w*x4.w;
    }
    ff[o] = acc;
  }
  __syncthreads();
  for (int j = tid; j < 704; j += 256){
    float g = ff[j];
    act[j] = 0.5f*g*(1.0f + erff(g*0.70710678118654752f)) * ff[704+j];
  }
  __syncthreads();
  for (int d2 = tid; d2 < 512; d2 += 256){
    const float4* wr = (const float4*)(dnw + (size_t)d2*704);
    float acc = dnb[d2];
    for (int k4 = 0; k4 < 176; ++k4){
      float4 w4 = wr[k4]; float4 a4 = ((const float4*)act)[k4];
      acc += w4.x*a4.x + w4.y*a4.y + w4.z*a4.z + w4.w*a4.w;
    }
    hb[d2] += acc;
  }
  __syncthreads();
  {
    float v0 = hb[tid], v1 = hb[tid+256];
    float s = v0+v1, ss = v0*v0+v1*v1;
    #pragma unroll
    for (int off = 32; off > 0; off >>= 1){ s += __shfl_down(s, off); ss += __shfl_down(ss, off); }
    if (lane == 0){ rA[wv] = s; rB[wv] = ss; }
    __syncthreads();
    float S = rA[0]+rA[1]+rA[2]+rA[3], SS = rB[0]+rB[1]+rB[2]+rB[3];
    float mu = S*(1.0f/512.0f);
    float inv = rsqrtf(SS*(1.0f/512.0f) - mu*mu + 1e-5f);
    xb[tid]     = (v0 - mu)*inv*lnfw[tid];
    xb[tid+256] = (v1 - mu)*inv*lnfw[tid+256];
  }
  __syncthreads();
  {
    float val = xb[tid]*fcw[tid] + xb[tid+256]*fcw[tid+256];
    #pragma unroll
    for (int off = 32; off > 0; off >>= 1) val += __shfl_down(val, off);
    if (lane == 0) rA[wv] = val;
    __syncthreads();
    if (tid == 0) out[b] = rA[0]+rA[1]+rA[2]+rA[3] + fcb[0];
  }
}

// ---------------- launch ----------------
extern "C" void kernel_launch(void* const* d_in, const int* in_sizes, int n_in,
                              void* d_out, int out_size, void* d_ws, size_t ws_size,
                              hipStream_t stream) {
  const float* x      = (const float*)d_in[0];
  const float* w_in   = (const float*)d_in[1];
  const float* b_in   = (const float*)d_in[2];
  const float* ln0_w  = (const float*)d_in[3];
  const float* m_up_w = (const float*)d_in[4];
  const float* m_up_b = (const float*)d_in[5];
  const float* m_cv_k = (const float*)d_in[6];
  const float* m_cv_b = (const float*)d_in[7];
  const float* q_w    = (const float*)d_in[8];
  const float* q_b    = (const float*)d_in[9];
  const float* k_w    = (const float*)d_in[10];
  const float* k_b    = (const float*)d_in[11];
  const float* v_w    = (const float*)d_in[12];
  const float* v_b    = (const float*)d_in[13];
  const float* ig_w   = (const float*)d_in[14];
  const float* ig_b   = (const float*)d_in[15];
  const float* fg_w   = (const float*)d_in[16];
  const float* fg_b   = (const float*)d_in[17];
  const float* onormw = (const float*)d_in[18];
  const float* skip_w = (const float*)d_in[19];
  const float* m_dn_w = (const float*)d_in[20];
  const float* m_dn_b = (const float*)d_in[21];
  const float* ln1_w  = (const float*)d_in[22];
  const float* s_cv_k = (const float*)d_in[23];
  const float* s_cv_b = (const float*)d_in[24];
  const float* wi     = (const float*)d_in[25];
  const float* wf     = (const float*)d_in[26];
  const float* wz     = (const float*)d_in[27];
  const float* wo     = (const float*)d_in[28];
  const float* r_kern = (const float*)d_in[29];
  const float* cell_b = (const float*)d_in[30];
  const float* gn_w   = (const float*)d_in[31];
  const float* ln2_w  = (const float*)d_in[32];
  const float* ffup_w = (const float*)d_in[33];
  const float* ffup_b = (const float*)d_in[34];
  const float* ffdn_w = (const float*)d_in[35];
  const float* ffdn_b = (const float*)d_in[36];
  const float* lnf_w  = (const float*)d_in[37];
  const float* fc_w   = (const float*)d_in[38];
  const float* fc_b   = (const float*)d_in[39];

  float* ws   = (float*)d_ws;
  float* hb   = ws + OFF_H;
  float* up   = ws + OFF_UP;
  float* xc   = ws + OFF_XC;
  ushort* qbu = (ushort*)(ws + OFF_Q);
  ushort* xnb = qbu;                       // alias: xn bf16 lives here until qbu written
  ushort* kbu = (ushort*)(ws + OFF_K);
  ushort* hsb = kbu;                       // alias: hs bf16 after k_mcell is done with k
  ushort* vbu = (ushort*)(ws + OFF_V);
  float* ht   = ws + OFF_HT;
  float* xn   = ws + OFF_XN;
  float* igv  = ws + OFF_IG;
  float* fgv  = ws + OFF_FG;
  float* av   = ws + OFF_A;
  float* pmv  = ws + OFF_PM;
  float* mldv = ws + OFF_MLD;
  float* ylast= ws + OFF_YL;
  ushort* wub = (ushort*)(ws + OFF_WUB);
  ushort* wdb = (ushort*)(ws + OFF_WDB);
  float* outp = (float*)d_out;

  // weight conversions (independent, tiny)
  k_cvt<<<(2048*512/8 + 255)/256, 256, 0, stream>>>(m_up_w, wub, 2048*512/8);
  k_cvt<<<(512*1024/8 + 255)/256, 256, 0, stream>>>(m_dn_w, wdb, 512*1024/8);

  // ---- block 0: mLSTM ----
  k_inproj<<<BS_, 256, 0, stream>>>(x, w_in, b_in, hb);
  k_lnb<<<BS_, 256, 0, stream>>>(hb, ln0_w, xnb);
  k_bgemm<<<dim3(2048/128, BS_/128), 256, 0, stream>>>(xnb, wub, m_up_b, up, 2048, 512, 0);
  k_convqkv<<<BS_, 256, 0, stream>>>(up, m_cv_k, m_cv_b, q_w, q_b, k_w, k_b, v_w, v_b,
                                     xc, qbu, kbu, vbu);   // qbu overwrites xnb (done)
  k_gates<<<BS_, 256, 0, stream>>>(qbu, kbu, vbu, ig_w, ig_b, fg_w, fg_b, igv, fgv);
  k_decay<<<1, 32, 0, stream>>>(igv, fgv, av, pmv, mldv);
  k_mcell<<<dim3(S_/32, 4, 8), 256, 0, stream>>>(qbu, kbu, vbu, av, pmv, mldv, onormw, ht);
  k_hsb<<<(BS_*1024)/256, 256, 0, stream>>>(xc, up, skip_w, ht, hsb);  // overwrites kbu (done)
  k_bgemm<<<dim3(512/128, BS_/128), 256, 0, stream>>>(hsb, wdb, m_dn_b, hb, 512, 1024, 1);

  // ---- block 1: sLSTM ----
  k_ln<<<BS_, 256, 0, stream>>>(hb, ln1_w, xn);
  k_conv_silu<<<(BS_*512)/256, 256, 0, stream>>>(xn, s_cv_k, s_cv_b, xc, 512, 512, 512);
  k_headwise128<<<dim3(BS_/32, 16), 256, 0, stream>>>(xc, xn, wi, wf, wz, wo, up);
  k_sscan<<<32, 512, 0, stream>>>(up, r_kern, cell_b, ylast);

  // ---- last-token epilogue ----
  k_final<<<B_, 256, 0, stream>>>(hb, ylast, gn_w, ln2_w, ffup_w, ffup_b,
                                  ffdn_w, ffdn_b, lnf_w, fc_w, fc_b, outp);
}